// Round 1
// baseline (3895.744 us; speedup 1.0000x reference)
//
#include <hip/hip_runtime.h>
#include <math.h>

// Problem constants (from reference)
constexpr int cN   = 10000;
constexpr int cE   = 120000;
constexpr int cFin = 64;
constexpr int cC   = 128;
constexpr int cH   = 4;
constexpr int cL   = 5;
constexpr int cG   = 500;
constexpr int cOUT = 1801;
constexpr int cHL  = 320;          // (L*C)/2
constexpr int cKcat = cC + cHL;    // 448
constexpr int c4HL = 4 * cHL;      // 1280

// ---------------- utility kernels ----------------
__global__ void fill_f32_kernel(float* __restrict__ p, long n, float v) {
    long i = (long)blockIdx.x * blockDim.x + threadIdx.x;
    if (i < n) p[i] = v;
}
__global__ void fill_i32_kernel(int* __restrict__ p, long n, int v) {
    long i = (long)blockIdx.x * blockDim.x + threadIdx.x;
    if (i < n) p[i] = v;
}
__global__ void copy_i32_kernel(const int* __restrict__ a, int* __restrict__ b, long n) {
    long i = (long)blockIdx.x * blockDim.x + threadIdx.x;
    if (i < n) b[i] = a[i];
}

// ---------------- CSR build (by dst) ----------------
__global__ void hist_kernel(const int* __restrict__ dst, int* __restrict__ count) {
    int i = blockIdx.x * blockDim.x + threadIdx.x;
    if (i < cE) atomicAdd(&count[dst[i]], 1);
}

// single-block exclusive scan over count[cN] -> offs[cN+1]
__global__ void scan_kernel(const int* __restrict__ count, int* __restrict__ offs) {
    __shared__ int part[256];
    const int tid = threadIdx.x;
    const int CH = (cN + 255) / 256;   // 40
    int base = tid * CH;
    int s = 0;
    for (int i = 0; i < CH; i++) {
        int idx = base + i;
        if (idx < cN) s += count[idx];
    }
    part[tid] = s;
    __syncthreads();
    for (int d = 1; d < 256; d <<= 1) {
        int v = 0;
        if (tid >= d) v = part[tid - d];
        __syncthreads();
        if (tid >= d) part[tid] += v;
        __syncthreads();
    }
    int prefix = (tid == 0) ? 0 : part[tid - 1];
    for (int i = 0; i < CH; i++) {
        int idx = base + i;
        if (idx < cN) { offs[idx] = prefix; prefix += count[idx]; }
    }
    if (tid == 255) offs[cN] = prefix;   // == cE
}

__global__ void scatter_kernel(const int* __restrict__ dst, int* __restrict__ cursor,
                               int* __restrict__ edge_id) {
    int i = blockIdx.x * blockDim.x + threadIdx.x;
    if (i < cE) {
        int pos = atomicAdd(&cursor[dst[i]], 1);
        edge_id[pos] = i;
    }
}

// ---------------- generic fp32 tiled GEMM ----------------
// C[M,N] = (ACCUM? C : 0) + A[M,K] @ B (+bias), optional relu.
// BT=0: B is [K,N] row-major.  BT=1: B is [N,K] row-major (i.e. C = A @ B^T).
// Requires K % 16 == 0, K % 4 == 0, 16B-aligned A/B rows (all our shapes qualify).
template<int BT, int ACT, int ACCUM>
__global__ __launch_bounds__(256)
void gemm_kernel(const float* __restrict__ A, const float* __restrict__ B,
                 const float* __restrict__ bias, float* __restrict__ C,
                 int M, int N, int K) {
    __shared__ float As[16][132];
    __shared__ float Bs[16][132];
    const int tid = threadIdx.x;
    const int bm = blockIdx.y * 128;
    const int bn = blockIdx.x * 128;
    const int tm = (tid >> 4) << 3;
    const int tn = (tid & 15) << 3;
    float acc[8][8];
#pragma unroll
    for (int i = 0; i < 8; i++)
#pragma unroll
        for (int j = 0; j < 8; j++) acc[i][j] = 0.f;

    for (int k0 = 0; k0 < K; k0 += 16) {
        // A tile: 128 rows x 16 k
#pragma unroll
        for (int i = 0; i < 2; i++) {
            int m = (tid >> 2) + (i << 6);
            int k4 = (tid & 3) << 2;
            float4 v = make_float4(0.f, 0.f, 0.f, 0.f);
            int row = bm + m;
            if (row < M) v = *reinterpret_cast<const float4*>(A + (size_t)row * K + k0 + k4);
            As[k4 + 0][m] = v.x; As[k4 + 1][m] = v.y; As[k4 + 2][m] = v.z; As[k4 + 3][m] = v.w;
        }
        if (BT) {
#pragma unroll
            for (int i = 0; i < 2; i++) {
                int n = (tid >> 2) + (i << 6);
                int k4 = (tid & 3) << 2;
                float4 v = make_float4(0.f, 0.f, 0.f, 0.f);
                int col = bn + n;
                if (col < N) v = *reinterpret_cast<const float4*>(B + (size_t)col * K + k0 + k4);
                Bs[k4 + 0][n] = v.x; Bs[k4 + 1][n] = v.y; Bs[k4 + 2][n] = v.z; Bs[k4 + 3][n] = v.w;
            }
        } else {
#pragma unroll
            for (int i = 0; i < 8; i++) {
                int idx = tid + (i << 8);
                int k = idx >> 7, n = idx & 127;
                float v = 0.f;
                if (bn + n < N) v = B[(size_t)(k0 + k) * N + bn + n];
                Bs[k][n] = v;
            }
        }
        __syncthreads();
#pragma unroll
        for (int k = 0; k < 16; k++) {
            float4 a0 = *reinterpret_cast<const float4*>(&As[k][tm]);
            float4 a1 = *reinterpret_cast<const float4*>(&As[k][tm + 4]);
            float4 b0 = *reinterpret_cast<const float4*>(&Bs[k][tn]);
            float4 b1 = *reinterpret_cast<const float4*>(&Bs[k][tn + 4]);
            float a[8] = {a0.x, a0.y, a0.z, a0.w, a1.x, a1.y, a1.z, a1.w};
            float b[8] = {b0.x, b0.y, b0.z, b0.w, b1.x, b1.y, b1.z, b1.w};
#pragma unroll
            for (int i = 0; i < 8; i++)
#pragma unroll
                for (int j = 0; j < 8; j++)
                    acc[i][j] = fmaf(a[i], b[j], acc[i][j]);
        }
        __syncthreads();
    }
#pragma unroll
    for (int i = 0; i < 8; i++) {
        int row = bm + tm + i;
        if (row >= M) break;
#pragma unroll
        for (int j = 0; j < 8; j++) {
            int col = bn + tn + j;
            if (col >= N) break;
            float v = acc[i][j];
            if (bias) v += bias[col];
            if (ACCUM) v += C[(size_t)row * N + col];
            if (ACT == 1) v = fmaxf(v, 0.f);
            C[(size_t)row * N + col] = v;
        }
    }
}

// ---------------- GAT kernels ----------------
// one wave per edge: score[e][h] = sum_c leaky(xl[src,h,c]+xr[dst,h,c]) * a[h,c]
__global__ void edge_score_kernel(const float* __restrict__ xl, const float* __restrict__ xr,
                                  const int* __restrict__ src, const int* __restrict__ dst,
                                  const float* __restrict__ att, float* __restrict__ score_e) {
    int wid = (blockIdx.x * blockDim.x + threadIdx.x) >> 6;
    int lane = threadIdx.x & 63;
    if (wid >= cE) return;
    const float* xls = xl + (size_t)src[wid] * 512;
    const float* xrd = xr + (size_t)dst[wid] * 512;
#pragma unroll
    for (int h = 0; h < 4; h++) {
        float acc = 0.f;
#pragma unroll
        for (int q = 0; q < 2; q++) {
            int c = lane + q * 64;
            float v = xls[h * 128 + c] + xrd[h * 128 + c];
            v = v > 0.f ? v : 0.2f * v;
            acc += v * att[h * 128 + c];
        }
        for (int o = 32; o; o >>= 1) acc += __shfl_xor(acc, o);
        if (lane == 0) score_e[(size_t)wid * 4 + h] = acc;
    }
}

__device__ inline void atomicMaxF(float* addr, float val) {
    int iv = __float_as_int(val);
    if (iv >= 0) atomicMax((int*)addr, iv);
    else atomicMin((unsigned int*)addr, (unsigned int)iv);
}

__global__ void seg_max_kernel(const float* __restrict__ score_e, const int* __restrict__ dst,
                               float* __restrict__ m) {
    int i = blockIdx.x * blockDim.x + threadIdx.x;
    if (i >= cE * 4) return;
    int e = i >> 2, h = i & 3;
    atomicMaxF(&m[(size_t)dst[e] * 4 + h], score_e[i]);
}

__global__ void seg_sum_kernel(float* __restrict__ score_e, const int* __restrict__ dst,
                               const float* __restrict__ m, float* __restrict__ denom) {
    int i = blockIdx.x * blockDim.x + threadIdx.x;
    if (i >= cE * 4) return;
    int e = i >> 2, h = i & 3;
    int d = dst[e];
    float ex = expf(score_e[i] - m[(size_t)d * 4 + h]);
    score_e[i] = ex;                       // overwrite with exp value
    atomicAdd(&denom[(size_t)d * 4 + h], ex);
}

// one wave per (node, head): agg[n,h,:] = sum_{e in CSR(n)} alpha_e * xl[src[e],h,:]
__global__ void aggregate_kernel(const float* __restrict__ xl, const float* __restrict__ ex,
                                 const float* __restrict__ denom, const int* __restrict__ src,
                                 const int* __restrict__ offs, const int* __restrict__ edge_id,
                                 float* __restrict__ agg) {
    int wid = (blockIdx.x * blockDim.x + threadIdx.x) >> 6;
    int lane = threadIdx.x & 63;
    if (wid >= cN * 4) return;
    int n = wid >> 2, h = wid & 3;
    float inv = 1.f / (denom[(size_t)n * 4 + h] + 1e-16f);
    int beg = offs[n], end = offs[n + 1];
    float acc0 = 0.f, acc1 = 0.f;
    for (int j = beg; j < end; j++) {
        int e = edge_id[j];
        float alpha = ex[(size_t)e * 4 + h] * inv;
        const float* xs = xl + (size_t)src[e] * 512 + h * 128;
        acc0 += alpha * xs[lane];
        acc1 += alpha * xs[lane + 64];
    }
    agg[(size_t)n * 512 + h * 128 + lane] = acc0;
    agg[(size_t)n * 512 + h * 128 + lane + 64] = acc1;
}

// one wave per node: mean over heads + conv bias, then layernorm; write h and seq[l]
__global__ void mean_ln_kernel(const float* __restrict__ agg, const float* __restrict__ conv_b,
                               const float* __restrict__ lnw, const float* __restrict__ lnb,
                               float* __restrict__ hout, float* __restrict__ seq_l) {
    int wid = (blockIdx.x * blockDim.x + threadIdx.x) >> 6;
    int lane = threadIdx.x & 63;
    if (wid >= cN) return;
    const float* a = agg + (size_t)wid * 512;
    float v0 = 0.25f * (a[lane] + a[128 + lane] + a[256 + lane] + a[384 + lane]) + conv_b[lane];
    float v1 = 0.25f * (a[64 + lane] + a[192 + lane] + a[320 + lane] + a[448 + lane]) + conv_b[64 + lane];
    float s = v0 + v1;
    for (int o = 32; o; o >>= 1) s += __shfl_xor(s, o);
    float mu = s * (1.f / 128.f);
    float d0 = v0 - mu, d1 = v1 - mu;
    float vs = d0 * d0 + d1 * d1;
    for (int o = 32; o; o >>= 1) vs += __shfl_xor(vs, o);
    float rstd = 1.f / sqrtf(vs * (1.f / 128.f) + 1e-5f);
    float o0 = d0 * rstd * lnw[lane] + lnb[lane];
    float o1 = d1 * rstd * lnw[64 + lane] + lnb[64 + lane];
    size_t b = (size_t)wid * 128;
    hout[b + lane] = o0;       hout[b + 64 + lane] = o1;
    seq_l[b + lane] = o0;      seq_l[b + 64 + lane] = o1;
}

// ---------------- LSTM kernels ----------------
__global__ void build_wcat_kernel(const float* __restrict__ Wih, const float* __restrict__ Whh,
                                  float* __restrict__ Wcat) {
    int n = blockIdx.x;
    int k = blockIdx.y * 256 + threadIdx.x;
    if (k < cKcat)
        Wcat[(size_t)n * cKcat + k] = (k < cC) ? Wih[(size_t)n * cC + k]
                                               : Whh[(size_t)n * cHL + (k - cC)];
}

__global__ void build_xcat_kernel(const float* __restrict__ seq_t, const float* __restrict__ h,
                                  float* __restrict__ xcat) {
    int n = blockIdx.x;
    int k = blockIdx.y * 256 + threadIdx.x;
    if (k < cKcat)
        xcat[(size_t)n * cKcat + k] = (k < cC) ? seq_t[(size_t)n * cC + k]
                                               : h[(size_t)n * cHL + (k - cC)];
}

__global__ void lstm_cell_kernel(const float* __restrict__ gates,
                                 const float* __restrict__ bih, const float* __restrict__ bhh,
                                 float* __restrict__ h, float* __restrict__ c) {
    int n = blockIdx.x;
    int u = blockIdx.y * 256 + threadIdx.x;
    if (u >= cHL) return;
    const float* g = gates + (size_t)n * c4HL;
    float gi = g[u]            + bih[u]            + bhh[u];
    float gf = g[cHL + u]      + bih[cHL + u]      + bhh[cHL + u];
    float gg = g[2 * cHL + u]  + bih[2 * cHL + u]  + bhh[2 * cHL + u];
    float go = g[3 * cHL + u]  + bih[3 * cHL + u]  + bhh[3 * cHL + u];
    float si = 1.f / (1.f + expf(-gi));
    float sf = 1.f / (1.f + expf(-gf));
    float so = 1.f / (1.f + expf(-go));
    float tg = tanhf(gg);
    size_t idx = (size_t)n * cHL + u;
    float cc = sf * c[idx] + si * tg;
    c[idx] = cc;
    h[idx] = so * tanhf(cc);
}

// score[t][n] += dot(h[n,:], jkw[off:off+320])
__global__ void jk_partial_kernel(const float* __restrict__ h, const float* __restrict__ jkw,
                                  int off, float* __restrict__ score_t) {
    int wid = (blockIdx.x * blockDim.x + threadIdx.x) >> 6;
    int lane = threadIdx.x & 63;
    if (wid >= cN) return;
    const float* hr = h + (size_t)wid * cHL;
    float acc = 0.f;
    for (int u = lane; u < cHL; u += 64) acc += hr[u] * jkw[off + u];
    for (int o = 32; o; o >>= 1) acc += __shfl_xor(acc, o);
    if (lane == 0) score_t[wid] += acc;
}

// ---------------- JK softmax + mean pooling ----------------
__global__ void jk_pool_kernel(const float* __restrict__ seq, const float* __restrict__ score,
                               const int* __restrict__ batch, float* __restrict__ pooled) {
    int wid = (blockIdx.x * blockDim.x + threadIdx.x) >> 6;
    int lane = threadIdx.x & 63;
    if (wid >= cN) return;
    float s[cL], mx = -INFINITY;
#pragma unroll
    for (int l = 0; l < cL; l++) { s[l] = score[(size_t)l * cN + wid]; mx = fmaxf(mx, s[l]); }
    float se = 0.f;
#pragma unroll
    for (int l = 0; l < cL; l++) { s[l] = expf(s[l] - mx); se += s[l]; }
    float inv = 1.f / se;
    int g = batch[wid];
    float acc0 = 0.f, acc1 = 0.f;
#pragma unroll
    for (int l = 0; l < cL; l++) {
        const float* sp = seq + ((size_t)l * cN + wid) * 128;
        float w = s[l] * inv;
        acc0 += w * sp[lane];
        acc1 += w * sp[lane + 64];
    }
    atomicAdd(&pooled[(size_t)g * 128 + lane], acc0);
    atomicAdd(&pooled[(size_t)g * 128 + lane + 64], acc1);
}

__global__ void count_kernel(const int* __restrict__ batch, float* __restrict__ cnt) {
    int i = blockIdx.x * blockDim.x + threadIdx.x;
    if (i < cN) atomicAdd(&cnt[batch[i]], 1.f);
}

__global__ void div_pool_kernel(float* __restrict__ pooled, const float* __restrict__ cnt) {
    int i = blockIdx.x * blockDim.x + threadIdx.x;
    if (i < cG * 128) pooled[i] /= fmaxf(cnt[i >> 7], 1.f);
}

// ---------------- launch helpers ----------------
static inline int ceil_div(long a, long b) { return (int)((a + b - 1) / b); }

template<int BT, int ACT, int ACCUM>
static void launch_gemm(const float* A, const float* B, const float* bias, float* C,
                        int M, int N, int K, hipStream_t s) {
    dim3 g(ceil_div(N, 128), ceil_div(M, 128));
    gemm_kernel<BT, ACT, ACCUM><<<g, 256, 0, s>>>(A, B, bias, C, M, N, K);
}

static void fillF(float* p, long n, float v, hipStream_t s) {
    fill_f32_kernel<<<ceil_div(n, 256), 256, 0, s>>>(p, n, v);
}
static void fillI(int* p, long n, int v, hipStream_t s) {
    fill_i32_kernel<<<ceil_div(n, 256), 256, 0, s>>>(p, n, v);
}

extern "C" void kernel_launch(void* const* d_in, const int* in_sizes, int n_in,
                              void* d_out, int out_size, void* d_ws, size_t ws_size,
                              hipStream_t stream) {
    // inputs
    const float* x      = (const float*)d_in[0];
    const int*   ei     = (const int*)d_in[1];
    const int*   batch  = (const int*)d_in[2];
    const float* emb_W  = (const float*)d_in[3];
    const float* emb_b  = (const float*)d_in[4];
    const float* Wl     = (const float*)d_in[5];
    const float* bl     = (const float*)d_in[6];
    const float* Wr     = (const float*)d_in[7];
    const float* br     = (const float*)d_in[8];
    const float* att_a  = (const float*)d_in[9];
    const float* conv_b = (const float*)d_in[10];
    const float* ln_w   = (const float*)d_in[11];
    const float* ln_b   = (const float*)d_in[12];
    const float* Wih_f  = (const float*)d_in[13];
    const float* Whh_f  = (const float*)d_in[14];
    const float* bih_f  = (const float*)d_in[15];
    const float* bhh_f  = (const float*)d_in[16];
    const float* Wih_b  = (const float*)d_in[17];
    const float* Whh_b  = (const float*)d_in[18];
    const float* bih_b  = (const float*)d_in[19];
    const float* bhh_b  = (const float*)d_in[20];
    const float* jk_w   = (const float*)d_in[21];
    // d_in[22] = jk_b: constant shift across L -> softmax-invariant, unused
    const float* m1_w   = (const float*)d_in[23];
    const float* m1_b   = (const float*)d_in[24];
    const float* m2_w   = (const float*)d_in[25];
    const float* m2_b   = (const float*)d_in[26];
    const float* res_w  = (const float*)d_in[27];
    const float* res_b  = (const float*)d_in[28];
    float* out = (float*)d_out;

    const int* src = ei;
    const int* dst = ei + cE;

    // ---------------- workspace layout (~156 MB) ----------------
    char* ws = (char*)d_ws;
    size_t off = 0;
    auto alloc = [&](size_t bytes) -> char* {
        size_t o = (off + 255) & ~(size_t)255;
        off = o + bytes;
        return ws + o;
    };
    float* h      = (float*)alloc((size_t)cN * cC * 4);
    float* seq    = (float*)alloc((size_t)cL * cN * cC * 4);
    float* Wcat_f = (float*)alloc((size_t)c4HL * cKcat * 4);
    float* Wcat_b = (float*)alloc((size_t)c4HL * cKcat * 4);
    float* hf     = (float*)alloc((size_t)cN * cHL * 4);
    float* cf     = (float*)alloc((size_t)cN * cHL * 4);
    float* hb     = (float*)alloc((size_t)cN * cHL * 4);
    float* cb     = (float*)alloc((size_t)cN * cHL * 4);
    float* jks    = (float*)alloc((size_t)cL * cN * 4);
    float* pooled = (float*)alloc((size_t)cG * cC * 4);
    float* cnt    = (float*)alloc((size_t)cG * 4);
    float* hdn    = (float*)alloc((size_t)cG * cC * 4);
    // overlapped region: GAT-phase buffers and LSTM-phase buffers share space
    size_t gat_bytes  = ((size_t)3 * cN * 512 + (size_t)cE * 4 + (size_t)2 * cN * 4) * 4
                      + ((size_t)(cN + 1) + cN + cE) * 4;
    size_t lstm_bytes = ((size_t)cN * cKcat + (size_t)cN * c4HL) * 4;
    char* region = alloc(gat_bytes > lstm_bytes ? gat_bytes : lstm_bytes);
    // GAT view
    float* xl      = (float*)region;
    float* xr      = xl + (size_t)cN * 512;
    float* agg     = xr + (size_t)cN * 512;
    float* score_e = agg + (size_t)cN * 512;
    float* mbuf    = score_e + (size_t)cE * 4;
    float* denom   = mbuf + (size_t)cN * 4;
    int*   offs    = (int*)(denom + (size_t)cN * 4);
    int*   cursor  = offs + (cN + 1);
    int*   edge_id = cursor + cN;
    // LSTM view (aliases GAT view; GAT is fully consumed before LSTM starts)
    float* xcat  = (float*)region;
    float* gates = xcat + (size_t)cN * cKcat;

    hipStream_t s = stream;

    // ---------------- CSR by dst (rebuilt every call) ----------------
    fillI(cursor, cN, 0, s);
    hist_kernel<<<ceil_div(cE, 256), 256, 0, s>>>(dst, cursor);
    scan_kernel<<<1, 256, 0, s>>>(cursor, offs);
    copy_i32_kernel<<<ceil_div(cN, 256), 256, 0, s>>>(offs, cursor, cN);
    scatter_kernel<<<ceil_div(cE, 256), 256, 0, s>>>(dst, cursor, edge_id);

    // ---------------- embedding ----------------
    launch_gemm<0, 0, 0>(x, emb_W, emb_b, h, cN, cC, cFin, s);

    // ---------------- GAT layers ----------------
    for (int l = 0; l < cL; l++) {
        launch_gemm<0, 0, 0>(h, Wl + (size_t)l * cC * 512, bl + (size_t)l * 512, xl, cN, 512, cC, s);
        launch_gemm<0, 0, 0>(h, Wr + (size_t)l * cC * 512, br + (size_t)l * 512, xr, cN, 512, cC, s);
        edge_score_kernel<<<ceil_div((long)cE * 64, 256), 256, 0, s>>>(
            xl, xr, src, dst, att_a + (size_t)l * cH * cC, score_e);
        fillF(mbuf, (long)cN * 4, -INFINITY, s);
        fillF(denom, (long)cN * 4, 0.f, s);
        seg_max_kernel<<<ceil_div((long)cE * 4, 256), 256, 0, s>>>(score_e, dst, mbuf);
        seg_sum_kernel<<<ceil_div((long)cE * 4, 256), 256, 0, s>>>(score_e, dst, mbuf, denom);
        aggregate_kernel<<<ceil_div((long)cN * 4 * 64, 256), 256, 0, s>>>(
            xl, score_e, denom, src, offs, edge_id, agg);
        mean_ln_kernel<<<ceil_div((long)cN * 64, 256), 256, 0, s>>>(
            agg, conv_b + (size_t)l * cC, ln_w + (size_t)l * cC, ln_b + (size_t)l * cC,
            h, seq + (size_t)l * cN * cC);
    }

    // ---------------- bidirectional LSTM + JK scores ----------------
    build_wcat_kernel<<<dim3(c4HL, 2), 256, 0, s>>>(Wih_f, Whh_f, Wcat_f);
    build_wcat_kernel<<<dim3(c4HL, 2), 256, 0, s>>>(Wih_b, Whh_b, Wcat_b);
    fillF(hf, (long)cN * cHL, 0.f, s);
    fillF(cf, (long)cN * cHL, 0.f, s);
    fillF(hb, (long)cN * cHL, 0.f, s);
    fillF(cb, (long)cN * cHL, 0.f, s);
    fillF(jks, (long)cL * cN, 0.f, s);

    for (int k = 0; k < cL; k++) {
        // forward step: t = k
        build_xcat_kernel<<<dim3(cN, 2), 256, 0, s>>>(seq + (size_t)k * cN * cC, hf, xcat);
        launch_gemm<1, 0, 0>(xcat, Wcat_f, nullptr, gates, cN, c4HL, cKcat, s);
        lstm_cell_kernel<<<dim3(cN, 2), 256, 0, s>>>(gates, bih_f, bhh_f, hf, cf);
        jk_partial_kernel<<<ceil_div((long)cN * 64, 256), 256, 0, s>>>(hf, jk_w, 0, jks + (size_t)k * cN);
        // backward step: t = L-1-k
        int t = cL - 1 - k;
        build_xcat_kernel<<<dim3(cN, 2), 256, 0, s>>>(seq + (size_t)t * cN * cC, hb, xcat);
        launch_gemm<1, 0, 0>(xcat, Wcat_b, nullptr, gates, cN, c4HL, cKcat, s);
        lstm_cell_kernel<<<dim3(cN, 2), 256, 0, s>>>(gates, bih_b, bhh_b, hb, cb);
        jk_partial_kernel<<<ceil_div((long)cN * 64, 256), 256, 0, s>>>(hb, jk_w, cHL, jks + (size_t)t * cN);
    }

    // ---------------- JK softmax, pooling, MLP head ----------------
    fillF(pooled, (long)cG * cC, 0.f, s);
    fillF(cnt, cG, 0.f, s);
    jk_pool_kernel<<<ceil_div((long)cN * 64, 256), 256, 0, s>>>(seq, jks, batch, pooled);
    count_kernel<<<ceil_div(cN, 256), 256, 0, s>>>(batch, cnt);
    div_pool_kernel<<<ceil_div((long)cG * 128, 256), 256, 0, s>>>(pooled, cnt);
    launch_gemm<0, 1, 0>(pooled, m1_w, m1_b, hdn, cG, cC, cC, s);
    launch_gemm<0, 0, 0>(hdn, m2_w, m2_b, out, cG, cOUT, cC, s);
    launch_gemm<0, 0, 1>(pooled, res_w, res_b, out, cG, cOUT, cC, s);
}

// Round 2
// 1670.261 us; speedup vs baseline: 2.3324x; 2.3324x over previous
//
#include <hip/hip_runtime.h>
#include <hip/hip_bf16.h>
#include <math.h>

// Problem constants (from reference)
constexpr int cN   = 10000;
constexpr int cE   = 120000;
constexpr int cFin = 64;
constexpr int cC   = 128;
constexpr int cH   = 4;
constexpr int cL   = 5;
constexpr int cG   = 500;
constexpr int cOUT = 1801;
constexpr int cHL  = 320;          // (L*C)/2
constexpr int c4HL = 4 * cHL;      // 1280

typedef short bf16x8 __attribute__((ext_vector_type(8)));
typedef float f32x4 __attribute__((ext_vector_type(4)));

__device__ inline unsigned short f2b(float x) {
    union { __hip_bfloat16 h; unsigned short u; } cv;
    cv.h = __float2bfloat16(x);
    return cv.u;
}

#define GLD16(g, l) __builtin_amdgcn_global_load_lds( \
    (const __attribute__((address_space(1))) unsigned int*)(g), \
    (__attribute__((address_space(3))) unsigned int*)(l), 16, 0, 0)

// ---------------- utility kernels ----------------
__global__ void fill_f32_kernel(float* __restrict__ p, long n, float v) {
    long i = (long)blockIdx.x * blockDim.x + threadIdx.x;
    if (i < n) p[i] = v;
}
__global__ void fill_i32_kernel(int* __restrict__ p, long n, int v) {
    long i = (long)blockIdx.x * blockDim.x + threadIdx.x;
    if (i < n) p[i] = v;
}
__global__ void copy_i32_kernel(const int* __restrict__ a, int* __restrict__ b, long n) {
    long i = (long)blockIdx.x * blockDim.x + threadIdx.x;
    if (i < n) b[i] = a[i];
}
__global__ void conv_bf16_kernel(const float* __restrict__ a, unsigned short* __restrict__ b, long n) {
    long i = (long)blockIdx.x * blockDim.x + threadIdx.x;
    if (i < n) b[i] = f2b(a[i]);
}
// W: [L][128][512] fp32  ->  WT: [L][512][128] bf16
__global__ void wproj_prep_kernel(const float* __restrict__ W, unsigned short* __restrict__ WT) {
    long i = (long)blockIdx.x * blockDim.x + threadIdx.x;
    if (i >= (long)cL * 512 * 128) return;
    int k = i & 127;
    int n = (int)((i >> 7) & 511);
    int l = (int)(i >> 16);
    WT[i] = f2b(W[(size_t)l * 65536 + (size_t)k * 512 + n]);
}
__global__ void fill_md_kernel(float* __restrict__ mbuf, float* __restrict__ denom) {
    int i = blockIdx.x * blockDim.x + threadIdx.x;
    if (i < cN * 4) { mbuf[i] = -INFINITY; denom[i] = 0.f; }
}

// ---------------- CSR build (by dst) ----------------
__global__ void hist_kernel(const int* __restrict__ dst, int* __restrict__ count) {
    int i = blockIdx.x * blockDim.x + threadIdx.x;
    if (i < cE) atomicAdd(&count[dst[i]], 1);
}
__global__ void scan_kernel(const int* __restrict__ count, int* __restrict__ offs) {
    __shared__ int part[256];
    const int tid = threadIdx.x;
    const int CH = (cN + 255) / 256;
    int base = tid * CH;
    int s = 0;
    for (int i = 0; i < CH; i++) {
        int idx = base + i;
        if (idx < cN) s += count[idx];
    }
    part[tid] = s;
    __syncthreads();
    for (int d = 1; d < 256; d <<= 1) {
        int v = 0;
        if (tid >= d) v = part[tid - d];
        __syncthreads();
        if (tid >= d) part[tid] += v;
        __syncthreads();
    }
    int prefix = (tid == 0) ? 0 : part[tid - 1];
    for (int i = 0; i < CH; i++) {
        int idx = base + i;
        if (idx < cN) { offs[idx] = prefix; prefix += count[idx]; }
    }
    if (tid == 255) offs[cN] = prefix;
}
__global__ void scatter_kernel(const int* __restrict__ dst, int* __restrict__ cursor,
                               int* __restrict__ edge_id) {
    int i = blockIdx.x * blockDim.x + threadIdx.x;
    if (i < cE) {
        int pos = atomicAdd(&cursor[dst[i]], 1);
        edge_id[pos] = i;
    }
}

// ---------------- bf16 MFMA GEMM ----------------
// C[M,N] = A@B^T (+bias). A = [A1|A2] rows of k1+k2 bf16; B = [B1|B2] rows [N][k].
// 128x128 tile, BK=32, 4 waves (2x2 of 64x64), mfma_f32_16x16x32_bf16.
// A/B fragments use identical symmetric lane->k mapping (k-permutation-safe).
// C/D mapping (m89-verified): n = lane&15, m = (lane>>4)*4 + reg.
template<int HASBIAS>
__global__ __launch_bounds__(256)
void gemm_mfma_kernel(const unsigned short* __restrict__ A1, const unsigned short* __restrict__ B1, int k1,
                      const unsigned short* __restrict__ A2, const unsigned short* __restrict__ B2, int k2,
                      const float* __restrict__ bias, float* __restrict__ C, int M, int N) {
    __shared__ unsigned short lds[2][2][128 * 32];
    const int tid  = threadIdx.x;
    const int lane = tid & 63;
    const int wave = tid >> 6;
    const int bm = blockIdx.y << 7;
    const int bn = blockIdx.x << 7;
    const int wr = (wave >> 1) << 6;
    const int wc = (wave & 1) << 6;
    const int ns1 = k1 >> 5, ns2 = k2 >> 5, ns = ns1 + ns2;

    const int lrow = lane >> 2;         // row within 16-row chunk
    const int lke  = (lane & 3) << 3;   // k-elem offset 0,8,16,24

    auto stage = [&](int s, int buf) {
        const unsigned short *Ab, *Bb;
        int stride, koff;
        if (s < ns1) { Ab = A1; Bb = B1; stride = k1; koff = s << 5; }
        else         { Ab = A2; Bb = B2; stride = k2; koff = (s - ns1) << 5; }
#pragma unroll
        for (int r = 0; r < 2; r++) {
            int ch  = wave * 2 + r;
            int row = ch * 16 + lrow;
            int ga  = bm + row; if (ga >= M) ga = M - 1;   // clamp (stores masked)
            GLD16(Ab + (size_t)ga * stride + koff + lke, &lds[buf][0][ch * 512]);
            GLD16(Bb + (size_t)(bn + row) * stride + koff + lke, &lds[buf][1][ch * 512]);
        }
    };

    f32x4 acc[4][4];
#pragma unroll
    for (int i = 0; i < 4; i++)
#pragma unroll
        for (int j = 0; j < 4; j++) acc[i][j] = (f32x4){0.f, 0.f, 0.f, 0.f};

    stage(0, 0);
    const int ko  = (lane >> 4) << 3;   // frag k-elem offset (symmetric A/B)
    const int rla = lane & 15;
    for (int s = 0; s < ns; s++) {
        int buf = s & 1;
        __syncthreads();                 // staged(s) visible; prev reads drained
        if (s + 1 < ns) stage(s + 1, buf ^ 1);
        bf16x8 af[4], bff[4];
#pragma unroll
        for (int f = 0; f < 4; f++) {
            af[f]  = *(const bf16x8*)&lds[buf][0][(wr + f * 16 + rla) * 32 + ko];
            bff[f] = *(const bf16x8*)&lds[buf][1][(wc + f * 16 + rla) * 32 + ko];
        }
#pragma unroll
        for (int i = 0; i < 4; i++)
#pragma unroll
            for (int j = 0; j < 4; j++)
                acc[i][j] = __builtin_amdgcn_mfma_f32_16x16x32_bf16(af[i], bff[j], acc[i][j], 0, 0, 0);
    }

#pragma unroll
    for (int i = 0; i < 4; i++) {
#pragma unroll
        for (int v = 0; v < 4; v++) {
            int m = bm + wr + i * 16 + ((lane >> 4) << 2) + v;
            if (m < M) {
#pragma unroll
                for (int j = 0; j < 4; j++) {
                    int n = bn + wc + j * 16 + rla;
                    float val = acc[i][j][v];
                    if (HASBIAS) val += bias[n];
                    C[(size_t)m * N + n] = val;
                }
            }
        }
    }
}

// ---------------- fp32 tiled GEMM (small shapes: embedding + head) ----------------
template<int ACT, int ACCUM>
__global__ __launch_bounds__(256)
void gemm_kernel(const float* __restrict__ A, const float* __restrict__ B,
                 const float* __restrict__ bias, float* __restrict__ C,
                 int M, int N, int K) {
    __shared__ float As[16][132];
    __shared__ float Bs[16][132];
    const int tid = threadIdx.x;
    const int bm = blockIdx.y * 128;
    const int bn = blockIdx.x * 128;
    const int tm = (tid >> 4) << 3;
    const int tn = (tid & 15) << 3;
    float acc[8][8];
#pragma unroll
    for (int i = 0; i < 8; i++)
#pragma unroll
        for (int j = 0; j < 8; j++) acc[i][j] = 0.f;

    for (int k0 = 0; k0 < K; k0 += 16) {
#pragma unroll
        for (int i = 0; i < 2; i++) {
            int m = (tid >> 2) + (i << 6);
            int k4 = (tid & 3) << 2;
            float4 v = make_float4(0.f, 0.f, 0.f, 0.f);
            int row = bm + m;
            if (row < M) v = *reinterpret_cast<const float4*>(A + (size_t)row * K + k0 + k4);
            As[k4 + 0][m] = v.x; As[k4 + 1][m] = v.y; As[k4 + 2][m] = v.z; As[k4 + 3][m] = v.w;
        }
#pragma unroll
        for (int i = 0; i < 8; i++) {
            int idx = tid + (i << 8);
            int k = idx >> 7, n = idx & 127;
            float v = 0.f;
            if (bn + n < N) v = B[(size_t)(k0 + k) * N + bn + n];
            Bs[k][n] = v;
        }
        __syncthreads();
#pragma unroll
        for (int k = 0; k < 16; k++) {
            float4 a0 = *reinterpret_cast<const float4*>(&As[k][tm]);
            float4 a1 = *reinterpret_cast<const float4*>(&As[k][tm + 4]);
            float4 b0 = *reinterpret_cast<const float4*>(&Bs[k][tn]);
            float4 b1 = *reinterpret_cast<const float4*>(&Bs[k][tn + 4]);
            float a[8] = {a0.x, a0.y, a0.z, a0.w, a1.x, a1.y, a1.z, a1.w};
            float b[8] = {b0.x, b0.y, b0.z, b0.w, b1.x, b1.y, b1.z, b1.w};
#pragma unroll
            for (int i = 0; i < 8; i++)
#pragma unroll
                for (int j = 0; j < 8; j++)
                    acc[i][j] = fmaf(a[i], b[j], acc[i][j]);
        }
        __syncthreads();
    }
#pragma unroll
    for (int i = 0; i < 8; i++) {
        int row = bm + tm + i;
        if (row >= M) break;
#pragma unroll
        for (int j = 0; j < 8; j++) {
            int col = bn + tn + j;
            if (col >= N) break;
            float v = acc[i][j];
            if (bias) v += bias[col];
            if (ACCUM) v += C[(size_t)row * N + col];
            if (ACT == 1) v = fmaxf(v, 0.f);
            C[(size_t)row * N + col] = v;
        }
    }
}

// ---------------- GAT kernels ----------------
__global__ void edge_score_kernel(const float* __restrict__ xl, const float* __restrict__ xr,
                                  const int* __restrict__ src, const int* __restrict__ dst,
                                  const float* __restrict__ att, float* __restrict__ score_e) {
    int wid = (blockIdx.x * blockDim.x + threadIdx.x) >> 6;
    int lane = threadIdx.x & 63;
    if (wid >= cE) return;
    const float* xls = xl + (size_t)src[wid] * 512;
    const float* xrd = xr + (size_t)dst[wid] * 512;
#pragma unroll
    for (int h = 0; h < 4; h++) {
        float acc = 0.f;
#pragma unroll
        for (int q = 0; q < 2; q++) {
            int c = lane + q * 64;
            float v = xls[h * 128 + c] + xrd[h * 128 + c];
            v = v > 0.f ? v : 0.2f * v;
            acc += v * att[h * 128 + c];
        }
        for (int o = 32; o; o >>= 1) acc += __shfl_xor(acc, o);
        if (lane == 0) score_e[(size_t)wid * 4 + h] = acc;
    }
}

__device__ inline void atomicMaxF(float* addr, float val) {
    int iv = __float_as_int(val);
    if (iv >= 0) atomicMax((int*)addr, iv);
    else atomicMin((unsigned int*)addr, (unsigned int)iv);
}

__global__ void seg_max_kernel(const float* __restrict__ score_e, const int* __restrict__ dst,
                               float* __restrict__ m) {
    int i = blockIdx.x * blockDim.x + threadIdx.x;
    if (i >= cE * 4) return;
    int e = i >> 2, h = i & 3;
    atomicMaxF(&m[(size_t)dst[e] * 4 + h], score_e[i]);
}

__global__ void seg_sum_kernel(float* __restrict__ score_e, const int* __restrict__ dst,
                               const float* __restrict__ m, float* __restrict__ denom) {
    int i = blockIdx.x * blockDim.x + threadIdx.x;
    if (i >= cE * 4) return;
    int e = i >> 2, h = i & 3;
    int d = dst[e];
    float ex = expf(score_e[i] - m[(size_t)d * 4 + h]);
    score_e[i] = ex;
    atomicAdd(&denom[(size_t)d * 4 + h], ex);
}

__global__ void aggregate_kernel(const float* __restrict__ xl, const float* __restrict__ ex,
                                 const float* __restrict__ denom, const int* __restrict__ src,
                                 const int* __restrict__ offs, const int* __restrict__ edge_id,
                                 float* __restrict__ agg) {
    int wid = (blockIdx.x * blockDim.x + threadIdx.x) >> 6;
    int lane = threadIdx.x & 63;
    if (wid >= cN * 4) return;
    int n = wid >> 2, h = wid & 3;
    float inv = 1.f / (denom[(size_t)n * 4 + h] + 1e-16f);
    int beg = offs[n], end = offs[n + 1];
    float acc0 = 0.f, acc1 = 0.f;
    for (int j = beg; j < end; j++) {
        int e = edge_id[j];
        float alpha = ex[(size_t)e * 4 + h] * inv;
        const float* xs = xl + (size_t)src[e] * 512 + h * 128;
        acc0 += alpha * xs[lane];
        acc1 += alpha * xs[lane + 64];
    }
    agg[(size_t)n * 512 + h * 128 + lane] = acc0;
    agg[(size_t)n * 512 + h * 128 + lane + 64] = acc1;
}

// mean over heads + conv bias + layernorm; write seq fp32 and seq bf16
__global__ void mean_ln_kernel(const float* __restrict__ agg, const float* __restrict__ conv_b,
                               const float* __restrict__ lnw, const float* __restrict__ lnb,
                               float* __restrict__ seq_l, unsigned short* __restrict__ seqb_l) {
    int wid = (blockIdx.x * blockDim.x + threadIdx.x) >> 6;
    int lane = threadIdx.x & 63;
    if (wid >= cN) return;
    const float* a = agg + (size_t)wid * 512;
    float v0 = 0.25f * (a[lane] + a[128 + lane] + a[256 + lane] + a[384 + lane]) + conv_b[lane];
    float v1 = 0.25f * (a[64 + lane] + a[192 + lane] + a[320 + lane] + a[448 + lane]) + conv_b[64 + lane];
    float s = v0 + v1;
    for (int o = 32; o; o >>= 1) s += __shfl_xor(s, o);
    float mu = s * (1.f / 128.f);
    float d0 = v0 - mu, d1 = v1 - mu;
    float vs = d0 * d0 + d1 * d1;
    for (int o = 32; o; o >>= 1) vs += __shfl_xor(vs, o);
    float rstd = 1.f / sqrtf(vs * (1.f / 128.f) + 1e-5f);
    float o0 = d0 * rstd * lnw[lane] + lnb[lane];
    float o1 = d1 * rstd * lnw[64 + lane] + lnb[64 + lane];
    size_t b = (size_t)wid * 128;
    seq_l[b + lane] = o0;        seq_l[b + 64 + lane] = o1;
    seqb_l[b + lane] = f2b(o0);  seqb_l[b + 64 + lane] = f2b(o1);
}

// ---------------- fused LSTM cell + JK partial score ----------------
// one wave per node; lane handles u = lane + q*64, q=0..4 (HL=320)
__global__ void lstm_cell_fused_kernel(const float* __restrict__ gates,
                                       const float* __restrict__ bih, const float* __restrict__ bhh,
                                       float* __restrict__ c, unsigned short* __restrict__ hb16,
                                       const float* __restrict__ jkw, int jkoff,
                                       float* __restrict__ score_t, int first) {
    int wid = (blockIdx.x * blockDim.x + threadIdx.x) >> 6;
    int lane = threadIdx.x & 63;
    if (wid >= cN) return;
    const float* g = gates + (size_t)wid * c4HL;
    float jacc = 0.f;
#pragma unroll
    for (int q = 0; q < 5; q++) {
        int u = lane + (q << 6);
        float gi  = g[u]            + bih[u]            + bhh[u];
        float gf_ = g[cHL + u]      + bih[cHL + u]      + bhh[cHL + u];
        float gg  = g[2 * cHL + u]  + bih[2 * cHL + u]  + bhh[2 * cHL + u];
        float go  = g[3 * cHL + u]  + bih[3 * cHL + u]  + bhh[3 * cHL + u];
        float si = 1.f / (1.f + expf(-gi));
        float sf = 1.f / (1.f + expf(-gf_));
        float so = 1.f / (1.f + expf(-go));
        float tg = tanhf(gg);
        size_t idx = (size_t)wid * cHL + u;
        float cold = first ? 0.f : c[idx];
        float cc = sf * cold + si * tg;
        c[idx] = cc;
        float hh = so * tanhf(cc);
        hb16[idx] = f2b(hh);
        jacc += hh * jkw[jkoff + u];
    }
    for (int o = 32; o; o >>= 1) jacc += __shfl_xor(jacc, o);
    if (lane == 0) score_t[wid] += jacc;
}

// ---------------- JK softmax + mean pooling ----------------
__global__ void jk_pool_kernel(const float* __restrict__ seq, const float* __restrict__ score,
                               const int* __restrict__ batch, float* __restrict__ pooled) {
    int wid = (blockIdx.x * blockDim.x + threadIdx.x) >> 6;
    int lane = threadIdx.x & 63;
    if (wid >= cN) return;
    float s[cL], mx = -INFINITY;
#pragma unroll
    for (int l = 0; l < cL; l++) { s[l] = score[(size_t)l * cN + wid]; mx = fmaxf(mx, s[l]); }
    float se = 0.f;
#pragma unroll
    for (int l = 0; l < cL; l++) { s[l] = expf(s[l] - mx); se += s[l]; }
    float inv = 1.f / se;
    int g = batch[wid];
    float acc0 = 0.f, acc1 = 0.f;
#pragma unroll
    for (int l = 0; l < cL; l++) {
        const float* sp = seq + ((size_t)l * cN + wid) * 128;
        float w = s[l] * inv;
        acc0 += w * sp[lane];
        acc1 += w * sp[lane + 64];
    }
    atomicAdd(&pooled[(size_t)g * 128 + lane], acc0);
    atomicAdd(&pooled[(size_t)g * 128 + lane + 64], acc1);
}

__global__ void count_kernel(const int* __restrict__ batch, float* __restrict__ cnt) {
    int i = blockIdx.x * blockDim.x + threadIdx.x;
    if (i < cN) atomicAdd(&cnt[batch[i]], 1.f);
}

__global__ void div_pool_kernel(float* __restrict__ pooled, const float* __restrict__ cnt) {
    int i = blockIdx.x * blockDim.x + threadIdx.x;
    if (i < cG * 128) pooled[i] /= fmaxf(cnt[i >> 7], 1.f);
}

// ---------------- launch helpers ----------------
static inline int ceil_div(long a, long b) { return (int)((a + b - 1) / b); }

template<int ACT, int ACCUM>
static void launch_gemm(const float* A, const float* B, const float* bias, float* C,
                        int M, int N, int K, hipStream_t s) {
    dim3 g(ceil_div(N, 128), ceil_div(M, 128));
    gemm_kernel<ACT, ACCUM><<<g, 256, 0, s>>>(A, B, bias, C, M, N, K);
}

static void launch_mfma(const unsigned short* A1, const unsigned short* B1, int k1,
                        const unsigned short* A2, const unsigned short* B2, int k2,
                        const float* bias, float* C, int M, int N, hipStream_t s) {
    dim3 g(N >> 7, (M + 127) >> 7);
    if (bias) gemm_mfma_kernel<1><<<g, 256, 0, s>>>(A1, B1, k1, A2, B2, k2, bias, C, M, N);
    else      gemm_mfma_kernel<0><<<g, 256, 0, s>>>(A1, B1, k1, A2, B2, k2, bias, C, M, N);
}

static void fillF(float* p, long n, float v, hipStream_t s) {
    fill_f32_kernel<<<ceil_div(n, 256), 256, 0, s>>>(p, n, v);
}
static void fillI(int* p, long n, int v, hipStream_t s) {
    fill_i32_kernel<<<ceil_div(n, 256), 256, 0, s>>>(p, n, v);
}
static void convB(const float* a, unsigned short* b, long n, hipStream_t s) {
    conv_bf16_kernel<<<ceil_div(n, 256), 256, 0, s>>>(a, b, n);
}

extern "C" void kernel_launch(void* const* d_in, const int* in_sizes, int n_in,
                              void* d_out, int out_size, void* d_ws, size_t ws_size,
                              hipStream_t stream) {
    const float* x      = (const float*)d_in[0];
    const int*   ei     = (const int*)d_in[1];
    const int*   batch  = (const int*)d_in[2];
    const float* emb_W  = (const float*)d_in[3];
    const float* emb_b  = (const float*)d_in[4];
    const float* Wl     = (const float*)d_in[5];
    const float* bl     = (const float*)d_in[6];
    const float* Wr     = (const float*)d_in[7];
    const float* br     = (const float*)d_in[8];
    const float* att_a  = (const float*)d_in[9];
    const float* conv_b = (const float*)d_in[10];
    const float* ln_w   = (const float*)d_in[11];
    const float* ln_b   = (const float*)d_in[12];
    const float* Wih_f  = (const float*)d_in[13];
    const float* Whh_f  = (const float*)d_in[14];
    const float* bih_f  = (const float*)d_in[15];
    const float* bhh_f  = (const float*)d_in[16];
    const float* Wih_b  = (const float*)d_in[17];
    const float* Whh_b  = (const float*)d_in[18];
    const float* bih_b  = (const float*)d_in[19];
    const float* bhh_b  = (const float*)d_in[20];
    const float* jk_w   = (const float*)d_in[21];
    // d_in[22] = jk_b: constant across L -> softmax-invariant, unused
    const float* m1_w   = (const float*)d_in[23];
    const float* m1_b   = (const float*)d_in[24];
    const float* m2_w   = (const float*)d_in[25];
    const float* m2_b   = (const float*)d_in[26];
    const float* res_w  = (const float*)d_in[27];
    const float* res_b  = (const float*)d_in[28];
    float* out = (float*)d_out;

    const int* src = ei;
    const int* dst = ei + cE;

    // ---------------- workspace layout (~150 MB) ----------------
    char* ws = (char*)d_ws;
    size_t off = 0;
    auto alloc = [&](size_t bytes) -> char* {
        size_t o = (off + 255) & ~(size_t)255;
        off = o + bytes;
        return ws + o;
    };
    float*          h       = (float*)alloc((size_t)cN * cC * 4);          // embedding out fp32
    unsigned short* emb_b16 = (unsigned short*)alloc((size_t)cN * cC * 2); // embedding out bf16
    float*          seq     = (float*)alloc((size_t)cL * cN * cC * 4);
    unsigned short* seqb16  = (unsigned short*)alloc((size_t)cL * cN * cC * 2);
    unsigned short* WlT     = (unsigned short*)alloc((size_t)cL * 512 * 128 * 2);
    unsigned short* WrT     = (unsigned short*)alloc((size_t)cL * 512 * 128 * 2);
    unsigned short* Wihf16  = (unsigned short*)alloc((size_t)c4HL * cC * 2);
    unsigned short* Whhf16  = (unsigned short*)alloc((size_t)c4HL * cHL * 2);
    unsigned short* Wihb16  = (unsigned short*)alloc((size_t)c4HL * cC * 2);
    unsigned short* Whhb16  = (unsigned short*)alloc((size_t)c4HL * cHL * 2);
    unsigned short* hf16    = (unsigned short*)alloc((size_t)cN * cHL * 2);
    unsigned short* hb16    = (unsigned short*)alloc((size_t)cN * cHL * 2);
    float*          cf      = (float*)alloc((size_t)cN * cHL * 4);
    float*          cb      = (float*)alloc((size_t)cN * cHL * 4);
    float*          jks     = (float*)alloc((size_t)cL * cN * 4);
    float*          pooled  = (float*)alloc((size_t)cG * cC * 4);
    float*          cnt     = (float*)alloc((size_t)cG * 4);
    float*          hdn     = (float*)alloc((size_t)cG * cC * 4);
    // overlapped region: GAT-phase buffers / LSTM gates share space
    size_t gat_bytes  = ((size_t)3 * cN * 512 + (size_t)cE * 4 + (size_t)2 * cN * 4) * 4
                      + ((size_t)(cN + 1) + cN + cE) * 4;
    size_t lstm_bytes = (size_t)cN * c4HL * 4;
    char* region = alloc(gat_bytes > lstm_bytes ? gat_bytes : lstm_bytes);
    float* xl      = (float*)region;
    float* xr      = xl + (size_t)cN * 512;
    float* agg     = xr + (size_t)cN * 512;
    float* score_e = agg + (size_t)cN * 512;
    float* mbuf    = score_e + (size_t)cE * 4;
    float* denom   = mbuf + (size_t)cN * 4;
    int*   offs    = (int*)(denom + (size_t)cN * 4);
    int*   cursor  = offs + (cN + 1);
    int*   edge_id = cursor + cN;
    float* gates   = (float*)region;   // LSTM view (GAT fully consumed first)

    hipStream_t s = stream;

    // ---------------- CSR by dst ----------------
    fillI(cursor, cN, 0, s);
    hist_kernel<<<ceil_div(cE, 256), 256, 0, s>>>(dst, cursor);
    scan_kernel<<<1, 256, 0, s>>>(cursor, offs);
    copy_i32_kernel<<<ceil_div(cN, 256), 256, 0, s>>>(offs, cursor, cN);
    scatter_kernel<<<ceil_div(cE, 256), 256, 0, s>>>(dst, cursor, edge_id);

    // ---------------- weight prep (bf16) ----------------
    wproj_prep_kernel<<<ceil_div((long)cL * 512 * 128, 256), 256, 0, s>>>(Wl, WlT);
    wproj_prep_kernel<<<ceil_div((long)cL * 512 * 128, 256), 256, 0, s>>>(Wr, WrT);
    convB(Wih_f, Wihf16, (long)c4HL * cC, s);
    convB(Whh_f, Whhf16, (long)c4HL * cHL, s);
    convB(Wih_b, Wihb16, (long)c4HL * cC, s);
    convB(Whh_b, Whhb16, (long)c4HL * cHL, s);

    // ---------------- embedding ----------------
    launch_gemm<0, 0>(x, emb_W, emb_b, h, cN, cC, cFin, s);
    convB(h, emb_b16, (long)cN * cC, s);

    // ---------------- GAT layers (bf16 MFMA projections) ----------------
    for (int l = 0; l < cL; l++) {
        const unsigned short* hin = (l == 0) ? emb_b16 : seqb16 + (size_t)(l - 1) * cN * cC;
        launch_mfma(hin, WlT + (size_t)l * 512 * 128, cC, nullptr, nullptr, 0,
                    bl + (size_t)l * 512, xl, cN, 512, s);
        launch_mfma(hin, WrT + (size_t)l * 512 * 128, cC, nullptr, nullptr, 0,
                    br + (size_t)l * 512, xr, cN, 512, s);
        edge_score_kernel<<<ceil_div((long)cE * 64, 256), 256, 0, s>>>(
            xl, xr, src, dst, att_a + (size_t)l * cH * cC, score_e);
        fill_md_kernel<<<ceil_div((long)cN * 4, 256), 256, 0, s>>>(mbuf, denom);
        seg_max_kernel<<<ceil_div((long)cE * 4, 256), 256, 0, s>>>(score_e, dst, mbuf);
        seg_sum_kernel<<<ceil_div((long)cE * 4, 256), 256, 0, s>>>(score_e, dst, mbuf, denom);
        aggregate_kernel<<<ceil_div((long)cN * 4 * 64, 256), 256, 0, s>>>(
            xl, score_e, denom, src, offs, edge_id, agg);
        mean_ln_kernel<<<ceil_div((long)cN * 64, 256), 256, 0, s>>>(
            agg, conv_b + (size_t)l * cC, ln_w + (size_t)l * cC, ln_b + (size_t)l * cC,
            seq + (size_t)l * cN * cC, seqb16 + (size_t)l * cN * cC);
    }

    // ---------------- bidirectional LSTM + JK scores ----------------
    fillF(jks, (long)cL * cN, 0.f, s);
    for (int k = 0; k < cL; k++) {
        int first = (k == 0);
        // forward step: t = k
        launch_mfma(seqb16 + (size_t)k * cN * cC, Wihf16, cC,
                    hf16, Whhf16, first ? 0 : cHL, nullptr, gates, cN, c4HL, s);
        lstm_cell_fused_kernel<<<ceil_div((long)cN * 64, 256), 256, 0, s>>>(
            gates, bih_f, bhh_f, cf, hf16, jk_w, 0, jks + (size_t)k * cN, first);
        // backward step: t = L-1-k
        int t = cL - 1 - k;
        launch_mfma(seqb16 + (size_t)t * cN * cC, Wihb16, cC,
                    hb16, Whhb16, first ? 0 : cHL, nullptr, gates, cN, c4HL, s);
        lstm_cell_fused_kernel<<<ceil_div((long)cN * 64, 256), 256, 0, s>>>(
            gates, bih_b, bhh_b, cb, hb16, jk_w, cHL, jks + (size_t)t * cN, first);
    }

    // ---------------- JK softmax, pooling, MLP head ----------------
    fillF(pooled, (long)cG * cC, 0.f, s);
    fillF(cnt, cG, 0.f, s);
    jk_pool_kernel<<<ceil_div((long)cN * 64, 256), 256, 0, s>>>(seq, jks, batch, pooled);
    count_kernel<<<ceil_div(cN, 256), 256, 0, s>>>(batch, cnt);
    div_pool_kernel<<<ceil_div((long)cG * 128, 256), 256, 0, s>>>(pooled, cnt);
    launch_gemm<1, 0>(pooled, m1_w, m1_b, hdn, cG, cC, cC, s);
    launch_gemm<0, 0>(hdn, m2_w, m2_b, out, cG, cOUT, cC, s);
    launch_gemm<0, 1>(pooled, res_w, res_b, out, cG, cOUT, cC, s);
}

// Round 3
// 1233.913 us; speedup vs baseline: 3.1572x; 1.3536x over previous
//
#include <hip/hip_runtime.h>
#include <hip/hip_bf16.h>
#include <math.h>

// Problem constants (from reference)
constexpr int cN   = 10000;
constexpr int cE   = 120000;
constexpr int cFin = 64;
constexpr int cC   = 128;
constexpr int cH   = 4;
constexpr int cL   = 5;
constexpr int cG   = 500;
constexpr int cOUT = 1801;
constexpr int cHL  = 320;          // (L*C)/2
constexpr int c4HL = 4 * cHL;      // 1280

typedef short bf16x8 __attribute__((ext_vector_type(8)));
typedef float f32x4 __attribute__((ext_vector_type(4)));

__device__ inline unsigned short f2b(float x) {
    union { __hip_bfloat16 h; unsigned short u; } cv;
    cv.h = __float2bfloat16(x);
    return cv.u;
}

#define GLD16(g, l) __builtin_amdgcn_global_load_lds( \
    (const __attribute__((address_space(1))) unsigned int*)(g), \
    (__attribute__((address_space(3))) unsigned int*)(l), 16, 0, 0)

// ---------------- utility kernels ----------------
__global__ void fill_f32_kernel(float* __restrict__ p, long n, float v) {
    long i = (long)blockIdx.x * blockDim.x + threadIdx.x;
    if (i < n) p[i] = v;
}
__global__ void fill_i32_kernel(int* __restrict__ p, long n, int v) {
    long i = (long)blockIdx.x * blockDim.x + threadIdx.x;
    if (i < n) p[i] = v;
}
__global__ void copy_i32_kernel(const int* __restrict__ a, int* __restrict__ b, long n) {
    long i = (long)blockIdx.x * blockDim.x + threadIdx.x;
    if (i < n) b[i] = a[i];
}
__global__ void conv_bf16_kernel(const float* __restrict__ a, unsigned short* __restrict__ b, long n) {
    long i = (long)blockIdx.x * blockDim.x + threadIdx.x;
    if (i < n) b[i] = f2b(a[i]);
}
// W: [L][128][512] fp32  ->  WT: [L][512][128] bf16
__global__ void wproj_prep_kernel(const float* __restrict__ W, unsigned short* __restrict__ WT) {
    long i = (long)blockIdx.x * blockDim.x + threadIdx.x;
    if (i >= (long)cL * 512 * 128) return;
    int k = i & 127;
    int n = (int)((i >> 7) & 511);
    int l = (int)(i >> 16);
    WT[i] = f2b(W[(size_t)l * 65536 + (size_t)k * 512 + n]);
}

// ---------------- CSR build (by dst) ----------------
__global__ void hist_kernel(const int* __restrict__ dst, int* __restrict__ count) {
    int i = blockIdx.x * blockDim.x + threadIdx.x;
    if (i < cE) atomicAdd(&count[dst[i]], 1);
}
__global__ void scan_kernel(const int* __restrict__ count, int* __restrict__ offs) {
    __shared__ int part[256];
    const int tid = threadIdx.x;
    const int CH = (cN + 255) / 256;
    int base = tid * CH;
    int s = 0;
    for (int i = 0; i < CH; i++) {
        int idx = base + i;
        if (idx < cN) s += count[idx];
    }
    part[tid] = s;
    __syncthreads();
    for (int d = 1; d < 256; d <<= 1) {
        int v = 0;
        if (tid >= d) v = part[tid - d];
        __syncthreads();
        if (tid >= d) part[tid] += v;
        __syncthreads();
    }
    int prefix = (tid == 0) ? 0 : part[tid - 1];
    for (int i = 0; i < CH; i++) {
        int idx = base + i;
        if (idx < cN) { offs[idx] = prefix; prefix += count[idx]; }
    }
    if (tid == 255) offs[cN] = prefix;
}
__global__ void scatter_kernel(const int* __restrict__ dst, int* __restrict__ cursor,
                               int* __restrict__ edge_id) {
    int i = blockIdx.x * blockDim.x + threadIdx.x;
    if (i < cE) {
        int pos = atomicAdd(&cursor[dst[i]], 1);
        edge_id[pos] = i;
    }
}

// ---------------- bf16 MFMA GEMM ----------------
// C[M,N] = A@B^T (+bias). A = [A1|A2] rows of k1+k2 bf16; B = [B1|B2] rows [N][k].
// 128x128 tile, BK=32, 4 waves (2x2 of 64x64), mfma_f32_16x16x32_bf16.
// A/B fragments use identical symmetric lane->k mapping (k-permutation-safe).
// C/D mapping (m89-verified): n = lane&15, m = (lane>>4)*4 + reg.
template<int HASBIAS>
__global__ __launch_bounds__(256)
void gemm_mfma_kernel(const unsigned short* __restrict__ A1, const unsigned short* __restrict__ B1, int k1,
                      const unsigned short* __restrict__ A2, const unsigned short* __restrict__ B2, int k2,
                      const float* __restrict__ bias, float* __restrict__ C, int M, int N) {
    __shared__ unsigned short lds[2][2][128 * 32];
    const int tid  = threadIdx.x;
    const int lane = tid & 63;
    const int wave = tid >> 6;
    const int bm = blockIdx.y << 7;
    const int bn = blockIdx.x << 7;
    const int wr = (wave >> 1) << 6;
    const int wc = (wave & 1) << 6;
    const int ns1 = k1 >> 5, ns2 = k2 >> 5, ns = ns1 + ns2;

    const int lrow = lane >> 2;         // row within 16-row chunk
    const int lke  = (lane & 3) << 3;   // k-elem offset 0,8,16,24

    auto stage = [&](int s, int buf) {
        const unsigned short *Ab, *Bb;
        int stride, koff;
        if (s < ns1) { Ab = A1; Bb = B1; stride = k1; koff = s << 5; }
        else         { Ab = A2; Bb = B2; stride = k2; koff = (s - ns1) << 5; }
#pragma unroll
        for (int r = 0; r < 2; r++) {
            int ch  = wave * 2 + r;
            int row = ch * 16 + lrow;
            int ga  = bm + row; if (ga >= M) ga = M - 1;   // clamp (stores masked)
            GLD16(Ab + (size_t)ga * stride + koff + lke, &lds[buf][0][ch * 512]);
            GLD16(Bb + (size_t)(bn + row) * stride + koff + lke, &lds[buf][1][ch * 512]);
        }
    };

    f32x4 acc[4][4];
#pragma unroll
    for (int i = 0; i < 4; i++)
#pragma unroll
        for (int j = 0; j < 4; j++) acc[i][j] = (f32x4){0.f, 0.f, 0.f, 0.f};

    stage(0, 0);
    const int ko  = (lane >> 4) << 3;   // frag k-elem offset (symmetric A/B)
    const int rla = lane & 15;
    for (int s = 0; s < ns; s++) {
        int buf = s & 1;
        __syncthreads();                 // staged(s) visible; prev reads drained
        if (s + 1 < ns) stage(s + 1, buf ^ 1);
        bf16x8 af[4], bff[4];
#pragma unroll
        for (int f = 0; f < 4; f++) {
            af[f]  = *(const bf16x8*)&lds[buf][0][(wr + f * 16 + rla) * 32 + ko];
            bff[f] = *(const bf16x8*)&lds[buf][1][(wc + f * 16 + rla) * 32 + ko];
        }
#pragma unroll
        for (int i = 0; i < 4; i++)
#pragma unroll
            for (int j = 0; j < 4; j++)
                acc[i][j] = __builtin_amdgcn_mfma_f32_16x16x32_bf16(af[i], bff[j], acc[i][j], 0, 0, 0);
    }

#pragma unroll
    for (int i = 0; i < 4; i++) {
#pragma unroll
        for (int v = 0; v < 4; v++) {
            int m = bm + wr + i * 16 + ((lane >> 4) << 2) + v;
            if (m < M) {
#pragma unroll
                for (int j = 0; j < 4; j++) {
                    int n = bn + wc + j * 16 + rla;
                    float val = acc[i][j][v];
                    if (HASBIAS) val += bias[n];
                    C[(size_t)m * N + n] = val;
                }
            }
        }
    }
}

// ---------------- fp32 tiled GEMM (small shapes: embedding + head) ----------------
template<int ACT, int ACCUM>
__global__ __launch_bounds__(256)
void gemm_kernel(const float* __restrict__ A, const float* __restrict__ B,
                 const float* __restrict__ bias, float* __restrict__ C,
                 int M, int N, int K) {
    __shared__ float As[16][132];
    __shared__ float Bs[16][132];
    const int tid = threadIdx.x;
    const int bm = blockIdx.y * 128;
    const int bn = blockIdx.x * 128;
    const int tm = (tid >> 4) << 3;
    const int tn = (tid & 15) << 3;
    float acc[8][8];
#pragma unroll
    for (int i = 0; i < 8; i++)
#pragma unroll
        for (int j = 0; j < 8; j++) acc[i][j] = 0.f;

    for (int k0 = 0; k0 < K; k0 += 16) {
#pragma unroll
        for (int i = 0; i < 2; i++) {
            int m = (tid >> 2) + (i << 6);
            int k4 = (tid & 3) << 2;
            float4 v = make_float4(0.f, 0.f, 0.f, 0.f);
            int row = bm + m;
            if (row < M) v = *reinterpret_cast<const float4*>(A + (size_t)row * K + k0 + k4);
            As[k4 + 0][m] = v.x; As[k4 + 1][m] = v.y; As[k4 + 2][m] = v.z; As[k4 + 3][m] = v.w;
        }
#pragma unroll
        for (int i = 0; i < 8; i++) {
            int idx = tid + (i << 8);
            int k = idx >> 7, n = idx & 127;
            float v = 0.f;
            if (bn + n < N) v = B[(size_t)(k0 + k) * N + bn + n];
            Bs[k][n] = v;
        }
        __syncthreads();
#pragma unroll
        for (int k = 0; k < 16; k++) {
            float4 a0 = *reinterpret_cast<const float4*>(&As[k][tm]);
            float4 a1 = *reinterpret_cast<const float4*>(&As[k][tm + 4]);
            float4 b0 = *reinterpret_cast<const float4*>(&Bs[k][tn]);
            float4 b1 = *reinterpret_cast<const float4*>(&Bs[k][tn + 4]);
            float a[8] = {a0.x, a0.y, a0.z, a0.w, a1.x, a1.y, a1.z, a1.w};
            float b[8] = {b0.x, b0.y, b0.z, b0.w, b1.x, b1.y, b1.z, b1.w};
#pragma unroll
            for (int i = 0; i < 8; i++)
#pragma unroll
                for (int j = 0; j < 8; j++)
                    acc[i][j] = fmaf(a[i], b[j], acc[i][j]);
        }
        __syncthreads();
    }
#pragma unroll
    for (int i = 0; i < 8; i++) {
        int row = bm + tm + i;
        if (row >= M) break;
#pragma unroll
        for (int j = 0; j < 8; j++) {
            int col = bn + tn + j;
            if (col >= N) break;
            float v = acc[i][j];
            if (bias) v += bias[col];
            if (ACCUM) v += C[(size_t)row * N + col];
            if (ACT == 1) v = fmaxf(v, 0.f);
            C[(size_t)row * N + col] = v;
        }
    }
}

// ---------------- fused GAT layer kernel ----------------
// one block per node; wave w = head w. Online softmax over incoming CSR edges,
// single pass: score + exp + weighted xl accumulation. Then heads-mean + conv
// bias + layernorm in LDS. Writes seq fp32 + bf16.
__global__ __launch_bounds__(256)
void gat_fused_kernel(const float* __restrict__ xl, const float* __restrict__ xr,
                      const int* __restrict__ src, const int* __restrict__ offs,
                      const int* __restrict__ edge_id, const float* __restrict__ att,
                      const float* __restrict__ conv_b, const float* __restrict__ lnw,
                      const float* __restrict__ lnb, float* __restrict__ seq_l,
                      unsigned short* __restrict__ seqb_l) {
    __shared__ float sm[512];
    const int n = blockIdx.x;
    const int h = threadIdx.x >> 6;
    const int lane = threadIdx.x & 63;
    const int beg = offs[n], end = offs[n + 1];

    const float xr0 = xr[(size_t)n * 512 + h * 128 + lane];
    const float xr1 = xr[(size_t)n * 512 + h * 128 + lane + 64];
    const float a0  = att[h * 128 + lane];
    const float a1  = att[h * 128 + lane + 64];

    float m = -INFINITY, l = 0.f, acc0 = 0.f, acc1 = 0.f;
    for (int j = beg; j < end; j++) {
        int e = edge_id[j];
        const float* xs = xl + (size_t)src[e] * 512 + h * 128;
        float x0 = xs[lane], x1 = xs[lane + 64];
        float v0 = x0 + xr0; v0 = v0 > 0.f ? v0 : 0.2f * v0;
        float v1 = x1 + xr1; v1 = v1 > 0.f ? v1 : 0.2f * v1;
        float sc = v0 * a0 + v1 * a1;
        for (int o = 32; o; o >>= 1) sc += __shfl_xor(sc, o);
        float mn = fmaxf(m, sc);
        float r  = expf(m - mn);    // first iter: exp(-inf)=0
        float p  = expf(sc - mn);
        l    = l * r + p;
        acc0 = acc0 * r + p * x0;
        acc1 = acc1 * r + p * x1;
        m = mn;
    }
    float inv = 1.f / (l + 1e-16f);   // matches PyG alpha = ex/(denom+1e-16)
    sm[h * 128 + lane]      = acc0 * inv;
    sm[h * 128 + lane + 64] = acc1 * inv;
    __syncthreads();

    if (threadIdx.x < 64) {   // wave 0: heads-mean + conv bias + layernorm
        float v0 = 0.25f * (sm[lane] + sm[128 + lane] + sm[256 + lane] + sm[384 + lane]) + conv_b[lane];
        float v1 = 0.25f * (sm[64 + lane] + sm[192 + lane] + sm[320 + lane] + sm[448 + lane]) + conv_b[64 + lane];
        float s = v0 + v1;
        for (int o = 32; o; o >>= 1) s += __shfl_xor(s, o);
        float mu = s * (1.f / 128.f);
        float d0 = v0 - mu, d1 = v1 - mu;
        float vs = d0 * d0 + d1 * d1;
        for (int o = 32; o; o >>= 1) vs += __shfl_xor(vs, o);
        float rstd = 1.f / sqrtf(vs * (1.f / 128.f) + 1e-5f);
        float o0 = d0 * rstd * lnw[lane] + lnb[lane];
        float o1 = d1 * rstd * lnw[64 + lane] + lnb[64 + lane];
        size_t b = (size_t)n * 128;
        seq_l[b + lane] = o0;        seq_l[b + 64 + lane] = o1;
        seqb_l[b + lane] = f2b(o0);  seqb_l[b + 64 + lane] = f2b(o1);
    }
}

// ---------------- fused LSTM cell + JK partial score ----------------
__global__ void lstm_cell_fused_kernel(const float* __restrict__ gates,
                                       const float* __restrict__ bih, const float* __restrict__ bhh,
                                       float* __restrict__ c, unsigned short* __restrict__ hb16,
                                       const float* __restrict__ jkw, int jkoff,
                                       float* __restrict__ score_t, int first) {
    int wid = (blockIdx.x * blockDim.x + threadIdx.x) >> 6;
    int lane = threadIdx.x & 63;
    if (wid >= cN) return;
    const float* g = gates + (size_t)wid * c4HL;
    float jacc = 0.f;
#pragma unroll
    for (int q = 0; q < 5; q++) {
        int u = lane + (q << 6);
        float gi  = g[u]            + bih[u]            + bhh[u];
        float gf_ = g[cHL + u]      + bih[cHL + u]      + bhh[cHL + u];
        float gg  = g[2 * cHL + u]  + bih[2 * cHL + u]  + bhh[2 * cHL + u];
        float go  = g[3 * cHL + u]  + bih[3 * cHL + u]  + bhh[3 * cHL + u];
        float si = 1.f / (1.f + expf(-gi));
        float sf = 1.f / (1.f + expf(-gf_));
        float so = 1.f / (1.f + expf(-go));
        float tg = tanhf(gg);
        size_t idx = (size_t)wid * cHL + u;
        float cold = first ? 0.f : c[idx];
        float cc = sf * cold + si * tg;
        c[idx] = cc;
        float hh = so * tanhf(cc);
        hb16[idx] = f2b(hh);
        jacc += hh * jkw[jkoff + u];
    }
    for (int o = 32; o; o >>= 1) jacc += __shfl_xor(jacc, o);
    if (lane == 0) score_t[wid] += jacc;
}

// ---------------- JK softmax + mean pooling ----------------
__global__ void jk_pool_kernel(const float* __restrict__ seq, const float* __restrict__ score,
                               const int* __restrict__ batch, float* __restrict__ pooled) {
    int wid = (blockIdx.x * blockDim.x + threadIdx.x) >> 6;
    int lane = threadIdx.x & 63;
    if (wid >= cN) return;
    float s[cL], mx = -INFINITY;
#pragma unroll
    for (int l = 0; l < cL; l++) { s[l] = score[(size_t)l * cN + wid]; mx = fmaxf(mx, s[l]); }
    float se = 0.f;
#pragma unroll
    for (int l = 0; l < cL; l++) { s[l] = expf(s[l] - mx); se += s[l]; }
    float inv = 1.f / se;
    int g = batch[wid];
    float acc0 = 0.f, acc1 = 0.f;
#pragma unroll
    for (int l = 0; l < cL; l++) {
        const float* sp = seq + ((size_t)l * cN + wid) * 128;
        float w = s[l] * inv;
        acc0 += w * sp[lane];
        acc1 += w * sp[lane + 64];
    }
    atomicAdd(&pooled[(size_t)g * 128 + lane], acc0);
    atomicAdd(&pooled[(size_t)g * 128 + lane + 64], acc1);
}

__global__ void count_kernel(const int* __restrict__ batch, float* __restrict__ cnt) {
    int i = blockIdx.x * blockDim.x + threadIdx.x;
    if (i < cN) atomicAdd(&cnt[batch[i]], 1.f);
}

__global__ void div_pool_kernel(float* __restrict__ pooled, const float* __restrict__ cnt) {
    int i = blockIdx.x * blockDim.x + threadIdx.x;
    if (i < cG * 128) pooled[i] /= fmaxf(cnt[i >> 7], 1.f);
}

// ---------------- launch helpers ----------------
static inline int ceil_div(long a, long b) { return (int)((a + b - 1) / b); }

template<int ACT, int ACCUM>
static void launch_gemm(const float* A, const float* B, const float* bias, float* C,
                        int M, int N, int K, hipStream_t s) {
    dim3 g(ceil_div(N, 128), ceil_div(M, 128));
    gemm_kernel<ACT, ACCUM><<<g, 256, 0, s>>>(A, B, bias, C, M, N, K);
}

static void launch_mfma(const unsigned short* A1, const unsigned short* B1, int k1,
                        const unsigned short* A2, const unsigned short* B2, int k2,
                        const float* bias, float* C, int M, int N, hipStream_t s) {
    dim3 g(N >> 7, (M + 127) >> 7);
    if (bias) gemm_mfma_kernel<1><<<g, 256, 0, s>>>(A1, B1, k1, A2, B2, k2, bias, C, M, N);
    else      gemm_mfma_kernel<0><<<g, 256, 0, s>>>(A1, B1, k1, A2, B2, k2, bias, C, M, N);
}

static void fillF(float* p, long n, float v, hipStream_t s) {
    fill_f32_kernel<<<ceil_div(n, 256), 256, 0, s>>>(p, n, v);
}
static void fillI(int* p, long n, int v, hipStream_t s) {
    fill_i32_kernel<<<ceil_div(n, 256), 256, 0, s>>>(p, n, v);
}
static void convB(const float* a, unsigned short* b, long n, hipStream_t s) {
    conv_bf16_kernel<<<ceil_div(n, 256), 256, 0, s>>>(a, b, n);
}

extern "C" void kernel_launch(void* const* d_in, const int* in_sizes, int n_in,
                              void* d_out, int out_size, void* d_ws, size_t ws_size,
                              hipStream_t stream) {
    const float* x      = (const float*)d_in[0];
    const int*   ei     = (const int*)d_in[1];
    const int*   batch  = (const int*)d_in[2];
    const float* emb_W  = (const float*)d_in[3];
    const float* emb_b  = (const float*)d_in[4];
    const float* Wl     = (const float*)d_in[5];
    const float* bl     = (const float*)d_in[6];
    const float* Wr     = (const float*)d_in[7];
    const float* br     = (const float*)d_in[8];
    const float* att_a  = (const float*)d_in[9];
    const float* conv_b = (const float*)d_in[10];
    const float* ln_w   = (const float*)d_in[11];
    const float* ln_b   = (const float*)d_in[12];
    const float* Wih_f  = (const float*)d_in[13];
    const float* Whh_f  = (const float*)d_in[14];
    const float* bih_f  = (const float*)d_in[15];
    const float* bhh_f  = (const float*)d_in[16];
    const float* Wih_b  = (const float*)d_in[17];
    const float* Whh_b  = (const float*)d_in[18];
    const float* bih_b  = (const float*)d_in[19];
    const float* bhh_b  = (const float*)d_in[20];
    const float* jk_w   = (const float*)d_in[21];
    // d_in[22] = jk_b: constant across L -> softmax-invariant, unused
    const float* m1_w   = (const float*)d_in[23];
    const float* m1_b   = (const float*)d_in[24];
    const float* m2_w   = (const float*)d_in[25];
    const float* m2_b   = (const float*)d_in[26];
    const float* res_w  = (const float*)d_in[27];
    const float* res_b  = (const float*)d_in[28];
    float* out = (float*)d_out;

    const int* src = ei;
    const int* dst = ei + cE;

    // ---------------- workspace layout ----------------
    char* ws = (char*)d_ws;
    size_t off = 0;
    auto alloc = [&](size_t bytes) -> char* {
        size_t o = (off + 255) & ~(size_t)255;
        off = o + bytes;
        return ws + o;
    };
    float*          h       = (float*)alloc((size_t)cN * cC * 4);
    unsigned short* emb_b16 = (unsigned short*)alloc((size_t)cN * cC * 2);
    float*          seq     = (float*)alloc((size_t)cL * cN * cC * 4);
    unsigned short* seqb16  = (unsigned short*)alloc((size_t)cL * cN * cC * 2);
    unsigned short* WlT     = (unsigned short*)alloc((size_t)cL * 512 * 128 * 2);
    unsigned short* WrT     = (unsigned short*)alloc((size_t)cL * 512 * 128 * 2);
    unsigned short* Wihf16  = (unsigned short*)alloc((size_t)c4HL * cC * 2);
    unsigned short* Whhf16  = (unsigned short*)alloc((size_t)c4HL * cHL * 2);
    unsigned short* Wihb16  = (unsigned short*)alloc((size_t)c4HL * cC * 2);
    unsigned short* Whhb16  = (unsigned short*)alloc((size_t)c4HL * cHL * 2);
    unsigned short* hf16    = (unsigned short*)alloc((size_t)cN * cHL * 2);
    unsigned short* hb16    = (unsigned short*)alloc((size_t)cN * cHL * 2);
    float*          cf      = (float*)alloc((size_t)cN * cHL * 4);
    float*          cb      = (float*)alloc((size_t)cN * cHL * 4);
    float*          jks     = (float*)alloc((size_t)cL * cN * 4);
    float*          pooled  = (float*)alloc((size_t)cG * cC * 4);
    float*          cnt     = (float*)alloc((size_t)cG * 4);
    float*          hdn     = (float*)alloc((size_t)cG * cC * 4);
    int*            offs    = (int*)alloc((size_t)(cN + 1) * 4);
    int*            cursor  = (int*)alloc((size_t)cN * 4);
    int*            edge_id = (int*)alloc((size_t)cE * 4);
    // overlapped region: GAT xl/xr vs LSTM gates
    size_t gat_bytes  = (size_t)2 * cN * 512 * 4;
    size_t lstm_bytes = (size_t)cN * c4HL * 4;
    char* region = alloc(gat_bytes > lstm_bytes ? gat_bytes : lstm_bytes);
    float* xl    = (float*)region;
    float* xr    = xl + (size_t)cN * 512;
    float* gates = (float*)region;   // LSTM view (GAT fully consumed first)

    hipStream_t s = stream;

    // ---------------- CSR by dst ----------------
    fillI(cursor, cN, 0, s);
    hist_kernel<<<ceil_div(cE, 256), 256, 0, s>>>(dst, cursor);
    scan_kernel<<<1, 256, 0, s>>>(cursor, offs);
    copy_i32_kernel<<<ceil_div(cN, 256), 256, 0, s>>>(offs, cursor, cN);
    scatter_kernel<<<ceil_div(cE, 256), 256, 0, s>>>(dst, cursor, edge_id);

    // ---------------- weight prep (bf16) ----------------
    wproj_prep_kernel<<<ceil_div((long)cL * 512 * 128, 256), 256, 0, s>>>(Wl, WlT);
    wproj_prep_kernel<<<ceil_div((long)cL * 512 * 128, 256), 256, 0, s>>>(Wr, WrT);
    convB(Wih_f, Wihf16, (long)c4HL * cC, s);
    convB(Whh_f, Whhf16, (long)c4HL * cHL, s);
    convB(Wih_b, Wihb16, (long)c4HL * cC, s);
    convB(Whh_b, Whhb16, (long)c4HL * cHL, s);

    // ---------------- embedding ----------------
    launch_gemm<0, 0>(x, emb_W, emb_b, h, cN, cC, cFin, s);
    convB(h, emb_b16, (long)cN * cC, s);

    // ---------------- GAT layers ----------------
    for (int l = 0; l < cL; l++) {
        const unsigned short* hin = (l == 0) ? emb_b16 : seqb16 + (size_t)(l - 1) * cN * cC;
        launch_mfma(hin, WlT + (size_t)l * 512 * 128, cC, nullptr, nullptr, 0,
                    bl + (size_t)l * 512, xl, cN, 512, s);
        launch_mfma(hin, WrT + (size_t)l * 512 * 128, cC, nullptr, nullptr, 0,
                    br + (size_t)l * 512, xr, cN, 512, s);
        gat_fused_kernel<<<cN, 256, 0, s>>>(
            xl, xr, src, offs, edge_id, att_a + (size_t)l * cH * cC,
            conv_b + (size_t)l * cC, ln_w + (size_t)l * cC, ln_b + (size_t)l * cC,
            seq + (size_t)l * cN * cC, seqb16 + (size_t)l * cN * cC);
    }

    // ---------------- bidirectional LSTM + JK scores ----------------
    fillF(jks, (long)cL * cN, 0.f, s);
    for (int k = 0; k < cL; k++) {
        int first = (k == 0);
        // forward step: t = k
        launch_mfma(seqb16 + (size_t)k * cN * cC, Wihf16, cC,
                    hf16, Whhf16, first ? 0 : cHL, nullptr, gates, cN, c4HL, s);
        lstm_cell_fused_kernel<<<ceil_div((long)cN * 64, 256), 256, 0, s>>>(
            gates, bih_f, bhh_f, cf, hf16, jk_w, 0, jks + (size_t)k * cN, first);
        // backward step: t = L-1-k
        int t = cL - 1 - k;
        launch_mfma(seqb16 + (size_t)t * cN * cC, Wihb16, cC,
                    hb16, Whhb16, first ? 0 : cHL, nullptr, gates, cN, c4HL, s);
        lstm_cell_fused_kernel<<<ceil_div((long)cN * 64, 256), 256, 0, s>>>(
            gates, bih_b, bhh_b, cb, hb16, jk_w, cHL, jks + (size_t)t * cN, first);
    }

    // ---------------- JK softmax, pooling, MLP head ----------------
    fillF(pooled, (long)cG * cC, 0.f, s);
    fillF(cnt, cG, 0.f, s);
    jk_pool_kernel<<<ceil_div((long)cN * 64, 256), 256, 0, s>>>(seq, jks, batch, pooled);
    count_kernel<<<ceil_div(cN, 256), 256, 0, s>>>(batch, cnt);
    div_pool_kernel<<<ceil_div((long)cG * 128, 256), 256, 0, s>>>(pooled, cnt);
    launch_gemm<1, 0>(pooled, m1_w, m1_b, hdn, cG, cC, cC, s);
    launch_gemm<0, 0>(hdn, m2_w, m2_b, out, cG, cOUT, cC, s);
    launch_gemm<0, 1>(pooled, res_w, res_b, out, cG, cOUT, cC, s);
}

// Round 4
// 1015.060 us; speedup vs baseline: 3.8379x; 1.2156x over previous
//
#include <hip/hip_runtime.h>
#include <hip/hip_bf16.h>
#include <math.h>

// Problem constants (from reference)
constexpr int cN   = 10000;
constexpr int cE   = 120000;
constexpr int cFin = 64;
constexpr int cC   = 128;
constexpr int cH   = 4;
constexpr int cL   = 5;
constexpr int cG   = 500;
constexpr int cOUT = 1801;
constexpr int cHL  = 320;          // (L*C)/2
constexpr int c4HL = 4 * cHL;      // 1280

typedef short bf16x8 __attribute__((ext_vector_type(8)));
typedef float f32x4 __attribute__((ext_vector_type(4)));

__device__ inline unsigned short f2b(float x) {
    union { __hip_bfloat16 h; unsigned short u; } cv;
    cv.h = __float2bfloat16(x);
    return cv.u;
}
__device__ inline float b2f(unsigned short u) {
    union { unsigned int i; float f; } cv;
    cv.i = ((unsigned int)u) << 16;
    return cv.f;
}

#define GLD16(g, l) __builtin_amdgcn_global_load_lds( \
    (const __attribute__((address_space(1))) unsigned int*)(g), \
    (__attribute__((address_space(3))) unsigned int*)(l), 16, 0, 0)

// ---------------- utility kernels ----------------
__global__ void fill_f32_kernel(float* __restrict__ p, long n, float v) {
    long i = (long)blockIdx.x * blockDim.x + threadIdx.x;
    if (i < n) p[i] = v;
}
__global__ void fill_i32_kernel(int* __restrict__ p, long n, int v) {
    long i = (long)blockIdx.x * blockDim.x + threadIdx.x;
    if (i < n) p[i] = v;
}
__global__ void copy_i32_kernel(const int* __restrict__ a, int* __restrict__ b, long n) {
    long i = (long)blockIdx.x * blockDim.x + threadIdx.x;
    if (i < n) b[i] = a[i];
}
__global__ void conv_bf16_kernel(const float* __restrict__ a, unsigned short* __restrict__ b, long n) {
    long i = (long)blockIdx.x * blockDim.x + threadIdx.x;
    if (i < n) b[i] = f2b(a[i]);
}
// Wl,Wr: [L][128][512] fp32 -> WT: [L][1024][128] bf16 (rows 0..511 = Wl^T, 512..1023 = Wr^T)
__global__ void wproj_prep_kernel(const float* __restrict__ Wl, const float* __restrict__ Wr,
                                  unsigned short* __restrict__ WT) {
    long i = (long)blockIdx.x * blockDim.x + threadIdx.x;
    if (i >= (long)cL * 1024 * 128) return;
    int k = i & 127;
    int n = (int)((i >> 7) & 1023);
    int l = (int)(i >> 17);
    const float* W = (n < 512) ? Wl : Wr;
    int nn = n & 511;
    WT[i] = f2b(W[(size_t)l * 65536 + (size_t)k * 512 + nn]);
}
// bl,br: [L][512] -> bb: [L][1024]
__global__ void bias_prep_kernel(const float* __restrict__ bl, const float* __restrict__ br,
                                 float* __restrict__ bb) {
    int i = blockIdx.x * blockDim.x + threadIdx.x;
    if (i >= cL * 1024) return;
    int n = i & 1023, l = i >> 10;
    bb[i] = (n < 512) ? bl[l * 512 + n] : br[l * 512 + (n - 512)];
}

// ---------------- CSR build (by dst), payload = src node ----------------
__global__ void hist_kernel(const int* __restrict__ dst, int* __restrict__ count) {
    int i = blockIdx.x * blockDim.x + threadIdx.x;
    if (i < cE) atomicAdd(&count[dst[i]], 1);
}
__global__ void scan_kernel(const int* __restrict__ count, int* __restrict__ offs) {
    __shared__ int part[256];
    const int tid = threadIdx.x;
    const int CH = (cN + 255) / 256;
    int base = tid * CH;
    int s = 0;
    for (int i = 0; i < CH; i++) {
        int idx = base + i;
        if (idx < cN) s += count[idx];
    }
    part[tid] = s;
    __syncthreads();
    for (int d = 1; d < 256; d <<= 1) {
        int v = 0;
        if (tid >= d) v = part[tid - d];
        __syncthreads();
        if (tid >= d) part[tid] += v;
        __syncthreads();
    }
    int prefix = (tid == 0) ? 0 : part[tid - 1];
    for (int i = 0; i < CH; i++) {
        int idx = base + i;
        if (idx < cN) { offs[idx] = prefix; prefix += count[idx]; }
    }
    if (tid == 255) offs[cN] = prefix;
}
__global__ void scatter_kernel(const int* __restrict__ src, const int* __restrict__ dst,
                               int* __restrict__ cursor, int* __restrict__ src_csr) {
    int i = blockIdx.x * blockDim.x + threadIdx.x;
    if (i < cE) {
        int pos = atomicAdd(&cursor[dst[i]], 1);
        src_csr[pos] = src[i];
    }
}

// ---------------- bf16 MFMA GEMM ----------------
// C[M,N] = A@B^T (+bias). A = [A1|A2] rows of k1+k2 bf16; B = [B1|B2] rows [N][k].
// 128x128 tile, BK=32, 4 waves, mfma_f32_16x16x32_bf16. OUTB: write bf16.
template<int HASBIAS, int OUTB>
__global__ __launch_bounds__(256)
void gemm_mfma_kernel(const unsigned short* __restrict__ A1, const unsigned short* __restrict__ B1, int k1,
                      const unsigned short* __restrict__ A2, const unsigned short* __restrict__ B2, int k2,
                      const float* __restrict__ bias, void* __restrict__ Cout, int M, int N) {
    __shared__ unsigned short lds[2][2][128 * 32];
    const int tid  = threadIdx.x;
    const int lane = tid & 63;
    const int wave = tid >> 6;
    const int bm = blockIdx.y << 7;
    const int bn = blockIdx.x << 7;
    const int wr = (wave >> 1) << 6;
    const int wc = (wave & 1) << 6;
    const int ns1 = k1 >> 5, ns2 = k2 >> 5, ns = ns1 + ns2;

    const int lrow = lane >> 2;
    const int lke  = (lane & 3) << 3;

    auto stage = [&](int s, int buf) {
        const unsigned short *Ab, *Bb;
        int stride, koff;
        if (s < ns1) { Ab = A1; Bb = B1; stride = k1; koff = s << 5; }
        else         { Ab = A2; Bb = B2; stride = k2; koff = (s - ns1) << 5; }
#pragma unroll
        for (int r = 0; r < 2; r++) {
            int ch  = wave * 2 + r;
            int row = ch * 16 + lrow;
            int ga  = bm + row; if (ga >= M) ga = M - 1;   // clamp (stores masked)
            GLD16(Ab + (size_t)ga * stride + koff + lke, &lds[buf][0][ch * 512]);
            GLD16(Bb + (size_t)(bn + row) * stride + koff + lke, &lds[buf][1][ch * 512]);
        }
    };

    f32x4 acc[4][4];
#pragma unroll
    for (int i = 0; i < 4; i++)
#pragma unroll
        for (int j = 0; j < 4; j++) acc[i][j] = (f32x4){0.f, 0.f, 0.f, 0.f};

    stage(0, 0);
    const int ko  = (lane >> 4) << 3;
    const int rla = lane & 15;
    for (int s = 0; s < ns; s++) {
        int buf = s & 1;
        __syncthreads();
        if (s + 1 < ns) stage(s + 1, buf ^ 1);
        bf16x8 af[4], bff[4];
#pragma unroll
        for (int f = 0; f < 4; f++) {
            af[f]  = *(const bf16x8*)&lds[buf][0][(wr + f * 16 + rla) * 32 + ko];
            bff[f] = *(const bf16x8*)&lds[buf][1][(wc + f * 16 + rla) * 32 + ko];
        }
#pragma unroll
        for (int i = 0; i < 4; i++)
#pragma unroll
            for (int j = 0; j < 4; j++)
                acc[i][j] = __builtin_amdgcn_mfma_f32_16x16x32_bf16(af[i], bff[j], acc[i][j], 0, 0, 0);
    }

#pragma unroll
    for (int i = 0; i < 4; i++) {
#pragma unroll
        for (int v = 0; v < 4; v++) {
            int m = bm + wr + i * 16 + ((lane >> 4) << 2) + v;
            if (m < M) {
#pragma unroll
                for (int j = 0; j < 4; j++) {
                    int n = bn + wc + j * 16 + rla;
                    float val = acc[i][j][v];
                    if (HASBIAS) val += bias[n];
                    if (OUTB) ((unsigned short*)Cout)[(size_t)m * N + n] = f2b(val);
                    else      ((float*)Cout)[(size_t)m * N + n] = val;
                }
            }
        }
    }
}

// ---------------- fp32 tiled GEMM (small shapes: embedding + head) ----------------
template<int ACT, int ACCUM>
__global__ __launch_bounds__(256)
void gemm_kernel(const float* __restrict__ A, const float* __restrict__ B,
                 const float* __restrict__ bias, float* __restrict__ C,
                 int M, int N, int K) {
    __shared__ float As[16][132];
    __shared__ float Bs[16][132];
    const int tid = threadIdx.x;
    const int bm = blockIdx.y * 128;
    const int bn = blockIdx.x * 128;
    const int tm = (tid >> 4) << 3;
    const int tn = (tid & 15) << 3;
    float acc[8][8];
#pragma unroll
    for (int i = 0; i < 8; i++)
#pragma unroll
        for (int j = 0; j < 8; j++) acc[i][j] = 0.f;

    for (int k0 = 0; k0 < K; k0 += 16) {
#pragma unroll
        for (int i = 0; i < 2; i++) {
            int m = (tid >> 2) + (i << 6);
            int k4 = (tid & 3) << 2;
            float4 v = make_float4(0.f, 0.f, 0.f, 0.f);
            int row = bm + m;
            if (row < M) v = *reinterpret_cast<const float4*>(A + (size_t)row * K + k0 + k4);
            As[k4 + 0][m] = v.x; As[k4 + 1][m] = v.y; As[k4 + 2][m] = v.z; As[k4 + 3][m] = v.w;
        }
#pragma unroll
        for (int i = 0; i < 8; i++) {
            int idx = tid + (i << 8);
            int k = idx >> 7, n = idx & 127;
            float v = 0.f;
            if (bn + n < N) v = B[(size_t)(k0 + k) * N + bn + n];
            Bs[k][n] = v;
        }
        __syncthreads();
#pragma unroll
        for (int k = 0; k < 16; k++) {
            float4 a0 = *reinterpret_cast<const float4*>(&As[k][tm]);
            float4 a1 = *reinterpret_cast<const float4*>(&As[k][tm + 4]);
            float4 b0 = *reinterpret_cast<const float4*>(&Bs[k][tn]);
            float4 b1 = *reinterpret_cast<const float4*>(&Bs[k][tn + 4]);
            float a[8] = {a0.x, a0.y, a0.z, a0.w, a1.x, a1.y, a1.z, a1.w};
            float b[8] = {b0.x, b0.y, b0.z, b0.w, b1.x, b1.y, b1.z, b1.w};
#pragma unroll
            for (int i = 0; i < 8; i++)
#pragma unroll
                for (int j = 0; j < 8; j++)
                    acc[i][j] = fmaf(a[i], b[j], acc[i][j]);
        }
        __syncthreads();
    }
#pragma unroll
    for (int i = 0; i < 8; i++) {
        int row = bm + tm + i;
        if (row >= M) break;
#pragma unroll
        for (int j = 0; j < 8; j++) {
            int col = bn + tn + j;
            if (col >= N) break;
            float v = acc[i][j];
            if (bias) v += bias[col];
            if (ACCUM) v += C[(size_t)row * N + col];
            if (ACT == 1) v = fmaxf(v, 0.f);
            C[(size_t)row * N + col] = v;
        }
    }
}

// ---------------- fused GAT layer: one wave per node ----------------
// lane = h*16 + l16; lane owns 8 channels (cb = l16*8) of head h.
// xlr: [N][1024] bf16 rows = [xl(512) | xr(512)]. Online softmax over CSR edges;
// score reduce = 4-level shfl within 16-lane group; heads-mean + LN via
// shfl_xor(16/32); no LDS, no barriers.
__global__ __launch_bounds__(256)
void gat_fused_kernel(const unsigned short* __restrict__ xlr, const int* __restrict__ src_csr,
                      const int* __restrict__ offs, const float* __restrict__ att,
                      const float* __restrict__ conv_b, const float* __restrict__ lnw,
                      const float* __restrict__ lnb, float* __restrict__ seq_l,
                      unsigned short* __restrict__ seqb_l) {
    const int wv   = (blockIdx.x * blockDim.x + threadIdx.x) >> 6;  // node
    const int lane = threadIdx.x & 63;
    if (wv >= cN) return;
    const int h   = lane >> 4;
    const int cb  = (lane & 15) << 3;   // channel base within head

    // xr channels of head h (bf16 -> f32); note h*128 + cb == lane*8
    bf16x8 xrv = *(const bf16x8*)&xlr[(size_t)wv * 1024 + 512 + lane * 8];
    float xr[8], av[8];
#pragma unroll
    for (int k = 0; k < 8; k++) {
        xr[k] = b2f((unsigned short)xrv[k]);
        av[k] = att[h * 128 + cb + k];
    }

    float m = -INFINITY, l = 0.f;
    float acc[8];
#pragma unroll
    for (int k = 0; k < 8; k++) acc[k] = 0.f;

    const int beg = offs[wv], end = offs[wv + 1];
    for (int j = beg; j < end; j++) {
        int s = src_csr[j];
        bf16x8 xv = *(const bf16x8*)&xlr[(size_t)s * 1024 + lane * 8];
        float x[8], sc = 0.f;
#pragma unroll
        for (int k = 0; k < 8; k++) {
            x[k] = b2f((unsigned short)xv[k]);
            float v = x[k] + xr[k];
            v = v > 0.f ? v : 0.2f * v;
            sc = fmaf(v, av[k], sc);
        }
#pragma unroll
        for (int o = 1; o < 16; o <<= 1) sc += __shfl_xor(sc, o);
        float mn = fmaxf(m, sc);
        float r  = expf(m - mn);     // first edge: exp(-inf)=0
        float p  = expf(sc - mn);
        l = l * r + p;
#pragma unroll
        for (int k = 0; k < 8; k++) acc[k] = acc[k] * r + p * x[k];
        m = mn;
    }
    float inv = 1.f / (l + 1e-16f);   // matches PyG alpha = ex/(denom+1e-16)

    // heads-mean (+conv bias): sum over the 4 16-lane groups
#pragma unroll
    for (int k = 0; k < 8; k++) {
        float v = acc[k] * inv;
        v += __shfl_xor(v, 16);
        v += __shfl_xor(v, 32);
        acc[k] = 0.25f * v + conv_b[cb + k];
    }
    // layernorm over 128 channels (16 lanes x 8 each; groups redundant)
    float ssum = 0.f;
#pragma unroll
    for (int k = 0; k < 8; k++) ssum += acc[k];
#pragma unroll
    for (int o = 1; o < 16; o <<= 1) ssum += __shfl_xor(ssum, o);
    float mu = ssum * (1.f / 128.f);
    float vs = 0.f;
#pragma unroll
    for (int k = 0; k < 8; k++) { float d = acc[k] - mu; vs = fmaf(d, d, vs); }
#pragma unroll
    for (int o = 1; o < 16; o <<= 1) vs += __shfl_xor(vs, o);
    float rstd = 1.f / sqrtf(vs * (1.f / 128.f) + 1e-5f);

    float outv[8];
#pragma unroll
    for (int k = 0; k < 8; k++)
        outv[k] = (acc[k] - mu) * rstd * lnw[cb + k] + lnb[cb + k];

    if (h == 0) {
        size_t b = (size_t)wv * 128 + cb;
        float4 o0 = make_float4(outv[0], outv[1], outv[2], outv[3]);
        float4 o1 = make_float4(outv[4], outv[5], outv[6], outv[7]);
        *(float4*)&seq_l[b]     = o0;
        *(float4*)&seq_l[b + 4] = o1;
        bf16x8 ob;
#pragma unroll
        for (int k = 0; k < 8; k++) ob[k] = (short)f2b(outv[k]);
        *(bf16x8*)&seqb_l[b] = ob;
    }
}

// ---------------- fused LSTM cell + JK partial score ----------------
__global__ void lstm_cell_fused_kernel(const float* __restrict__ gates,
                                       const float* __restrict__ bih, const float* __restrict__ bhh,
                                       float* __restrict__ c, unsigned short* __restrict__ hb16,
                                       const float* __restrict__ jkw, int jkoff,
                                       float* __restrict__ score_t, int first) {
    int wid = (blockIdx.x * blockDim.x + threadIdx.x) >> 6;
    int lane = threadIdx.x & 63;
    if (wid >= cN) return;
    const float* g = gates + (size_t)wid * c4HL;
    float jacc = 0.f;
#pragma unroll
    for (int q = 0; q < 5; q++) {
        int u = lane + (q << 6);
        float gi  = g[u]            + bih[u]            + bhh[u];
        float gf_ = g[cHL + u]      + bih[cHL + u]      + bhh[cHL + u];
        float gg  = g[2 * cHL + u]  + bih[2 * cHL + u]  + bhh[2 * cHL + u];
        float go  = g[3 * cHL + u]  + bih[3 * cHL + u]  + bhh[3 * cHL + u];
        float si = 1.f / (1.f + expf(-gi));
        float sf = 1.f / (1.f + expf(-gf_));
        float so = 1.f / (1.f + expf(-go));
        float tg = tanhf(gg);
        size_t idx = (size_t)wid * cHL + u;
        float cold = first ? 0.f : c[idx];
        float cc = sf * cold + si * tg;
        c[idx] = cc;
        float hh = so * tanhf(cc);
        hb16[idx] = f2b(hh);
        jacc += hh * jkw[jkoff + u];
    }
    for (int o = 32; o; o >>= 1) jacc += __shfl_xor(jacc, o);
    if (lane == 0) score_t[wid] += jacc;
}

// ---------------- JK softmax + mean pooling ----------------
__global__ void jk_pool_kernel(const float* __restrict__ seq, const float* __restrict__ score,
                               const int* __restrict__ batch, float* __restrict__ pooled) {
    int wid = (blockIdx.x * blockDim.x + threadIdx.x) >> 6;
    int lane = threadIdx.x & 63;
    if (wid >= cN) return;
    float s[cL], mx = -INFINITY;
#pragma unroll
    for (int l = 0; l < cL; l++) { s[l] = score[(size_t)l * cN + wid]; mx = fmaxf(mx, s[l]); }
    float se = 0.f;
#pragma unroll
    for (int l = 0; l < cL; l++) { s[l] = expf(s[l] - mx); se += s[l]; }
    float inv = 1.f / se;
    int g = batch[wid];
    float acc0 = 0.f, acc1 = 0.f;
#pragma unroll
    for (int l = 0; l < cL; l++) {
        const float* sp = seq + ((size_t)l * cN + wid) * 128;
        float w = s[l] * inv;
        acc0 += w * sp[lane];
        acc1 += w * sp[lane + 64];
    }
    atomicAdd(&pooled[(size_t)g * 128 + lane], acc0);
    atomicAdd(&pooled[(size_t)g * 128 + lane + 64], acc1);
}

__global__ void count_kernel(const int* __restrict__ batch, float* __restrict__ cnt) {
    int i = blockIdx.x * blockDim.x + threadIdx.x;
    if (i < cN) atomicAdd(&cnt[batch[i]], 1.f);
}

__global__ void div_pool_kernel(float* __restrict__ pooled, const float* __restrict__ cnt) {
    int i = blockIdx.x * blockDim.x + threadIdx.x;
    if (i < cG * 128) pooled[i] /= fmaxf(cnt[i >> 7], 1.f);
}

// ---------------- launch helpers ----------------
static inline int ceil_div(long a, long b) { return (int)((a + b - 1) / b); }

template<int ACT, int ACCUM>
static void launch_gemm(const float* A, const float* B, const float* bias, float* C,
                        int M, int N, int K, hipStream_t s) {
    dim3 g(ceil_div(N, 128), ceil_div(M, 128));
    gemm_kernel<ACT, ACCUM><<<g, 256, 0, s>>>(A, B, bias, C, M, N, K);
}

template<int OUTB>
static void launch_mfma(const unsigned short* A1, const unsigned short* B1, int k1,
                        const unsigned short* A2, const unsigned short* B2, int k2,
                        const float* bias, void* C, int M, int N, hipStream_t s) {
    dim3 g(N >> 7, (M + 127) >> 7);
    if (bias) gemm_mfma_kernel<1, OUTB><<<g, 256, 0, s>>>(A1, B1, k1, A2, B2, k2, bias, C, M, N);
    else      gemm_mfma_kernel<0, OUTB><<<g, 256, 0, s>>>(A1, B1, k1, A2, B2, k2, bias, C, M, N);
}

static void fillF(float* p, long n, float v, hipStream_t s) {
    fill_f32_kernel<<<ceil_div(n, 256), 256, 0, s>>>(p, n, v);
}
static void fillI(int* p, long n, int v, hipStream_t s) {
    fill_i32_kernel<<<ceil_div(n, 256), 256, 0, s>>>(p, n, v);
}
static void convB(const float* a, unsigned short* b, long n, hipStream_t s) {
    conv_bf16_kernel<<<ceil_div(n, 256), 256, 0, s>>>(a, b, n);
}

extern "C" void kernel_launch(void* const* d_in, const int* in_sizes, int n_in,
                              void* d_out, int out_size, void* d_ws, size_t ws_size,
                              hipStream_t stream) {
    const float* x      = (const float*)d_in[0];
    const int*   ei     = (const int*)d_in[1];
    const int*   batch  = (const int*)d_in[2];
    const float* emb_W  = (const float*)d_in[3];
    const float* emb_b  = (const float*)d_in[4];
    const float* Wl     = (const float*)d_in[5];
    const float* bl     = (const float*)d_in[6];
    const float* Wr     = (const float*)d_in[7];
    const float* br     = (const float*)d_in[8];
    const float* att_a  = (const float*)d_in[9];
    const float* conv_b = (const float*)d_in[10];
    const float* ln_w   = (const float*)d_in[11];
    const float* ln_b   = (const float*)d_in[12];
    const float* Wih_f  = (const float*)d_in[13];
    const float* Whh_f  = (const float*)d_in[14];
    const float* bih_f  = (const float*)d_in[15];
    const float* bhh_f  = (const float*)d_in[16];
    const float* Wih_b  = (const float*)d_in[17];
    const float* Whh_b  = (const float*)d_in[18];
    const float* bih_b  = (const float*)d_in[19];
    const float* bhh_b  = (const float*)d_in[20];
    const float* jk_w   = (const float*)d_in[21];
    // d_in[22] = jk_b: constant across L -> softmax-invariant, unused
    const float* m1_w   = (const float*)d_in[23];
    const float* m1_b   = (const float*)d_in[24];
    const float* m2_w   = (const float*)d_in[25];
    const float* m2_b   = (const float*)d_in[26];
    const float* res_w  = (const float*)d_in[27];
    const float* res_b  = (const float*)d_in[28];
    float* out = (float*)d_out;

    const int* src = ei;
    const int* dst = ei + cE;

    // ---------------- workspace layout ----------------
    char* ws = (char*)d_ws;
    size_t off = 0;
    auto alloc = [&](size_t bytes) -> char* {
        size_t o = (off + 255) & ~(size_t)255;
        off = o + bytes;
        return ws + o;
    };
    float*          h       = (float*)alloc((size_t)cN * cC * 4);
    unsigned short* emb_b16 = (unsigned short*)alloc((size_t)cN * cC * 2);
    float*          seq     = (float*)alloc((size_t)cL * cN * cC * 4);
    unsigned short* seqb16  = (unsigned short*)alloc((size_t)cL * cN * cC * 2);
    unsigned short* WT      = (unsigned short*)alloc((size_t)cL * 1024 * 128 * 2);
    float*          bb      = (float*)alloc((size_t)cL * 1024 * 4);
    unsigned short* Wihf16  = (unsigned short*)alloc((size_t)c4HL * cC * 2);
    unsigned short* Whhf16  = (unsigned short*)alloc((size_t)c4HL * cHL * 2);
    unsigned short* Wihb16  = (unsigned short*)alloc((size_t)c4HL * cC * 2);
    unsigned short* Whhb16  = (unsigned short*)alloc((size_t)c4HL * cHL * 2);
    unsigned short* hf16    = (unsigned short*)alloc((size_t)cN * cHL * 2);
    unsigned short* hb16    = (unsigned short*)alloc((size_t)cN * cHL * 2);
    float*          cf      = (float*)alloc((size_t)cN * cHL * 4);
    float*          cb      = (float*)alloc((size_t)cN * cHL * 4);
    float*          jks     = (float*)alloc((size_t)cL * cN * 4);
    float*          pooled  = (float*)alloc((size_t)cG * cC * 4);
    float*          cnt     = (float*)alloc((size_t)cG * 4);
    float*          hdn     = (float*)alloc((size_t)cG * cC * 4);
    int*            offs    = (int*)alloc((size_t)(cN + 1) * 4);
    int*            cursor  = (int*)alloc((size_t)cN * 4);
    int*            src_csr = (int*)alloc((size_t)cE * 4);
    // overlapped region: GAT xlr (bf16, 20 MB) vs LSTM gates (fp32, 51 MB)
    size_t gat_bytes  = (size_t)cN * 1024 * 2;
    size_t lstm_bytes = (size_t)cN * c4HL * 4;
    char* region = alloc(gat_bytes > lstm_bytes ? gat_bytes : lstm_bytes);
    unsigned short* xlr = (unsigned short*)region;
    float* gates = (float*)region;   // LSTM view (GAT fully consumed first)

    hipStream_t s = stream;

    // ---------------- CSR by dst (payload = src) ----------------
    fillI(cursor, cN, 0, s);
    hist_kernel<<<ceil_div(cE, 256), 256, 0, s>>>(dst, cursor);
    scan_kernel<<<1, 256, 0, s>>>(cursor, offs);
    copy_i32_kernel<<<ceil_div(cN, 256), 256, 0, s>>>(offs, cursor, cN);
    scatter_kernel<<<ceil_div(cE, 256), 256, 0, s>>>(src, dst, cursor, src_csr);

    // ---------------- weight prep (bf16) ----------------
    wproj_prep_kernel<<<ceil_div((long)cL * 1024 * 128, 256), 256, 0, s>>>(Wl, Wr, WT);
    bias_prep_kernel<<<ceil_div((long)cL * 1024, 256), 256, 0, s>>>(bl, br, bb);
    convB(Wih_f, Wihf16, (long)c4HL * cC, s);
    convB(Whh_f, Whhf16, (long)c4HL * cHL, s);
    convB(Wih_b, Wihb16, (long)c4HL * cC, s);
    convB(Whh_b, Whhb16, (long)c4HL * cHL, s);

    // ---------------- embedding ----------------
    launch_gemm<0, 0>(x, emb_W, emb_b, h, cN, cC, cFin, s);
    convB(h, emb_b16, (long)cN * cC, s);

    // ---------------- GAT layers ----------------
    for (int l = 0; l < cL; l++) {
        const unsigned short* hin = (l == 0) ? emb_b16 : seqb16 + (size_t)(l - 1) * cN * cC;
        launch_mfma<1>(hin, WT + (size_t)l * 1024 * 128, cC, nullptr, nullptr, 0,
                       bb + (size_t)l * 1024, xlr, cN, 1024, s);
        gat_fused_kernel<<<ceil_div((long)cN * 64, 256), 256, 0, s>>>(
            xlr, src_csr, offs, att_a + (size_t)l * cH * cC,
            conv_b + (size_t)l * cC, ln_w + (size_t)l * cC, ln_b + (size_t)l * cC,
            seq + (size_t)l * cN * cC, seqb16 + (size_t)l * cN * cC);
    }

    // ---------------- bidirectional LSTM + JK scores ----------------
    fillF(jks, (long)cL * cN, 0.f, s);
    for (int k = 0; k < cL; k++) {
        int first = (k == 0);
        // forward step: t = k
        launch_mfma<0>(seqb16 + (size_t)k * cN * cC, Wihf16, cC,
                       hf16, Whhf16, first ? 0 : cHL, nullptr, gates, cN, c4HL, s);
        lstm_cell_fused_kernel<<<ceil_div((long)cN * 64, 256), 256, 0, s>>>(
            gates, bih_f, bhh_f, cf, hf16, jk_w, 0, jks + (size_t)k * cN, first);
        // backward step: t = L-1-k
        int t = cL - 1 - k;
        launch_mfma<0>(seqb16 + (size_t)t * cN * cC, Wihb16, cC,
                       hb16, Whhb16, first ? 0 : cHL, nullptr, gates, cN, c4HL, s);
        lstm_cell_fused_kernel<<<ceil_div((long)cN * 64, 256), 256, 0, s>>>(
            gates, bih_b, bhh_b, cb, hb16, jk_w, cHL, jks + (size_t)t * cN, first);
    }

    // ---------------- JK softmax, pooling, MLP head ----------------
    fillF(pooled, (long)cG * cC, 0.f, s);
    fillF(cnt, cG, 0.f, s);
    jk_pool_kernel<<<ceil_div((long)cN * 64, 256), 256, 0, s>>>(seq, jks, batch, pooled);
    count_kernel<<<ceil_div(cN, 256), 256, 0, s>>>(batch, cnt);
    div_pool_kernel<<<ceil_div((long)cG * 128, 256), 256, 0, s>>>(pooled, cnt);
    launch_gemm<1, 0>(pooled, m1_w, m1_b, hdn, cG, cC, cC, s);
    launch_gemm<0, 0>(hdn, m2_w, m2_b, out, cG, cOUT, cC, s);
    launch_gemm<0, 1>(pooled, res_w, res_b, out, cG, cOUT, cC, s);
}

// Round 5
// 896.494 us; speedup vs baseline: 4.3455x; 1.1323x over previous
//
#include <hip/hip_runtime.h>
#include <hip/hip_bf16.h>
#include <math.h>

// Problem constants (from reference)
constexpr int cN   = 10000;
constexpr int cE   = 120000;
constexpr int cFin = 64;
constexpr int cC   = 128;
constexpr int cH   = 4;
constexpr int cL   = 5;
constexpr int cG   = 500;
constexpr int cOUT = 1801;
constexpr int cHL  = 320;          // (L*C)/2
constexpr int c4HL = 4 * cHL;      // 1280

typedef short bf16x8 __attribute__((ext_vector_type(8)));
typedef float f32x4 __attribute__((ext_vector_type(4)));

__device__ inline unsigned short f2b(float x) {
    union { __hip_bfloat16 h; unsigned short u; } cv;
    cv.h = __float2bfloat16(x);
    return cv.u;
}
__device__ inline float b2f(unsigned short u) {
    union { unsigned int i; float f; } cv;
    cv.i = ((unsigned int)u) << 16;
    return cv.f;
}

#define GLD16(g, l) __builtin_amdgcn_global_load_lds( \
    (const __attribute__((address_space(1))) unsigned int*)(g), \
    (__attribute__((address_space(3))) unsigned int*)(l), 16, 0, 0)

// ---------------- utility kernels ----------------
__global__ void fill_f32_kernel(float* __restrict__ p, long n, float v) {
    long i = (long)blockIdx.x * blockDim.x + threadIdx.x;
    if (i < n) p[i] = v;
}
__global__ void fill_i32_kernel(int* __restrict__ p, long n, int v) {
    long i = (long)blockIdx.x * blockDim.x + threadIdx.x;
    if (i < n) p[i] = v;
}
__global__ void copy_i32_kernel(const int* __restrict__ a, int* __restrict__ b, long n) {
    long i = (long)blockIdx.x * blockDim.x + threadIdx.x;
    if (i < n) b[i] = a[i];
}
__global__ void conv_bf16_kernel(const float* __restrict__ a, unsigned short* __restrict__ b, long n) {
    long i = (long)blockIdx.x * blockDim.x + threadIdx.x;
    if (i < n) b[i] = f2b(a[i]);
}
// Wl,Wr: [L][128][512] fp32 -> WT: [L][1024][128] bf16 (rows 0..511 = Wl^T, 512..1023 = Wr^T)
__global__ void wproj_prep_kernel(const float* __restrict__ Wl, const float* __restrict__ Wr,
                                  unsigned short* __restrict__ WT) {
    long i = (long)blockIdx.x * blockDim.x + threadIdx.x;
    if (i >= (long)cL * 1024 * 128) return;
    int k = i & 127;
    int n = (int)((i >> 7) & 1023);
    int l = (int)(i >> 17);
    const float* W = (n < 512) ? Wl : Wr;
    int nn = n & 511;
    WT[i] = f2b(W[(size_t)l * 65536 + (size_t)k * 512 + nn]);
}
// bl,br: [L][512] -> bb: [L][1024]
__global__ void bias_prep_kernel(const float* __restrict__ bl, const float* __restrict__ br,
                                 float* __restrict__ bb) {
    int i = blockIdx.x * blockDim.x + threadIdx.x;
    if (i >= cL * 1024) return;
    int n = i & 1023, l = i >> 10;
    bb[i] = (n < 512) ? bl[l * 512 + n] : br[l * 512 + (n - 512)];
}
// emb_W: [64][128] fp32 (KxN) -> embWT: [128][64] bf16 (NxK)
__global__ void embw_prep_kernel(const float* __restrict__ W, unsigned short* __restrict__ WT) {
    int i = blockIdx.x * blockDim.x + threadIdx.x;
    if (i >= cC * cFin) return;
    int k = i & 63, n = i >> 6;
    WT[i] = f2b(W[(size_t)k * cC + n]);
}

// ---------------- CSR build (by dst), payload = src node ----------------
__global__ void hist_kernel(const int* __restrict__ dst, int* __restrict__ count) {
    int i = blockIdx.x * blockDim.x + threadIdx.x;
    if (i < cE) atomicAdd(&count[dst[i]], 1);
}
__global__ void scan_kernel(const int* __restrict__ count, int* __restrict__ offs) {
    __shared__ int part[256];
    const int tid = threadIdx.x;
    const int CH = (cN + 255) / 256;
    int base = tid * CH;
    int s = 0;
    for (int i = 0; i < CH; i++) {
        int idx = base + i;
        if (idx < cN) s += count[idx];
    }
    part[tid] = s;
    __syncthreads();
    for (int d = 1; d < 256; d <<= 1) {
        int v = 0;
        if (tid >= d) v = part[tid - d];
        __syncthreads();
        if (tid >= d) part[tid] += v;
        __syncthreads();
    }
    int prefix = (tid == 0) ? 0 : part[tid - 1];
    for (int i = 0; i < CH; i++) {
        int idx = base + i;
        if (idx < cN) { offs[idx] = prefix; prefix += count[idx]; }
    }
    if (tid == 255) offs[cN] = prefix;
}
__global__ void scatter_kernel(const int* __restrict__ src, const int* __restrict__ dst,
                               int* __restrict__ cursor, int* __restrict__ src_csr) {
    int i = blockIdx.x * blockDim.x + threadIdx.x;
    if (i < cE) {
        int pos = atomicAdd(&cursor[dst[i]], 1);
        src_csr[pos] = src[i];
    }
}

// ---------------- bf16 MFMA GEMM ----------------
// C[M,N] = A@B^T (+bias). A = [A1|A2] rows of k1+k2 bf16; B = [B1|B2] rows [N][k].
// 128x128 tile, BK=32, 4 waves, mfma_f32_16x16x32_bf16. OUTB: write bf16.
template<int HASBIAS, int OUTB>
__global__ __launch_bounds__(256)
void gemm_mfma_kernel(const unsigned short* __restrict__ A1, const unsigned short* __restrict__ B1, int k1,
                      const unsigned short* __restrict__ A2, const unsigned short* __restrict__ B2, int k2,
                      const float* __restrict__ bias, void* __restrict__ Cout, int M, int N) {
    __shared__ unsigned short lds[2][2][128 * 32];
    const int tid  = threadIdx.x;
    const int lane = tid & 63;
    const int wave = tid >> 6;
    const int bm = blockIdx.y << 7;
    const int bn = blockIdx.x << 7;
    const int wr = (wave >> 1) << 6;
    const int wc = (wave & 1) << 6;
    const int ns1 = k1 >> 5, ns2 = k2 >> 5, ns = ns1 + ns2;

    const int lrow = lane >> 2;
    const int lke  = (lane & 3) << 3;

    auto stage = [&](int s, int buf) {
        const unsigned short *Ab, *Bb;
        int stride, koff;
        if (s < ns1) { Ab = A1; Bb = B1; stride = k1; koff = s << 5; }
        else         { Ab = A2; Bb = B2; stride = k2; koff = (s - ns1) << 5; }
#pragma unroll
        for (int r = 0; r < 2; r++) {
            int ch  = wave * 2 + r;
            int row = ch * 16 + lrow;
            int ga  = bm + row; if (ga >= M) ga = M - 1;   // clamp (stores masked)
            GLD16(Ab + (size_t)ga * stride + koff + lke, &lds[buf][0][ch * 512]);
            GLD16(Bb + (size_t)(bn + row) * stride + koff + lke, &lds[buf][1][ch * 512]);
        }
    };

    f32x4 acc[4][4];
#pragma unroll
    for (int i = 0; i < 4; i++)
#pragma unroll
        for (int j = 0; j < 4; j++) acc[i][j] = (f32x4){0.f, 0.f, 0.f, 0.f};

    stage(0, 0);
    const int ko  = (lane >> 4) << 3;
    const int rla = lane & 15;
    for (int s = 0; s < ns; s++) {
        int buf = s & 1;
        __syncthreads();
        if (s + 1 < ns) stage(s + 1, buf ^ 1);
        bf16x8 af[4], bff[4];
#pragma unroll
        for (int f = 0; f < 4; f++) {
            af[f]  = *(const bf16x8*)&lds[buf][0][(wr + f * 16 + rla) * 32 + ko];
            bff[f] = *(const bf16x8*)&lds[buf][1][(wc + f * 16 + rla) * 32 + ko];
        }
#pragma unroll
        for (int i = 0; i < 4; i++)
#pragma unroll
            for (int j = 0; j < 4; j++)
                acc[i][j] = __builtin_amdgcn_mfma_f32_16x16x32_bf16(af[i], bff[j], acc[i][j], 0, 0, 0);
    }

#pragma unroll
    for (int i = 0; i < 4; i++) {
#pragma unroll
        for (int v = 0; v < 4; v++) {
            int m = bm + wr + i * 16 + ((lane >> 4) << 2) + v;
            if (m < M) {
#pragma unroll
                for (int j = 0; j < 4; j++) {
                    int n = bn + wc + j * 16 + rla;
                    float val = acc[i][j][v];
                    if (HASBIAS) val += bias[n];
                    if (OUTB) ((unsigned short*)Cout)[(size_t)m * N + n] = f2b(val);
                    else      ((float*)Cout)[(size_t)m * N + n] = val;
                }
            }
        }
    }
}

// ---------------- fused GAT layer: one wave per node ----------------
__global__ __launch_bounds__(256)
void gat_fused_kernel(const unsigned short* __restrict__ xlr, const int* __restrict__ src_csr,
                      const int* __restrict__ offs, const float* __restrict__ att,
                      const float* __restrict__ conv_b, const float* __restrict__ lnw,
                      const float* __restrict__ lnb, float* __restrict__ seq_l,
                      unsigned short* __restrict__ seqb_l) {
    const int wv   = (blockIdx.x * blockDim.x + threadIdx.x) >> 6;  // node
    const int lane = threadIdx.x & 63;
    if (wv >= cN) return;
    const int h   = lane >> 4;
    const int cb  = (lane & 15) << 3;   // channel base within head

    bf16x8 xrv = *(const bf16x8*)&xlr[(size_t)wv * 1024 + 512 + lane * 8];
    float xr[8], av[8];
#pragma unroll
    for (int k = 0; k < 8; k++) {
        xr[k] = b2f((unsigned short)xrv[k]);
        av[k] = att[h * 128 + cb + k];
    }

    float m = -INFINITY, l = 0.f;
    float acc[8];
#pragma unroll
    for (int k = 0; k < 8; k++) acc[k] = 0.f;

    const int beg = offs[wv], end = offs[wv + 1];
    for (int j = beg; j < end; j++) {
        int s = src_csr[j];
        bf16x8 xv = *(const bf16x8*)&xlr[(size_t)s * 1024 + lane * 8];
        float x[8], sc = 0.f;
#pragma unroll
        for (int k = 0; k < 8; k++) {
            x[k] = b2f((unsigned short)xv[k]);
            float v = x[k] + xr[k];
            v = v > 0.f ? v : 0.2f * v;
            sc = fmaf(v, av[k], sc);
        }
#pragma unroll
        for (int o = 1; o < 16; o <<= 1) sc += __shfl_xor(sc, o);
        float mn = fmaxf(m, sc);
        float r  = expf(m - mn);
        float p  = expf(sc - mn);
        l = l * r + p;
#pragma unroll
        for (int k = 0; k < 8; k++) acc[k] = acc[k] * r + p * x[k];
        m = mn;
    }
    float inv = 1.f / (l + 1e-16f);

    // heads-mean (+conv bias)
#pragma unroll
    for (int k = 0; k < 8; k++) {
        float v = acc[k] * inv;
        v += __shfl_xor(v, 16);
        v += __shfl_xor(v, 32);
        acc[k] = 0.25f * v + conv_b[cb + k];
    }
    // layernorm over 128 channels
    float ssum = 0.f;
#pragma unroll
    for (int k = 0; k < 8; k++) ssum += acc[k];
#pragma unroll
    for (int o = 1; o < 16; o <<= 1) ssum += __shfl_xor(ssum, o);
    float mu = ssum * (1.f / 128.f);
    float vs = 0.f;
#pragma unroll
    for (int k = 0; k < 8; k++) { float d = acc[k] - mu; vs = fmaf(d, d, vs); }
#pragma unroll
    for (int o = 1; o < 16; o <<= 1) vs += __shfl_xor(vs, o);
    float rstd = 1.f / sqrtf(vs * (1.f / 128.f) + 1e-5f);

    float outv[8];
#pragma unroll
    for (int k = 0; k < 8; k++)
        outv[k] = (acc[k] - mu) * rstd * lnw[cb + k] + lnb[cb + k];

    if (h == 0) {
        size_t b = (size_t)wv * 128 + cb;
        float4 o0 = make_float4(outv[0], outv[1], outv[2], outv[3]);
        float4 o1 = make_float4(outv[4], outv[5], outv[6], outv[7]);
        *(float4*)&seq_l[b]     = o0;
        *(float4*)&seq_l[b + 4] = o1;
        bf16x8 ob;
#pragma unroll
        for (int k = 0; k < 8; k++) ob[k] = (short)f2b(outv[k]);
        *(bf16x8*)&seqb_l[b] = ob;
    }
}

// ---------------- fused LSTM cell + JK partial score ----------------
__global__ void lstm_cell_fused_kernel(const float* __restrict__ gates,
                                       const float* __restrict__ bih, const float* __restrict__ bhh,
                                       float* __restrict__ c, unsigned short* __restrict__ hb16,
                                       const float* __restrict__ jkw, int jkoff,
                                       float* __restrict__ score_t, int first) {
    int wid = (blockIdx.x * blockDim.x + threadIdx.x) >> 6;
    int lane = threadIdx.x & 63;
    if (wid >= cN) return;
    const float* g = gates + (size_t)wid * c4HL;
    float jacc = 0.f;
#pragma unroll
    for (int q = 0; q < 5; q++) {
        int u = lane + (q << 6);
        float gi  = g[u]            + bih[u]            + bhh[u];
        float gf_ = g[cHL + u]      + bih[cHL + u]      + bhh[cHL + u];
        float gg  = g[2 * cHL + u]  + bih[2 * cHL + u]  + bhh[2 * cHL + u];
        float go  = g[3 * cHL + u]  + bih[3 * cHL + u]  + bhh[3 * cHL + u];
        float si = 1.f / (1.f + expf(-gi));
        float sf = 1.f / (1.f + expf(-gf_));
        float so = 1.f / (1.f + expf(-go));
        float tg = tanhf(gg);
        size_t idx = (size_t)wid * cHL + u;
        float cold = first ? 0.f : c[idx];
        float cc = sf * cold + si * tg;
        c[idx] = cc;
        float hh = so * tanhf(cc);
        hb16[idx] = f2b(hh);
        jacc += hh * jkw[jkoff + u];
    }
    for (int o = 32; o; o >>= 1) jacc += __shfl_xor(jacc, o);
    if (lane == 0) score_t[wid] += jacc;
}

// ---------------- JK softmax + mean pooling ----------------
__global__ void jk_pool_kernel(const float* __restrict__ seq, const float* __restrict__ score,
                               const int* __restrict__ batch, float* __restrict__ pooled) {
    int wid = (blockIdx.x * blockDim.x + threadIdx.x) >> 6;
    int lane = threadIdx.x & 63;
    if (wid >= cN) return;
    float s[cL], mx = -INFINITY;
#pragma unroll
    for (int l = 0; l < cL; l++) { s[l] = score[(size_t)l * cN + wid]; mx = fmaxf(mx, s[l]); }
    float se = 0.f;
#pragma unroll
    for (int l = 0; l < cL; l++) { s[l] = expf(s[l] - mx); se += s[l]; }
    float inv = 1.f / se;
    int g = batch[wid];
    float acc0 = 0.f, acc1 = 0.f;
#pragma unroll
    for (int l = 0; l < cL; l++) {
        const float* sp = seq + ((size_t)l * cN + wid) * 128;
        float w = s[l] * inv;
        acc0 += w * sp[lane];
        acc1 += w * sp[lane + 64];
    }
    atomicAdd(&pooled[(size_t)g * 128 + lane], acc0);
    atomicAdd(&pooled[(size_t)g * 128 + lane + 64], acc1);
}

__global__ void count_kernel(const int* __restrict__ batch, float* __restrict__ cnt) {
    int i = blockIdx.x * blockDim.x + threadIdx.x;
    if (i < cN) atomicAdd(&cnt[batch[i]], 1.f);
}

__global__ void div_pool_kernel(float* __restrict__ pooled, const float* __restrict__ cnt) {
    int i = blockIdx.x * blockDim.x + threadIdx.x;
    if (i < cG * 128) pooled[i] /= fmaxf(cnt[i >> 7], 1.f);
}

// ---------------- fused MLP head ----------------
// out = relu(pooled@m1_w+m1_b)@m2_w + m2_b + pooled@res_w + res_b
// block = 4 pooled rows x 256 out cols; hdn recomputed per block in LDS (cheap).
__global__ __launch_bounds__(256)
void head_fused_kernel(const float* __restrict__ pooled,
                       const float* __restrict__ m1_w, const float* __restrict__ m1_b,
                       const float* __restrict__ m2_w, const float* __restrict__ m2_b,
                       const float* __restrict__ res_w, const float* __restrict__ res_b,
                       float* __restrict__ out) {
    __shared__ float pl[4][128];
    __shared__ float hd[4][128];
    const int tid = threadIdx.x;
    const int r0 = blockIdx.y << 2;
    const int c0 = blockIdx.x << 8;
#pragma unroll
    for (int e = tid; e < 512; e += 256) {
        int r = e >> 7, k = e & 127;
        pl[r][k] = pooled[(size_t)(r0 + r) * 128 + k];   // 125*4 == 500 exact
    }
    __syncthreads();
#pragma unroll
    for (int e = tid; e < 512; e += 256) {
        int r = e >> 7, n = e & 127;
        float acc = m1_b[n];
#pragma unroll 8
        for (int k = 0; k < 128; k++) acc = fmaf(pl[r][k], m1_w[k * 128 + n], acc);
        hd[r][n] = fmaxf(acc, 0.f);
    }
    __syncthreads();
    int col = c0 + tid;
    if (col >= cOUT) return;
    float b = m2_b[col] + res_b[col];
    float acc[4] = {b, b, b, b};
    for (int k = 0; k < 128; k++) {
        float w2 = m2_w[(size_t)k * cOUT + col];
        float wr = res_w[(size_t)k * cOUT + col];
#pragma unroll
        for (int r = 0; r < 4; r++)
            acc[r] = fmaf(hd[r][k], w2, fmaf(pl[r][k], wr, acc[r]));
    }
#pragma unroll
    for (int r = 0; r < 4; r++)
        out[(size_t)(r0 + r) * cOUT + col] = acc[r];
}

// ---------------- launch helpers ----------------
static inline int ceil_div(long a, long b) { return (int)((a + b - 1) / b); }

template<int OUTB>
static void launch_mfma(const unsigned short* A1, const unsigned short* B1, int k1,
                        const unsigned short* A2, const unsigned short* B2, int k2,
                        const float* bias, void* C, int M, int N, hipStream_t s) {
    dim3 g((N + 127) >> 7, (M + 127) >> 7);
    if (bias) gemm_mfma_kernel<1, OUTB><<<g, 256, 0, s>>>(A1, B1, k1, A2, B2, k2, bias, C, M, N);
    else      gemm_mfma_kernel<0, OUTB><<<g, 256, 0, s>>>(A1, B1, k1, A2, B2, k2, bias, C, M, N);
}

static void fillF(float* p, long n, float v, hipStream_t s) {
    fill_f32_kernel<<<ceil_div(n, 256), 256, 0, s>>>(p, n, v);
}
static void fillI(int* p, long n, int v, hipStream_t s) {
    fill_i32_kernel<<<ceil_div(n, 256), 256, 0, s>>>(p, n, v);
}
static void convB(const float* a, unsigned short* b, long n, hipStream_t s) {
    conv_bf16_kernel<<<ceil_div(n, 256), 256, 0, s>>>(a, b, n);
}

extern "C" void kernel_launch(void* const* d_in, const int* in_sizes, int n_in,
                              void* d_out, int out_size, void* d_ws, size_t ws_size,
                              hipStream_t stream) {
    const float* x      = (const float*)d_in[0];
    const int*   ei     = (const int*)d_in[1];
    const int*   batch  = (const int*)d_in[2];
    const float* emb_W  = (const float*)d_in[3];
    const float* emb_b  = (const float*)d_in[4];
    const float* Wl     = (const float*)d_in[5];
    const float* bl     = (const float*)d_in[6];
    const float* Wr     = (const float*)d_in[7];
    const float* br     = (const float*)d_in[8];
    const float* att_a  = (const float*)d_in[9];
    const float* conv_b = (const float*)d_in[10];
    const float* ln_w   = (const float*)d_in[11];
    const float* ln_b   = (const float*)d_in[12];
    const float* Wih_f  = (const float*)d_in[13];
    const float* Whh_f  = (const float*)d_in[14];
    const float* bih_f  = (const float*)d_in[15];
    const float* bhh_f  = (const float*)d_in[16];
    const float* Wih_b  = (const float*)d_in[17];
    const float* Whh_b  = (const float*)d_in[18];
    const float* bih_b  = (const float*)d_in[19];
    const float* bhh_b  = (const float*)d_in[20];
    const float* jk_w   = (const float*)d_in[21];
    // d_in[22] = jk_b: constant across L -> softmax-invariant, unused
    const float* m1_w   = (const float*)d_in[23];
    const float* m1_b   = (const float*)d_in[24];
    const float* m2_w   = (const float*)d_in[25];
    const float* m2_b   = (const float*)d_in[26];
    const float* res_w  = (const float*)d_in[27];
    const float* res_b  = (const float*)d_in[28];
    float* out = (float*)d_out;

    const int* src = ei;
    const int* dst = ei + cE;

    // ---------------- workspace layout ----------------
    char* ws = (char*)d_ws;
    size_t off = 0;
    auto alloc = [&](size_t bytes) -> char* {
        size_t o = (off + 255) & ~(size_t)255;
        off = o + bytes;
        return ws + o;
    };
    unsigned short* x16     = (unsigned short*)alloc((size_t)cN * cFin * 2);
    unsigned short* embWT   = (unsigned short*)alloc((size_t)cC * cFin * 2);
    unsigned short* emb_b16 = (unsigned short*)alloc((size_t)cN * cC * 2);
    float*          seq     = (float*)alloc((size_t)cL * cN * cC * 4);
    unsigned short* seqb16  = (unsigned short*)alloc((size_t)cL * cN * cC * 2);
    unsigned short* WT      = (unsigned short*)alloc((size_t)cL * 1024 * 128 * 2);
    float*          bb      = (float*)alloc((size_t)cL * 1024 * 4);
    unsigned short* Wihf16  = (unsigned short*)alloc((size_t)c4HL * cC * 2);
    unsigned short* Whhf16  = (unsigned short*)alloc((size_t)c4HL * cHL * 2);
    unsigned short* Wihb16  = (unsigned short*)alloc((size_t)c4HL * cC * 2);
    unsigned short* Whhb16  = (unsigned short*)alloc((size_t)c4HL * cHL * 2);
    unsigned short* hf16    = (unsigned short*)alloc((size_t)cN * cHL * 2);
    unsigned short* hb16    = (unsigned short*)alloc((size_t)cN * cHL * 2);
    float*          cf      = (float*)alloc((size_t)cN * cHL * 4);
    float*          cb      = (float*)alloc((size_t)cN * cHL * 4);
    float*          jks     = (float*)alloc((size_t)cL * cN * 4);
    float*          pooled  = (float*)alloc((size_t)cG * cC * 4);
    float*          cnt     = (float*)alloc((size_t)cG * 4);
    int*            offs    = (int*)alloc((size_t)(cN + 1) * 4);
    int*            cursor  = (int*)alloc((size_t)cN * 4);
    int*            src_csr = (int*)alloc((size_t)cE * 4);
    // overlapped region: GAT xlr (bf16, 20 MB) vs LSTM gates (fp32, 51 MB)
    size_t gat_bytes  = (size_t)cN * 1024 * 2;
    size_t lstm_bytes = (size_t)cN * c4HL * 4;
    char* region = alloc(gat_bytes > lstm_bytes ? gat_bytes : lstm_bytes);
    unsigned short* xlr = (unsigned short*)region;
    float* gates = (float*)region;   // LSTM view (GAT fully consumed first)

    hipStream_t s = stream;

    // ---------------- CSR by dst (payload = src) ----------------
    fillI(cursor, cN, 0, s);
    hist_kernel<<<ceil_div(cE, 256), 256, 0, s>>>(dst, cursor);
    scan_kernel<<<1, 256, 0, s>>>(cursor, offs);
    copy_i32_kernel<<<ceil_div(cN, 256), 256, 0, s>>>(offs, cursor, cN);
    scatter_kernel<<<ceil_div(cE, 256), 256, 0, s>>>(src, dst, cursor, src_csr);

    // ---------------- weight prep (bf16) ----------------
    wproj_prep_kernel<<<ceil_div((long)cL * 1024 * 128, 256), 256, 0, s>>>(Wl, Wr, WT);
    bias_prep_kernel<<<ceil_div((long)cL * 1024, 256), 256, 0, s>>>(bl, br, bb);
    embw_prep_kernel<<<ceil_div((long)cC * cFin, 256), 256, 0, s>>>(emb_W, embWT);
    convB(x, x16, (long)cN * cFin, s);
    convB(Wih_f, Wihf16, (long)c4HL * cC, s);
    convB(Whh_f, Whhf16, (long)c4HL * cHL, s);
    convB(Wih_b, Wihb16, (long)c4HL * cC, s);
    convB(Whh_b, Whhb16, (long)c4HL * cHL, s);

    // ---------------- embedding (bf16 MFMA, direct bf16 out) ----------------
    launch_mfma<1>(x16, embWT, cFin, nullptr, nullptr, 0, emb_b, emb_b16, cN, cC, s);

    // ---------------- GAT layers ----------------
    for (int l = 0; l < cL; l++) {
        const unsigned short* hin = (l == 0) ? emb_b16 : seqb16 + (size_t)(l - 1) * cN * cC;
        launch_mfma<1>(hin, WT + (size_t)l * 1024 * 128, cC, nullptr, nullptr, 0,
                       bb + (size_t)l * 1024, xlr, cN, 1024, s);
        gat_fused_kernel<<<ceil_div((long)cN * 64, 256), 256, 0, s>>>(
            xlr, src_csr, offs, att_a + (size_t)l * cH * cC,
            conv_b + (size_t)l * cC, ln_w + (size_t)l * cC, ln_b + (size_t)l * cC,
            seq + (size_t)l * cN * cC, seqb16 + (size_t)l * cN * cC);
    }

    // ---------------- bidirectional LSTM + JK scores ----------------
    fillF(jks, (long)cL * cN, 0.f, s);
    for (int k = 0; k < cL; k++) {
        int first = (k == 0);
        // forward step: t = k
        launch_mfma<0>(seqb16 + (size_t)k * cN * cC, Wihf16, cC,
                       hf16, Whhf16, first ? 0 : cHL, nullptr, gates, cN, c4HL, s);
        lstm_cell_fused_kernel<<<ceil_div((long)cN * 64, 256), 256, 0, s>>>(
            gates, bih_f, bhh_f, cf, hf16, jk_w, 0, jks + (size_t)k * cN, first);
        // backward step: t = L-1-k
        int t = cL - 1 - k;
        launch_mfma<0>(seqb16 + (size_t)t * cN * cC, Wihb16, cC,
                       hb16, Whhb16, first ? 0 : cHL, nullptr, gates, cN, c4HL, s);
        lstm_cell_fused_kernel<<<ceil_div((long)cN * 64, 256), 256, 0, s>>>(
            gates, bih_b, bhh_b, cb, hb16, jk_w, cHL, jks + (size_t)t * cN, first);
    }

    // ---------------- JK softmax, pooling, fused head ----------------
    fillF(pooled, (long)cG * cC, 0.f, s);
    fillF(cnt, cG, 0.f, s);
    jk_pool_kernel<<<ceil_div((long)cN * 64, 256), 256, 0, s>>>(seq, jks, batch, pooled);
    count_kernel<<<ceil_div(cN, 256), 256, 0, s>>>(batch, cnt);
    div_pool_kernel<<<ceil_div((long)cG * 128, 256), 256, 0, s>>>(pooled, cnt);
    head_fused_kernel<<<dim3(ceil_div(cOUT, 256), cG / 4), 256, 0, s>>>(
        pooled, m1_w, m1_b, m2_w, m2_b, res_w, res_b, out);
}

// Round 6
// 895.606 us; speedup vs baseline: 4.3498x; 1.0010x over previous
//
#include <hip/hip_runtime.h>
#include <hip/hip_bf16.h>
#include <math.h>

// Problem constants (from reference)
constexpr int cN   = 10000;
constexpr int cE   = 120000;
constexpr int cFin = 64;
constexpr int cC   = 128;
constexpr int cH   = 4;
constexpr int cL   = 5;
constexpr int cG   = 500;
constexpr int cOUT = 1801;
constexpr int cHL  = 320;          // (L*C)/2
constexpr int c4HL = 4 * cHL;      // 1280

typedef short bf16x8 __attribute__((ext_vector_type(8)));
typedef float f32x4 __attribute__((ext_vector_type(4)));

__device__ inline unsigned short f2b(float x) {
    union { __hip_bfloat16 h; unsigned short u; } cv;
    cv.h = __float2bfloat16(x);
    return cv.u;
}
__device__ inline float b2f(unsigned short u) {
    union { unsigned int i; float f; } cv;
    cv.i = ((unsigned int)u) << 16;
    return cv.f;
}

#define GLD16(g, l) __builtin_amdgcn_global_load_lds( \
    (const __attribute__((address_space(1))) unsigned int*)(g), \
    (__attribute__((address_space(3))) unsigned int*)(l), 16, 0, 0)

// ---------------- utility kernels ----------------
__global__ void fill_f32_kernel(float* __restrict__ p, long n, float v) {
    long i = (long)blockIdx.x * blockDim.x + threadIdx.x;
    if (i < n) p[i] = v;
}
__global__ void fill_i32_kernel(int* __restrict__ p, long n, int v) {
    long i = (long)blockIdx.x * blockDim.x + threadIdx.x;
    if (i < n) p[i] = v;
}
__global__ void copy_i32_kernel(const int* __restrict__ a, int* __restrict__ b, long n) {
    long i = (long)blockIdx.x * blockDim.x + threadIdx.x;
    if (i < n) b[i] = a[i];
}
__global__ void conv_bf16_kernel(const float* __restrict__ a, unsigned short* __restrict__ b, long n) {
    long i = (long)blockIdx.x * blockDim.x + threadIdx.x;
    if (i < n) b[i] = f2b(a[i]);
}
// Wl,Wr: [L][128][512] fp32 -> WT: [L][1024][128] bf16 (rows 0..511 = Wl^T, 512..1023 = Wr^T)
__global__ void wproj_prep_kernel(const float* __restrict__ Wl, const float* __restrict__ Wr,
                                  unsigned short* __restrict__ WT) {
    long i = (long)blockIdx.x * blockDim.x + threadIdx.x;
    if (i >= (long)cL * 1024 * 128) return;
    int k = i & 127;
    int n = (int)((i >> 7) & 1023);
    int l = (int)(i >> 17);
    const float* W = (n < 512) ? Wl : Wr;
    int nn = n & 511;
    WT[i] = f2b(W[(size_t)l * 65536 + (size_t)k * 512 + nn]);
}
// bl,br: [L][512] -> bb: [L][1024]
__global__ void bias_prep_kernel(const float* __restrict__ bl, const float* __restrict__ br,
                                 float* __restrict__ bb) {
    int i = blockIdx.x * blockDim.x + threadIdx.x;
    if (i >= cL * 1024) return;
    int n = i & 1023, l = i >> 10;
    bb[i] = (n < 512) ? bl[l * 512 + n] : br[l * 512 + (n - 512)];
}
// emb_W: [64][128] fp32 (KxN) -> embWT: [128][64] bf16 (NxK)
__global__ void embw_prep_kernel(const float* __restrict__ W, unsigned short* __restrict__ WT) {
    int i = blockIdx.x * blockDim.x + threadIdx.x;
    if (i >= cC * cFin) return;
    int k = i & 63, n = i >> 6;
    WT[i] = f2b(W[(size_t)k * cC + n]);
}
// LSTM weights -> gate-interleaved rows: p = (u>>4)*64 + g*16 + (u&15), r = g*320+u
// WihP [1280][128] bf16, WhhP [1280][320] bf16, biasP[1280] = bih[r]+bhh[r]
__global__ void lstm_prep_kernel(const float* __restrict__ Wih, const float* __restrict__ Whh,
                                 const float* __restrict__ bih, const float* __restrict__ bhh,
                                 unsigned short* __restrict__ WihP, unsigned short* __restrict__ WhhP,
                                 float* __restrict__ biasP) {
    long i = (long)blockIdx.x * blockDim.x + threadIdx.x;   // over 1280*449
    if (i >= (long)c4HL * 449) return;
    int p = (int)(i / 449), c = (int)(i % 449);
    int u = (p >> 6) * 16 + (p & 15);
    int g = (p >> 4) & 3;
    int r = g * cHL + u;
    if (c < cC)       WihP[(size_t)p * cC + c] = f2b(Wih[(size_t)r * cC + c]);
    else if (c < 448) WhhP[(size_t)p * cHL + (c - cC)] = f2b(Whh[(size_t)r * cHL + (c - cC)]);
    else              biasP[p] = bih[r] + bhh[r];
}

// ---------------- CSR build (by dst), payload = src node ----------------
__global__ void hist_kernel(const int* __restrict__ dst, int* __restrict__ count) {
    int i = blockIdx.x * blockDim.x + threadIdx.x;
    if (i < cE) atomicAdd(&count[dst[i]], 1);
}
__global__ void scan_kernel(const int* __restrict__ count, int* __restrict__ offs) {
    __shared__ int part[256];
    const int tid = threadIdx.x;
    const int CH = (cN + 255) / 256;
    int base = tid * CH;
    int s = 0;
    for (int i = 0; i < CH; i++) {
        int idx = base + i;
        if (idx < cN) s += count[idx];
    }
    part[tid] = s;
    __syncthreads();
    for (int d = 1; d < 256; d <<= 1) {
        int v = 0;
        if (tid >= d) v = part[tid - d];
        __syncthreads();
        if (tid >= d) part[tid] += v;
        __syncthreads();
    }
    int prefix = (tid == 0) ? 0 : part[tid - 1];
    for (int i = 0; i < CH; i++) {
        int idx = base + i;
        if (idx < cN) { offs[idx] = prefix; prefix += count[idx]; }
    }
    if (tid == 255) offs[cN] = prefix;
}
__global__ void scatter_kernel(const int* __restrict__ src, const int* __restrict__ dst,
                               int* __restrict__ cursor, int* __restrict__ src_csr) {
    int i = blockIdx.x * blockDim.x + threadIdx.x;
    if (i < cE) {
        int pos = atomicAdd(&cursor[dst[i]], 1);
        src_csr[pos] = src[i];
    }
}

// ---------------- bf16 MFMA GEMM (plain epilogue) ----------------
// C[M,N] = A@B^T (+bias). 128x128 tile, BK=32, 4 waves, mfma_f32_16x16x32_bf16.
template<int HASBIAS, int OUTB>
__global__ __launch_bounds__(256)
void gemm_mfma_kernel(const unsigned short* __restrict__ A1, const unsigned short* __restrict__ B1, int k1,
                      const unsigned short* __restrict__ A2, const unsigned short* __restrict__ B2, int k2,
                      const float* __restrict__ bias, void* __restrict__ Cout, int M, int N) {
    __shared__ unsigned short lds[2][2][128 * 32];
    const int tid  = threadIdx.x;
    const int lane = tid & 63;
    const int wave = tid >> 6;
    const int bm = blockIdx.y << 7;
    const int bn = blockIdx.x << 7;
    const int wr = (wave >> 1) << 6;
    const int wc = (wave & 1) << 6;
    const int ns1 = k1 >> 5, ns2 = k2 >> 5, ns = ns1 + ns2;

    const int lrow = lane >> 2;
    const int lke  = (lane & 3) << 3;

    auto stage = [&](int s, int buf) {
        const unsigned short *Ab, *Bb;
        int stride, koff;
        if (s < ns1) { Ab = A1; Bb = B1; stride = k1; koff = s << 5; }
        else         { Ab = A2; Bb = B2; stride = k2; koff = (s - ns1) << 5; }
#pragma unroll
        for (int r = 0; r < 2; r++) {
            int ch  = wave * 2 + r;
            int row = ch * 16 + lrow;
            int ga  = bm + row; if (ga >= M) ga = M - 1;
            GLD16(Ab + (size_t)ga * stride + koff + lke, &lds[buf][0][ch * 512]);
            GLD16(Bb + (size_t)(bn + row) * stride + koff + lke, &lds[buf][1][ch * 512]);
        }
    };

    f32x4 acc[4][4];
#pragma unroll
    for (int i = 0; i < 4; i++)
#pragma unroll
        for (int j = 0; j < 4; j++) acc[i][j] = (f32x4){0.f, 0.f, 0.f, 0.f};

    stage(0, 0);
    const int ko  = (lane >> 4) << 3;
    const int rla = lane & 15;
    for (int s = 0; s < ns; s++) {
        int buf = s & 1;
        __syncthreads();
        if (s + 1 < ns) stage(s + 1, buf ^ 1);
        bf16x8 af[4], bff[4];
#pragma unroll
        for (int f = 0; f < 4; f++) {
            af[f]  = *(const bf16x8*)&lds[buf][0][(wr + f * 16 + rla) * 32 + ko];
            bff[f] = *(const bf16x8*)&lds[buf][1][(wc + f * 16 + rla) * 32 + ko];
        }
#pragma unroll
        for (int i = 0; i < 4; i++)
#pragma unroll
            for (int j = 0; j < 4; j++)
                acc[i][j] = __builtin_amdgcn_mfma_f32_16x16x32_bf16(af[i], bff[j], acc[i][j], 0, 0, 0);
    }

#pragma unroll
    for (int i = 0; i < 4; i++) {
#pragma unroll
        for (int v = 0; v < 4; v++) {
            int m = bm + wr + i * 16 + ((lane >> 4) << 2) + v;
            if (m < M) {
#pragma unroll
                for (int j = 0; j < 4; j++) {
                    int n = bn + wc + j * 16 + rla;
                    float val = acc[i][j][v];
                    if (HASBIAS) val += bias[n];
                    if (OUTB) ((unsigned short*)Cout)[(size_t)m * N + n] = f2b(val);
                    else      ((float*)Cout)[(size_t)m * N + n] = val;
                }
            }
        }
    }
}

// ---------------- LSTM step: GEMM + fused cell + JK score ----------------
// gates = seq_t @ WihP^T + h_prev @ WhhP^T (+biasP), gate-interleaved cols.
// Per lane: j=0..3 are gates i,f,g,o of unit u = ((bn+wc)>>6)*16 + rla.
// Epilogue: cell update (c in/out), h -> bf16 hOut, JK partial -> atomicAdd.
template<int FIRST>
__global__ __launch_bounds__(256)
void gemm_lstm_kernel(const unsigned short* __restrict__ A1, const unsigned short* __restrict__ B1,
                      const unsigned short* __restrict__ A2, const unsigned short* __restrict__ B2,
                      const float* __restrict__ biasP, float* __restrict__ cbuf,
                      unsigned short* __restrict__ hOut, const float* __restrict__ jkw,
                      float* __restrict__ score_t) {
    constexpr int M = cN, k1 = cC, k2 = FIRST ? 0 : cHL;
    __shared__ unsigned short lds[2][2][128 * 32];
    const int tid  = threadIdx.x;
    const int lane = tid & 63;
    const int wave = tid >> 6;
    const int bm = blockIdx.y << 7;
    const int bn = blockIdx.x << 7;
    const int wr = (wave >> 1) << 6;
    const int wc = (wave & 1) << 6;
    const int ns1 = k1 >> 5, ns2 = k2 >> 5, ns = ns1 + ns2;

    const int lrow = lane >> 2;
    const int lke  = (lane & 3) << 3;

    auto stage = [&](int s, int buf) {
        const unsigned short *Ab, *Bb;
        int stride, koff;
        if (s < ns1) { Ab = A1; Bb = B1; stride = k1; koff = s << 5; }
        else         { Ab = A2; Bb = B2; stride = k2; koff = (s - ns1) << 5; }
#pragma unroll
        for (int r = 0; r < 2; r++) {
            int ch  = wave * 2 + r;
            int row = ch * 16 + lrow;
            int ga  = bm + row; if (ga >= M) ga = M - 1;
            GLD16(Ab + (size_t)ga * stride + koff + lke, &lds[buf][0][ch * 512]);
            GLD16(Bb + (size_t)(bn + row) * stride + koff + lke, &lds[buf][1][ch * 512]);
        }
    };

    f32x4 acc[4][4];
#pragma unroll
    for (int i = 0; i < 4; i++)
#pragma unroll
        for (int j = 0; j < 4; j++) acc[i][j] = (f32x4){0.f, 0.f, 0.f, 0.f};

    stage(0, 0);
    const int ko  = (lane >> 4) << 3;
    const int rla = lane & 15;
    for (int s = 0; s < ns; s++) {
        int buf = s & 1;
        __syncthreads();
        if (s + 1 < ns) stage(s + 1, buf ^ 1);
        bf16x8 af[4], bff[4];
#pragma unroll
        for (int f = 0; f < 4; f++) {
            af[f]  = *(const bf16x8*)&lds[buf][0][(wr + f * 16 + rla) * 32 + ko];
            bff[f] = *(const bf16x8*)&lds[buf][1][(wc + f * 16 + rla) * 32 + ko];
        }
#pragma unroll
        for (int i = 0; i < 4; i++)
#pragma unroll
            for (int j = 0; j < 4; j++)
                acc[i][j] = __builtin_amdgcn_mfma_f32_16x16x32_bf16(af[i], bff[j], acc[i][j], 0, 0, 0);
    }

    // gate-fused epilogue
    float bias4[4];
#pragma unroll
    for (int j = 0; j < 4; j++) bias4[j] = biasP[bn + wc + j * 16 + rla];
    const int u = ((bn + wc) >> 6) * 16 + rla;
    const float jw = jkw[u];

#pragma unroll
    for (int i = 0; i < 4; i++) {
#pragma unroll
        for (int v = 0; v < 4; v++) {
            int m = bm + wr + i * 16 + ((lane >> 4) << 2) + v;
            bool ok = (m < M);                      // uniform across rla group
            float gi = acc[i][0][v] + bias4[0];
            float gf = acc[i][1][v] + bias4[1];
            float gg = acc[i][2][v] + bias4[2];
            float go = acc[i][3][v] + bias4[3];
            float si = 1.f / (1.f + expf(-gi));
            float sf = 1.f / (1.f + expf(-gf));
            float so = 1.f / (1.f + expf(-go));
            float tg = tanhf(gg);
            size_t idx = (size_t)m * cHL + u;
            float cold = (FIRST || !ok) ? 0.f : cbuf[idx];
            float cc = sf * cold + si * tg;
            float hh = so * tanhf(cc);
            if (ok) { cbuf[idx] = cc; hOut[idx] = f2b(hh); }
            float part = ok ? hh * jw : 0.f;
#pragma unroll
            for (int o = 1; o < 16; o <<= 1) part += __shfl_xor(part, o);
            if (rla == 0 && ok) atomicAdd(&score_t[m], part);
        }
    }
}

// ---------------- fused GAT layer: one wave per node ----------------
__global__ __launch_bounds__(256)
void gat_fused_kernel(const unsigned short* __restrict__ xlr, const int* __restrict__ src_csr,
                      const int* __restrict__ offs, const float* __restrict__ att,
                      const float* __restrict__ conv_b, const float* __restrict__ lnw,
                      const float* __restrict__ lnb, float* __restrict__ seq_l,
                      unsigned short* __restrict__ seqb_l) {
    const int wv   = (blockIdx.x * blockDim.x + threadIdx.x) >> 6;  // node
    const int lane = threadIdx.x & 63;
    if (wv >= cN) return;
    const int h   = lane >> 4;
    const int cb  = (lane & 15) << 3;

    bf16x8 xrv = *(const bf16x8*)&xlr[(size_t)wv * 1024 + 512 + lane * 8];
    float xr[8], av[8];
#pragma unroll
    for (int k = 0; k < 8; k++) {
        xr[k] = b2f((unsigned short)xrv[k]);
        av[k] = att[h * 128 + cb + k];
    }

    float m = -INFINITY, l = 0.f;
    float acc[8];
#pragma unroll
    for (int k = 0; k < 8; k++) acc[k] = 0.f;

    const int beg = offs[wv], end = offs[wv + 1];
    for (int j = beg; j < end; j++) {
        int s = src_csr[j];
        bf16x8 xv = *(const bf16x8*)&xlr[(size_t)s * 1024 + lane * 8];
        float x[8], sc = 0.f;
#pragma unroll
        for (int k = 0; k < 8; k++) {
            x[k] = b2f((unsigned short)xv[k]);
            float v = x[k] + xr[k];
            v = v > 0.f ? v : 0.2f * v;
            sc = fmaf(v, av[k], sc);
        }
#pragma unroll
        for (int o = 1; o < 16; o <<= 1) sc += __shfl_xor(sc, o);
        float mn = fmaxf(m, sc);
        float r  = expf(m - mn);
        float p  = expf(sc - mn);
        l = l * r + p;
#pragma unroll
        for (int k = 0; k < 8; k++) acc[k] = acc[k] * r + p * x[k];
        m = mn;
    }
    float inv = 1.f / (l + 1e-16f);

#pragma unroll
    for (int k = 0; k < 8; k++) {
        float v = acc[k] * inv;
        v += __shfl_xor(v, 16);
        v += __shfl_xor(v, 32);
        acc[k] = 0.25f * v + conv_b[cb + k];
    }
    float ssum = 0.f;
#pragma unroll
    for (int k = 0; k < 8; k++) ssum += acc[k];
#pragma unroll
    for (int o = 1; o < 16; o <<= 1) ssum += __shfl_xor(ssum, o);
    float mu = ssum * (1.f / 128.f);
    float vs = 0.f;
#pragma unroll
    for (int k = 0; k < 8; k++) { float d = acc[k] - mu; vs = fmaf(d, d, vs); }
#pragma unroll
    for (int o = 1; o < 16; o <<= 1) vs += __shfl_xor(vs, o);
    float rstd = 1.f / sqrtf(vs * (1.f / 128.f) + 1e-5f);

    float outv[8];
#pragma unroll
    for (int k = 0; k < 8; k++)
        outv[k] = (acc[k] - mu) * rstd * lnw[cb + k] + lnb[cb + k];

    if (h == 0) {
        size_t b = (size_t)wv * 128 + cb;
        float4 o0 = make_float4(outv[0], outv[1], outv[2], outv[3]);
        float4 o1 = make_float4(outv[4], outv[5], outv[6], outv[7]);
        *(float4*)&seq_l[b]     = o0;
        *(float4*)&seq_l[b + 4] = o1;
        bf16x8 ob;
#pragma unroll
        for (int k = 0; k < 8; k++) ob[k] = (short)f2b(outv[k]);
        *(bf16x8*)&seqb_l[b] = ob;
    }
}

// ---------------- JK softmax + mean pooling ----------------
__global__ void jk_pool_kernel(const float* __restrict__ seq, const float* __restrict__ score,
                               const int* __restrict__ batch, float* __restrict__ pooled) {
    int wid = (blockIdx.x * blockDim.x + threadIdx.x) >> 6;
    int lane = threadIdx.x & 63;
    if (wid >= cN) return;
    float s[cL], mx = -INFINITY;
#pragma unroll
    for (int l = 0; l < cL; l++) { s[l] = score[(size_t)l * cN + wid]; mx = fmaxf(mx, s[l]); }
    float se = 0.f;
#pragma unroll
    for (int l = 0; l < cL; l++) { s[l] = expf(s[l] - mx); se += s[l]; }
    float inv = 1.f / se;
    int g = batch[wid];
    float acc0 = 0.f, acc1 = 0.f;
#pragma unroll
    for (int l = 0; l < cL; l++) {
        const float* sp = seq + ((size_t)l * cN + wid) * 128;
        float w = s[l] * inv;
        acc0 += w * sp[lane];
        acc1 += w * sp[lane + 64];
    }
    atomicAdd(&pooled[(size_t)g * 128 + lane], acc0);
    atomicAdd(&pooled[(size_t)g * 128 + lane + 64], acc1);
}

__global__ void count_kernel(const int* __restrict__ batch, float* __restrict__ cnt) {
    int i = blockIdx.x * blockDim.x + threadIdx.x;
    if (i < cN) atomicAdd(&cnt[batch[i]], 1.f);
}

__global__ void div_pool_kernel(float* __restrict__ pooled, const float* __restrict__ cnt) {
    int i = blockIdx.x * blockDim.x + threadIdx.x;
    if (i < cG * 128) pooled[i] /= fmaxf(cnt[i >> 7], 1.f);
}

// ---------------- fused MLP head ----------------
__global__ __launch_bounds__(256)
void head_fused_kernel(const float* __restrict__ pooled,
                       const float* __restrict__ m1_w, const float* __restrict__ m1_b,
                       const float* __restrict__ m2_w, const float* __restrict__ m2_b,
                       const float* __restrict__ res_w, const float* __restrict__ res_b,
                       float* __restrict__ out) {
    __shared__ float pl[4][128];
    __shared__ float hd[4][128];
    const int tid = threadIdx.x;
    const int r0 = blockIdx.y << 2;
    const int c0 = blockIdx.x << 8;
#pragma unroll
    for (int e = tid; e < 512; e += 256) {
        int r = e >> 7, k = e & 127;
        pl[r][k] = pooled[(size_t)(r0 + r) * 128 + k];
    }
    __syncthreads();
#pragma unroll
    for (int e = tid; e < 512; e += 256) {
        int r = e >> 7, n = e & 127;
        float acc = m1_b[n];
#pragma unroll 8
        for (int k = 0; k < 128; k++) acc = fmaf(pl[r][k], m1_w[k * 128 + n], acc);
        hd[r][n] = fmaxf(acc, 0.f);
    }
    __syncthreads();
    int col = c0 + tid;
    if (col >= cOUT) return;
    float b = m2_b[col] + res_b[col];
    float acc[4] = {b, b, b, b};
    for (int k = 0; k < 128; k++) {
        float w2 = m2_w[(size_t)k * cOUT + col];
        float wr = res_w[(size_t)k * cOUT + col];
#pragma unroll
        for (int r = 0; r < 4; r++)
            acc[r] = fmaf(hd[r][k], w2, fmaf(pl[r][k], wr, acc[r]));
    }
#pragma unroll
    for (int r = 0; r < 4; r++)
        out[(size_t)(r0 + r) * cOUT + col] = acc[r];
}

// ---------------- launch helpers ----------------
static inline int ceil_div(long a, long b) { return (int)((a + b - 1) / b); }

template<int OUTB>
static void launch_mfma(const unsigned short* A1, const unsigned short* B1, int k1,
                        const unsigned short* A2, const unsigned short* B2, int k2,
                        const float* bias, void* C, int M, int N, hipStream_t s) {
    dim3 g((N + 127) >> 7, (M + 127) >> 7);
    if (bias) gemm_mfma_kernel<1, OUTB><<<g, 256, 0, s>>>(A1, B1, k1, A2, B2, k2, bias, C, M, N);
    else      gemm_mfma_kernel<0, OUTB><<<g, 256, 0, s>>>(A1, B1, k1, A2, B2, k2, bias, C, M, N);
}

static void fillF(float* p, long n, float v, hipStream_t s) {
    fill_f32_kernel<<<ceil_div(n, 256), 256, 0, s>>>(p, n, v);
}
static void fillI(int* p, long n, int v, hipStream_t s) {
    fill_i32_kernel<<<ceil_div(n, 256), 256, 0, s>>>(p, n, v);
}
static void convB(const float* a, unsigned short* b, long n, hipStream_t s) {
    conv_bf16_kernel<<<ceil_div(n, 256), 256, 0, s>>>(a, b, n);
}

extern "C" void kernel_launch(void* const* d_in, const int* in_sizes, int n_in,
                              void* d_out, int out_size, void* d_ws, size_t ws_size,
                              hipStream_t stream) {
    const float* x      = (const float*)d_in[0];
    const int*   ei     = (const int*)d_in[1];
    const int*   batch  = (const int*)d_in[2];
    const float* emb_W  = (const float*)d_in[3];
    const float* emb_b  = (const float*)d_in[4];
    const float* Wl     = (const float*)d_in[5];
    const float* bl     = (const float*)d_in[6];
    const float* Wr     = (const float*)d_in[7];
    const float* br     = (const float*)d_in[8];
    const float* att_a  = (const float*)d_in[9];
    const float* conv_b = (const float*)d_in[10];
    const float* ln_w   = (const float*)d_in[11];
    const float* ln_b   = (const float*)d_in[12];
    const float* Wih_f  = (const float*)d_in[13];
    const float* Whh_f  = (const float*)d_in[14];
    const float* bih_f  = (const float*)d_in[15];
    const float* bhh_f  = (const float*)d_in[16];
    const float* Wih_b  = (const float*)d_in[17];
    const float* Whh_b  = (const float*)d_in[18];
    const float* bih_b  = (const float*)d_in[19];
    const float* bhh_b  = (const float*)d_in[20];
    const float* jk_w   = (const float*)d_in[21];
    // d_in[22] = jk_b: constant across L -> softmax-invariant, unused
    const float* m1_w   = (const float*)d_in[23];
    const float* m1_b   = (const float*)d_in[24];
    const float* m2_w   = (const float*)d_in[25];
    const float* m2_b   = (const float*)d_in[26];
    const float* res_w  = (const float*)d_in[27];
    const float* res_b  = (const float*)d_in[28];
    float* out = (float*)d_out;

    const int* src = ei;
    const int* dst = ei + cE;

    // ---------------- workspace layout ----------------
    char* ws = (char*)d_ws;
    size_t off = 0;
    auto alloc = [&](size_t bytes) -> char* {
        size_t o = (off + 255) & ~(size_t)255;
        off = o + bytes;
        return ws + o;
    };
    unsigned short* x16     = (unsigned short*)alloc((size_t)cN * cFin * 2);
    unsigned short* embWT   = (unsigned short*)alloc((size_t)cC * cFin * 2);
    unsigned short* emb_b16 = (unsigned short*)alloc((size_t)cN * cC * 2);
    float*          seq     = (float*)alloc((size_t)cL * cN * cC * 4);
    unsigned short* seqb16  = (unsigned short*)alloc((size_t)cL * cN * cC * 2);
    unsigned short* WT      = (unsigned short*)alloc((size_t)cL * 1024 * 128 * 2);
    float*          bb      = (float*)alloc((size_t)cL * 1024 * 4);
    unsigned short* WihPf   = (unsigned short*)alloc((size_t)c4HL * cC * 2);
    unsigned short* WhhPf   = (unsigned short*)alloc((size_t)c4HL * cHL * 2);
    unsigned short* WihPb   = (unsigned short*)alloc((size_t)c4HL * cC * 2);
    unsigned short* WhhPb   = (unsigned short*)alloc((size_t)c4HL * cHL * 2);
    float*          biasPf  = (float*)alloc((size_t)c4HL * 4);
    float*          biasPb  = (float*)alloc((size_t)c4HL * 4);
    unsigned short* hf0     = (unsigned short*)alloc((size_t)cN * cHL * 2);
    unsigned short* hf1     = (unsigned short*)alloc((size_t)cN * cHL * 2);
    unsigned short* hbk0    = (unsigned short*)alloc((size_t)cN * cHL * 2);
    unsigned short* hbk1    = (unsigned short*)alloc((size_t)cN * cHL * 2);
    float*          cf      = (float*)alloc((size_t)cN * cHL * 4);
    float*          cbk     = (float*)alloc((size_t)cN * cHL * 4);
    float*          jks     = (float*)alloc((size_t)cL * cN * 4);
    float*          pooled  = (float*)alloc((size_t)cG * cC * 4);
    float*          cnt     = (float*)alloc((size_t)cG * 4);
    int*            offs    = (int*)alloc((size_t)(cN + 1) * 4);
    int*            cursor  = (int*)alloc((size_t)cN * 4);
    int*            src_csr = (int*)alloc((size_t)cE * 4);
    unsigned short* xlr     = (unsigned short*)alloc((size_t)cN * 1024 * 2);

    hipStream_t s = stream;

    // ---------------- CSR by dst (payload = src) ----------------
    fillI(cursor, cN, 0, s);
    hist_kernel<<<ceil_div(cE, 256), 256, 0, s>>>(dst, cursor);
    scan_kernel<<<1, 256, 0, s>>>(cursor, offs);
    copy_i32_kernel<<<ceil_div(cN, 256), 256, 0, s>>>(offs, cursor, cN);
    scatter_kernel<<<ceil_div(cE, 256), 256, 0, s>>>(src, dst, cursor, src_csr);

    // ---------------- weight prep (bf16) ----------------
    wproj_prep_kernel<<<ceil_div((long)cL * 1024 * 128, 256), 256, 0, s>>>(Wl, Wr, WT);
    bias_prep_kernel<<<ceil_div((long)cL * 1024, 256), 256, 0, s>>>(bl, br, bb);
    embw_prep_kernel<<<ceil_div((long)cC * cFin, 256), 256, 0, s>>>(emb_W, embWT);
    convB(x, x16, (long)cN * cFin, s);
    lstm_prep_kernel<<<ceil_div((long)c4HL * 449, 256), 256, 0, s>>>(
        Wih_f, Whh_f, bih_f, bhh_f, WihPf, WhhPf, biasPf);
    lstm_prep_kernel<<<ceil_div((long)c4HL * 449, 256), 256, 0, s>>>(
        Wih_b, Whh_b, bih_b, bhh_b, WihPb, WhhPb, biasPb);

    // ---------------- embedding (bf16 MFMA, direct bf16 out) ----------------
    launch_mfma<1>(x16, embWT, cFin, nullptr, nullptr, 0, emb_b, emb_b16, cN, cC, s);

    // ---------------- GAT layers ----------------
    for (int l = 0; l < cL; l++) {
        const unsigned short* hin = (l == 0) ? emb_b16 : seqb16 + (size_t)(l - 1) * cN * cC;
        launch_mfma<1>(hin, WT + (size_t)l * 1024 * 128, cC, nullptr, nullptr, 0,
                       bb + (size_t)l * 1024, xlr, cN, 1024, s);
        gat_fused_kernel<<<ceil_div((long)cN * 64, 256), 256, 0, s>>>(
            xlr, src_csr, offs, att_a + (size_t)l * cH * cC,
            conv_b + (size_t)l * cC, ln_w + (size_t)l * cC, ln_b + (size_t)l * cC,
            seq + (size_t)l * cN * cC, seqb16 + (size_t)l * cN * cC);
    }

    // ---------------- bidirectional LSTM (cell+JK fused in GEMM epilogue) ----
    fillF(jks, (long)cL * cN, 0.f, s);
    unsigned short* hfb[2]  = {hf0, hf1};
    unsigned short* hbb[2]  = {hbk0, hbk1};
    dim3 lg(c4HL >> 7, (cN + 127) >> 7);   // 10 x 79
    for (int k = 0; k < cL; k++) {
        int cur = k & 1, prev = cur ^ 1;
        // forward step: t = k
        if (k == 0)
            gemm_lstm_kernel<1><<<lg, 256, 0, s>>>(
                seqb16, WihPf, nullptr, nullptr, biasPf, cf, hfb[cur], jk_w, jks);
        else
            gemm_lstm_kernel<0><<<lg, 256, 0, s>>>(
                seqb16 + (size_t)k * cN * cC, WihPf, hfb[prev], WhhPf, biasPf,
                cf, hfb[cur], jk_w, jks + (size_t)k * cN);
        // backward step: t = L-1-k
        int t = cL - 1 - k;
        if (k == 0)
            gemm_lstm_kernel<1><<<lg, 256, 0, s>>>(
                seqb16 + (size_t)t * cN * cC, WihPb, nullptr, nullptr, biasPb,
                cbk, hbb[cur], jk_w + cHL, jks + (size_t)t * cN);
        else
            gemm_lstm_kernel<0><<<lg, 256, 0, s>>>(
                seqb16 + (size_t)t * cN * cC, WihPb, hbb[prev], WhhPb, biasPb,
                cbk, hbb[cur], jk_w + cHL, jks + (size_t)t * cN);
    }

    // ---------------- JK softmax, pooling, fused head ----------------
    fillF(pooled, (long)cG * cC, 0.f, s);
    fillF(cnt, cG, 0.f, s);
    jk_pool_kernel<<<ceil_div((long)cN * 64, 256), 256, 0, s>>>(seq, jks, batch, pooled);
    count_kernel<<<ceil_div(cN, 256), 256, 0, s>>>(batch, cnt);
    div_pool_kernel<<<ceil_div((long)cG * 128, 256), 256, 0, s>>>(pooled, cnt);
    head_fused_kernel<<<dim3(ceil_div(cOUT, 256), cG / 4), 256, 0, s>>>(
        pooled, m1_w, m1_b, m2_w, m2_b, res_w, res_b, out);
}

// Round 7
// 713.729 us; speedup vs baseline: 5.4583x; 1.2548x over previous
//
#include <hip/hip_runtime.h>
#include <hip/hip_bf16.h>
#include <math.h>

// Problem constants (from reference)
constexpr int cN   = 10000;
constexpr int cE   = 120000;
constexpr int cFin = 64;
constexpr int cC   = 128;
constexpr int cH   = 4;
constexpr int cL   = 5;
constexpr int cG   = 500;
constexpr int cOUT = 1801;
constexpr int cHL  = 320;          // (L*C)/2
constexpr int c4HL = 4 * cHL;      // 1280

typedef short bf16x8 __attribute__((ext_vector_type(8)));
typedef float f32x4 __attribute__((ext_vector_type(4)));

__device__ inline unsigned short f2b(float x) {
    union { __hip_bfloat16 h; unsigned short u; } cv;
    cv.h = __float2bfloat16(x);
    return cv.u;
}
__device__ inline float b2f(unsigned short u) {
    union { unsigned int i; float f; } cv;
    cv.i = ((unsigned int)u) << 16;
    return cv.f;
}
__device__ inline float fsig(float x)  { return 1.f / (1.f + __expf(-x)); }
__device__ inline float ftanh(float x) { return 1.f - 2.f / (__expf(2.f * x) + 1.f); }

#define GLD16(g, l) __builtin_amdgcn_global_load_lds( \
    (const __attribute__((address_space(1))) unsigned int*)(g), \
    (__attribute__((address_space(3))) unsigned int*)(l), 16, 0, 0)

// ---------------- utility kernels ----------------
__global__ void fill_f32_kernel(float* __restrict__ p, long n, float v) {
    long i = (long)blockIdx.x * blockDim.x + threadIdx.x;
    if (i < n) p[i] = v;
}
__global__ void fill_i32_kernel(int* __restrict__ p, long n, int v) {
    long i = (long)blockIdx.x * blockDim.x + threadIdx.x;
    if (i < n) p[i] = v;
}
__global__ void copy_i32_kernel(const int* __restrict__ a, int* __restrict__ b, long n) {
    long i = (long)blockIdx.x * blockDim.x + threadIdx.x;
    if (i < n) b[i] = a[i];
}
__global__ void conv_bf16_kernel(const float* __restrict__ a, unsigned short* __restrict__ b, long n) {
    long i = (long)blockIdx.x * blockDim.x + threadIdx.x;
    if (i < n) b[i] = f2b(a[i]);
}
// Wl,Wr: [L][128][512] fp32 -> WT: [L][1024][128] bf16 (rows 0..511 = Wl^T, 512..1023 = Wr^T)
__global__ void wproj_prep_kernel(const float* __restrict__ Wl, const float* __restrict__ Wr,
                                  unsigned short* __restrict__ WT) {
    long i = (long)blockIdx.x * blockDim.x + threadIdx.x;
    if (i >= (long)cL * 1024 * 128) return;
    int k = i & 127;
    int n = (int)((i >> 7) & 1023);
    int l = (int)(i >> 17);
    const float* W = (n < 512) ? Wl : Wr;
    int nn = n & 511;
    WT[i] = f2b(W[(size_t)l * 65536 + (size_t)k * 512 + nn]);
}
// bl,br: [L][512] -> bb: [L][1024]
__global__ void bias_prep_kernel(const float* __restrict__ bl, const float* __restrict__ br,
                                 float* __restrict__ bb) {
    int i = blockIdx.x * blockDim.x + threadIdx.x;
    if (i >= cL * 1024) return;
    int n = i & 1023, l = i >> 10;
    bb[i] = (n < 512) ? bl[l * 512 + n] : br[l * 512 + (n - 512)];
}
// emb_W: [64][128] fp32 (KxN) -> embWT: [128][64] bf16 (NxK)
__global__ void embw_prep_kernel(const float* __restrict__ W, unsigned short* __restrict__ WT) {
    int i = blockIdx.x * blockDim.x + threadIdx.x;
    if (i >= cC * cFin) return;
    int k = i & 63, n = i >> 6;
    WT[i] = f2b(W[(size_t)k * cC + n]);
}
// LSTM weights -> gate-interleaved rows: p = (u>>4)*64 + g*16 + (u&15), r = g*320+u
__global__ void lstm_prep_kernel(const float* __restrict__ Wih, const float* __restrict__ Whh,
                                 const float* __restrict__ bih, const float* __restrict__ bhh,
                                 unsigned short* __restrict__ WihP, unsigned short* __restrict__ WhhP,
                                 float* __restrict__ biasP) {
    long i = (long)blockIdx.x * blockDim.x + threadIdx.x;   // over 1280*449
    if (i >= (long)c4HL * 449) return;
    int p = (int)(i / 449), c = (int)(i % 449);
    int u = (p >> 6) * 16 + (p & 15);
    int g = (p >> 4) & 3;
    int r = g * cHL + u;
    if (c < cC)       WihP[(size_t)p * cC + c] = f2b(Wih[(size_t)r * cC + c]);
    else if (c < 448) WhhP[(size_t)p * cHL + (c - cC)] = f2b(Whh[(size_t)r * cHL + (c - cC)]);
    else              biasP[p] = bih[r] + bhh[r];
}

// ---------------- CSR build (by dst), payload = src node ----------------
__global__ void hist_kernel(const int* __restrict__ dst, int* __restrict__ count) {
    int i = blockIdx.x * blockDim.x + threadIdx.x;
    if (i < cE) atomicAdd(&count[dst[i]], 1);
}
__global__ void scan_kernel(const int* __restrict__ count, int* __restrict__ offs) {
    __shared__ int part[256];
    const int tid = threadIdx.x;
    const int CH = (cN + 255) / 256;
    int base = tid * CH;
    int s = 0;
    for (int i = 0; i < CH; i++) {
        int idx = base + i;
        if (idx < cN) s += count[idx];
    }
    part[tid] = s;
    __syncthreads();
    for (int d = 1; d < 256; d <<= 1) {
        int v = 0;
        if (tid >= d) v = part[tid - d];
        __syncthreads();
        if (tid >= d) part[tid] += v;
        __syncthreads();
    }
    int prefix = (tid == 0) ? 0 : part[tid - 1];
    for (int i = 0; i < CH; i++) {
        int idx = base + i;
        if (idx < cN) { offs[idx] = prefix; prefix += count[idx]; }
    }
    if (tid == 255) offs[cN] = prefix;
}
__global__ void scatter_kernel(const int* __restrict__ src, const int* __restrict__ dst,
                               int* __restrict__ cursor, int* __restrict__ src_csr) {
    int i = blockIdx.x * blockDim.x + threadIdx.x;
    if (i < cE) {
        int pos = atomicAdd(&cursor[dst[i]], 1);
        src_csr[pos] = src[i];
    }
}

// ---------------- bf16 MFMA GEMM (plain epilogue) ----------------
template<int HASBIAS, int OUTB>
__global__ __launch_bounds__(256)
void gemm_mfma_kernel(const unsigned short* __restrict__ A1, const unsigned short* __restrict__ B1, int k1,
                      const unsigned short* __restrict__ A2, const unsigned short* __restrict__ B2, int k2,
                      const float* __restrict__ bias, void* __restrict__ Cout, int M, int N) {
    __shared__ unsigned short lds[2][2][128 * 32];
    const int tid  = threadIdx.x;
    const int lane = tid & 63;
    const int wave = tid >> 6;
    const int bm = blockIdx.y << 7;
    const int bn = blockIdx.x << 7;
    const int wr = (wave >> 1) << 6;
    const int wc = (wave & 1) << 6;
    const int ns1 = k1 >> 5, ns2 = k2 >> 5, ns = ns1 + ns2;

    const int lrow = lane >> 2;
    const int lke  = (lane & 3) << 3;

    auto stage = [&](int s, int buf) {
        const unsigned short *Ab, *Bb;
        int stride, koff;
        if (s < ns1) { Ab = A1; Bb = B1; stride = k1; koff = s << 5; }
        else         { Ab = A2; Bb = B2; stride = k2; koff = (s - ns1) << 5; }
#pragma unroll
        for (int r = 0; r < 2; r++) {
            int ch  = wave * 2 + r;
            int row = ch * 16 + lrow;
            int ga  = bm + row; if (ga >= M) ga = M - 1;
            GLD16(Ab + (size_t)ga * stride + koff + lke, &lds[buf][0][ch * 512]);
            GLD16(Bb + (size_t)(bn + row) * stride + koff + lke, &lds[buf][1][ch * 512]);
        }
    };

    f32x4 acc[4][4];
#pragma unroll
    for (int i = 0; i < 4; i++)
#pragma unroll
        for (int j = 0; j < 4; j++) acc[i][j] = (f32x4){0.f, 0.f, 0.f, 0.f};

    stage(0, 0);
    const int ko  = (lane >> 4) << 3;
    const int rla = lane & 15;
    for (int s = 0; s < ns; s++) {
        int buf = s & 1;
        __syncthreads();
        if (s + 1 < ns) stage(s + 1, buf ^ 1);
        bf16x8 af[4], bff[4];
#pragma unroll
        for (int f = 0; f < 4; f++) {
            af[f]  = *(const bf16x8*)&lds[buf][0][(wr + f * 16 + rla) * 32 + ko];
            bff[f] = *(const bf16x8*)&lds[buf][1][(wc + f * 16 + rla) * 32 + ko];
        }
#pragma unroll
        for (int i = 0; i < 4; i++)
#pragma unroll
            for (int j = 0; j < 4; j++)
                acc[i][j] = __builtin_amdgcn_mfma_f32_16x16x32_bf16(af[i], bff[j], acc[i][j], 0, 0, 0);
    }

#pragma unroll
    for (int i = 0; i < 4; i++) {
#pragma unroll
        for (int v = 0; v < 4; v++) {
            int m = bm + wr + i * 16 + ((lane >> 4) << 2) + v;
            if (m < M) {
#pragma unroll
                for (int j = 0; j < 4; j++) {
                    int n = bn + wc + j * 16 + rla;
                    float val = acc[i][j][v];
                    if (HASBIAS) val += bias[n];
                    if (OUTB) ((unsigned short*)Cout)[(size_t)m * N + n] = f2b(val);
                    else      ((float*)Cout)[(size_t)m * N + n] = val;
                }
            }
        }
    }
}

// ---------------- dual-direction LSTM step: GEMM + fused cell + JK ----------
// blockIdx.z: 0 = forward, 1 = backward (independent work, one launch).
// gates = seq_t @ WihP^T + h_prev @ WhhP^T (+biasP), gate-interleaved cols:
// lane's j=0..3 are gates i,f,g,o of unit u = ((bn+wc)>>6)*16 + rla.
template<int FIRST>
__global__ __launch_bounds__(256)
void gemm_lstm_dual_kernel(const unsigned short* __restrict__ A1f, const unsigned short* __restrict__ A1b,
                           const unsigned short* __restrict__ Bihf, const unsigned short* __restrict__ Bihb,
                           const unsigned short* __restrict__ A2f, const unsigned short* __restrict__ A2b,
                           const unsigned short* __restrict__ Bhhf, const unsigned short* __restrict__ Bhhb,
                           const float* __restrict__ biasPf, const float* __restrict__ biasPb,
                           float* __restrict__ cff, float* __restrict__ cbb,
                           unsigned short* __restrict__ hOutf, unsigned short* __restrict__ hOutb,
                           const float* __restrict__ jkw,
                           float* __restrict__ scoref, float* __restrict__ scoreb) {
    constexpr int M = cN, k1 = cC, k2 = FIRST ? 0 : cHL;
    const int z = blockIdx.z;
    const unsigned short* A1 = z ? A1b : A1f;
    const unsigned short* B1 = z ? Bihb : Bihf;
    const unsigned short* A2 = z ? A2b : A2f;
    const unsigned short* B2 = z ? Bhhb : Bhhf;
    const float* biasP = z ? biasPb : biasPf;
    float* cbuf = z ? cbb : cff;
    unsigned short* hOut = z ? hOutb : hOutf;
    const float* jkwz = jkw + (z ? cHL : 0);
    float* score_t = z ? scoreb : scoref;

    __shared__ unsigned short lds[2][2][128 * 32];
    const int tid  = threadIdx.x;
    const int lane = tid & 63;
    const int wave = tid >> 6;
    const int bm = blockIdx.y << 7;
    const int bn = blockIdx.x << 7;
    const int wr = (wave >> 1) << 6;
    const int wc = (wave & 1) << 6;
    const int ns1 = k1 >> 5, ns2 = k2 >> 5, ns = ns1 + ns2;

    const int lrow = lane >> 2;
    const int lke  = (lane & 3) << 3;

    auto stage = [&](int s, int buf) {
        const unsigned short *Ab, *Bb;
        int stride, koff;
        if (s < ns1) { Ab = A1; Bb = B1; stride = k1; koff = s << 5; }
        else         { Ab = A2; Bb = B2; stride = k2; koff = (s - ns1) << 5; }
#pragma unroll
        for (int r = 0; r < 2; r++) {
            int ch  = wave * 2 + r;
            int row = ch * 16 + lrow;
            int ga  = bm + row; if (ga >= M) ga = M - 1;
            GLD16(Ab + (size_t)ga * stride + koff + lke, &lds[buf][0][ch * 512]);
            GLD16(Bb + (size_t)(bn + row) * stride + koff + lke, &lds[buf][1][ch * 512]);
        }
    };

    f32x4 acc[4][4];
#pragma unroll
    for (int i = 0; i < 4; i++)
#pragma unroll
        for (int j = 0; j < 4; j++) acc[i][j] = (f32x4){0.f, 0.f, 0.f, 0.f};

    stage(0, 0);
    const int ko  = (lane >> 4) << 3;
    const int rla = lane & 15;
    for (int s = 0; s < ns; s++) {
        int buf = s & 1;
        __syncthreads();
        if (s + 1 < ns) stage(s + 1, buf ^ 1);
        bf16x8 af[4], bff[4];
#pragma unroll
        for (int f = 0; f < 4; f++) {
            af[f]  = *(const bf16x8*)&lds[buf][0][(wr + f * 16 + rla) * 32 + ko];
            bff[f] = *(const bf16x8*)&lds[buf][1][(wc + f * 16 + rla) * 32 + ko];
        }
#pragma unroll
        for (int i = 0; i < 4; i++)
#pragma unroll
            for (int j = 0; j < 4; j++)
                acc[i][j] = __builtin_amdgcn_mfma_f32_16x16x32_bf16(af[i], bff[j], acc[i][j], 0, 0, 0);
    }

    // gate-fused epilogue (fast sigmoid/tanh via v_exp_f32)
    float bias4[4];
#pragma unroll
    for (int j = 0; j < 4; j++) bias4[j] = biasP[bn + wc + j * 16 + rla];
    const int u = ((bn + wc) >> 6) * 16 + rla;
    const float jw = jkwz[u];

#pragma unroll
    for (int i = 0; i < 4; i++) {
#pragma unroll
        for (int v = 0; v < 4; v++) {
            int m = bm + wr + i * 16 + ((lane >> 4) << 2) + v;
            bool ok = (m < M);                      // uniform across rla group
            float gi = acc[i][0][v] + bias4[0];
            float gf = acc[i][1][v] + bias4[1];
            float gg = acc[i][2][v] + bias4[2];
            float go = acc[i][3][v] + bias4[3];
            float si = fsig(gi);
            float sf = fsig(gf);
            float so = fsig(go);
            float tg = ftanh(gg);
            size_t idx = (size_t)m * cHL + u;
            float cold = (FIRST || !ok) ? 0.f : cbuf[idx];
            float cc = sf * cold + si * tg;
            float hh = so * ftanh(cc);
            if (ok) { cbuf[idx] = cc; hOut[idx] = f2b(hh); }
            float part = ok ? hh * jw : 0.f;
#pragma unroll
            for (int o = 1; o < 16; o <<= 1) part += __shfl_xor(part, o);
            if (rla == 0 && ok) atomicAdd(&score_t[m], part);
        }
    }
}

// ---------------- fused GAT layer: one wave per node ----------------
__global__ __launch_bounds__(256)
void gat_fused_kernel(const unsigned short* __restrict__ xlr, const int* __restrict__ src_csr,
                      const int* __restrict__ offs, const float* __restrict__ att,
                      const float* __restrict__ conv_b, const float* __restrict__ lnw,
                      const float* __restrict__ lnb, float* __restrict__ seq_l,
                      unsigned short* __restrict__ seqb_l) {
    const int wv   = (blockIdx.x * blockDim.x + threadIdx.x) >> 6;  // node
    const int lane = threadIdx.x & 63;
    if (wv >= cN) return;
    const int h   = lane >> 4;
    const int cb  = (lane & 15) << 3;

    bf16x8 xrv = *(const bf16x8*)&xlr[(size_t)wv * 1024 + 512 + lane * 8];
    float xr[8], av[8];
#pragma unroll
    for (int k = 0; k < 8; k++) {
        xr[k] = b2f((unsigned short)xrv[k]);
        av[k] = att[h * 128 + cb + k];
    }

    float m = -INFINITY, l = 0.f;
    float acc[8];
#pragma unroll
    for (int k = 0; k < 8; k++) acc[k] = 0.f;

    const int beg = offs[wv], end = offs[wv + 1];
    int j = beg;
    // 2-edge pipelined online softmax: one combined rescale per pair
    for (; j + 1 < end; j += 2) {
        int s0 = src_csr[j], s1 = src_csr[j + 1];
        bf16x8 xv0 = *(const bf16x8*)&xlr[(size_t)s0 * 1024 + lane * 8];
        bf16x8 xv1 = *(const bf16x8*)&xlr[(size_t)s1 * 1024 + lane * 8];
        float x0[8], x1[8], sc0 = 0.f, sc1 = 0.f;
#pragma unroll
        for (int k = 0; k < 8; k++) {
            x0[k] = b2f((unsigned short)xv0[k]);
            float v0 = x0[k] + xr[k];
            v0 = v0 > 0.f ? v0 : 0.2f * v0;
            sc0 = fmaf(v0, av[k], sc0);
            x1[k] = b2f((unsigned short)xv1[k]);
            float v1 = x1[k] + xr[k];
            v1 = v1 > 0.f ? v1 : 0.2f * v1;
            sc1 = fmaf(v1, av[k], sc1);
        }
#pragma unroll
        for (int o = 1; o < 16; o <<= 1) {
            sc0 += __shfl_xor(sc0, o);
            sc1 += __shfl_xor(sc1, o);
        }
        float mn = fmaxf(m, fmaxf(sc0, sc1));
        float r  = __expf(m - mn);
        float p0 = __expf(sc0 - mn);
        float p1 = __expf(sc1 - mn);
        l = l * r + p0 + p1;
#pragma unroll
        for (int k = 0; k < 8; k++)
            acc[k] = fmaf(acc[k], r, fmaf(p0, x0[k], p1 * x1[k]));
        m = mn;
    }
    if (j < end) {   // tail edge
        int s0 = src_csr[j];
        bf16x8 xv = *(const bf16x8*)&xlr[(size_t)s0 * 1024 + lane * 8];
        float x[8], sc = 0.f;
#pragma unroll
        for (int k = 0; k < 8; k++) {
            x[k] = b2f((unsigned short)xv[k]);
            float v = x[k] + xr[k];
            v = v > 0.f ? v : 0.2f * v;
            sc = fmaf(v, av[k], sc);
        }
#pragma unroll
        for (int o = 1; o < 16; o <<= 1) sc += __shfl_xor(sc, o);
        float mn = fmaxf(m, sc);
        float r  = __expf(m - mn);
        float p  = __expf(sc - mn);
        l = l * r + p;
#pragma unroll
        for (int k = 0; k < 8; k++) acc[k] = fmaf(acc[k], r, p * x[k]);
        m = mn;
    }
    float inv = 1.f / (l + 1e-16f);

#pragma unroll
    for (int k = 0; k < 8; k++) {
        float v = acc[k] * inv;
        v += __shfl_xor(v, 16);
        v += __shfl_xor(v, 32);
        acc[k] = 0.25f * v + conv_b[cb + k];
    }
    float ssum = 0.f;
#pragma unroll
    for (int k = 0; k < 8; k++) ssum += acc[k];
#pragma unroll
    for (int o = 1; o < 16; o <<= 1) ssum += __shfl_xor(ssum, o);
    float mu = ssum * (1.f / 128.f);
    float vs = 0.f;
#pragma unroll
    for (int k = 0; k < 8; k++) { float d = acc[k] - mu; vs = fmaf(d, d, vs); }
#pragma unroll
    for (int o = 1; o < 16; o <<= 1) vs += __shfl_xor(vs, o);
    float rstd = 1.f / sqrtf(vs * (1.f / 128.f) + 1e-5f);

    float outv[8];
#pragma unroll
    for (int k = 0; k < 8; k++)
        outv[k] = (acc[k] - mu) * rstd * lnw[cb + k] + lnb[cb + k];

    if (h == 0) {
        size_t b = (size_t)wv * 128 + cb;
        float4 o0 = make_float4(outv[0], outv[1], outv[2], outv[3]);
        float4 o1 = make_float4(outv[4], outv[5], outv[6], outv[7]);
        *(float4*)&seq_l[b]     = o0;
        *(float4*)&seq_l[b + 4] = o1;
        bf16x8 ob;
#pragma unroll
        for (int k = 0; k < 8; k++) ob[k] = (short)f2b(outv[k]);
        *(bf16x8*)&seqb_l[b] = ob;
    }
}

// ---------------- JK softmax + mean pooling ----------------
__global__ void jk_pool_kernel(const float* __restrict__ seq, const float* __restrict__ score,
                               const int* __restrict__ batch, float* __restrict__ pooled) {
    int wid = (blockIdx.x * blockDim.x + threadIdx.x) >> 6;
    int lane = threadIdx.x & 63;
    if (wid >= cN) return;
    float s[cL], mx = -INFINITY;
#pragma unroll
    for (int l = 0; l < cL; l++) { s[l] = score[(size_t)l * cN + wid]; mx = fmaxf(mx, s[l]); }
    float se = 0.f;
#pragma unroll
    for (int l = 0; l < cL; l++) { s[l] = __expf(s[l] - mx); se += s[l]; }
    float inv = 1.f / se;
    int g = batch[wid];
    float acc0 = 0.f, acc1 = 0.f;
#pragma unroll
    for (int l = 0; l < cL; l++) {
        const float* sp = seq + ((size_t)l * cN + wid) * 128;
        float w = s[l] * inv;
        acc0 += w * sp[lane];
        acc1 += w * sp[lane + 64];
    }
    atomicAdd(&pooled[(size_t)g * 128 + lane], acc0);
    atomicAdd(&pooled[(size_t)g * 128 + lane + 64], acc1);
}

__global__ void count_kernel(const int* __restrict__ batch, float* __restrict__ cnt) {
    int i = blockIdx.x * blockDim.x + threadIdx.x;
    if (i < cN) atomicAdd(&cnt[batch[i]], 1.f);
}

__global__ void div_pool_kernel(float* __restrict__ pooled, const float* __restrict__ cnt) {
    int i = blockIdx.x * blockDim.x + threadIdx.x;
    if (i < cG * 128) pooled[i] /= fmaxf(cnt[i >> 7], 1.f);
}

// ---------------- fused MLP head ----------------
__global__ __launch_bounds__(256)
void head_fused_kernel(const float* __restrict__ pooled,
                       const float* __restrict__ m1_w, const float* __restrict__ m1_b,
                       const float* __restrict__ m2_w, const float* __restrict__ m2_b,
                       const float* __restrict__ res_w, const float* __restrict__ res_b,
                       float* __restrict__ out) {
    __shared__ float pl[4][128];
    __shared__ float hd[4][128];
    const int tid = threadIdx.x;
    const int r0 = blockIdx.y << 2;
    const int c0 = blockIdx.x << 8;
#pragma unroll
    for (int e = tid; e < 512; e += 256) {
        int r = e >> 7, k = e & 127;
        pl[r][k] = pooled[(size_t)(r0 + r) * 128 + k];
    }
    __syncthreads();
#pragma unroll
    for (int e = tid; e < 512; e += 256) {
        int r = e >> 7, n = e & 127;
        float acc = m1_b[n];
#pragma unroll 8
        for (int k = 0; k < 128; k++) acc = fmaf(pl[r][k], m1_w[k * 128 + n], acc);
        hd[r][n] = fmaxf(acc, 0.f);
    }
    __syncthreads();
    int col = c0 + tid;
    if (col >= cOUT) return;
    float b = m2_b[col] + res_b[col];
    float acc[4] = {b, b, b, b};
    for (int k = 0; k < 128; k++) {
        float w2 = m2_w[(size_t)k * cOUT + col];
        float wr = res_w[(size_t)k * cOUT + col];
#pragma unroll
        for (int r = 0; r < 4; r++)
            acc[r] = fmaf(hd[r][k], w2, fmaf(pl[r][k], wr, acc[r]));
    }
#pragma unroll
    for (int r = 0; r < 4; r++)
        out[(size_t)(r0 + r) * cOUT + col] = acc[r];
}

// ---------------- launch helpers ----------------
static inline int ceil_div(long a, long b) { return (int)((a + b - 1) / b); }

template<int OUTB>
static void launch_mfma(const unsigned short* A1, const unsigned short* B1, int k1,
                        const unsigned short* A2, const unsigned short* B2, int k2,
                        const float* bias, void* C, int M, int N, hipStream_t s) {
    dim3 g((N + 127) >> 7, (M + 127) >> 7);
    if (bias) gemm_mfma_kernel<1, OUTB><<<g, 256, 0, s>>>(A1, B1, k1, A2, B2, k2, bias, C, M, N);
    else      gemm_mfma_kernel<0, OUTB><<<g, 256, 0, s>>>(A1, B1, k1, A2, B2, k2, bias, C, M, N);
}

static void fillF(float* p, long n, float v, hipStream_t s) {
    fill_f32_kernel<<<ceil_div(n, 256), 256, 0, s>>>(p, n, v);
}
static void fillI(int* p, long n, int v, hipStream_t s) {
    fill_i32_kernel<<<ceil_div(n, 256), 256, 0, s>>>(p, n, v);
}
static void convB(const float* a, unsigned short* b, long n, hipStream_t s) {
    conv_bf16_kernel<<<ceil_div(n, 256), 256, 0, s>>>(a, b, n);
}

extern "C" void kernel_launch(void* const* d_in, const int* in_sizes, int n_in,
                              void* d_out, int out_size, void* d_ws, size_t ws_size,
                              hipStream_t stream) {
    const float* x      = (const float*)d_in[0];
    const int*   ei     = (const int*)d_in[1];
    const int*   batch  = (const int*)d_in[2];
    const float* emb_W  = (const float*)d_in[3];
    const float* emb_b  = (const float*)d_in[4];
    const float* Wl     = (const float*)d_in[5];
    const float* bl     = (const float*)d_in[6];
    const float* Wr     = (const float*)d_in[7];
    const float* br     = (const float*)d_in[8];
    const float* att_a  = (const float*)d_in[9];
    const float* conv_b = (const float*)d_in[10];
    const float* ln_w   = (const float*)d_in[11];
    const float* ln_b   = (const float*)d_in[12];
    const float* Wih_f  = (const float*)d_in[13];
    const float* Whh_f  = (const float*)d_in[14];
    const float* bih_f  = (const float*)d_in[15];
    const float* bhh_f  = (const float*)d_in[16];
    const float* Wih_b  = (const float*)d_in[17];
    const float* Whh_b  = (const float*)d_in[18];
    const float* bih_b  = (const float*)d_in[19];
    const float* bhh_b  = (const float*)d_in[20];
    const float* jk_w   = (const float*)d_in[21];
    // d_in[22] = jk_b: constant across L -> softmax-invariant, unused
    const float* m1_w   = (const float*)d_in[23];
    const float* m1_b   = (const float*)d_in[24];
    const float* m2_w   = (const float*)d_in[25];
    const float* m2_b   = (const float*)d_in[26];
    const float* res_w  = (const float*)d_in[27];
    const float* res_b  = (const float*)d_in[28];
    float* out = (float*)d_out;

    const int* src = ei;
    const int* dst = ei + cE;

    // ---------------- workspace layout ----------------
    char* ws = (char*)d_ws;
    size_t off = 0;
    auto alloc = [&](size_t bytes) -> char* {
        size_t o = (off + 255) & ~(size_t)255;
        off = o + bytes;
        return ws + o;
    };
    unsigned short* x16     = (unsigned short*)alloc((size_t)cN * cFin * 2);
    unsigned short* embWT   = (unsigned short*)alloc((size_t)cC * cFin * 2);
    unsigned short* emb_b16 = (unsigned short*)alloc((size_t)cN * cC * 2);
    float*          seq     = (float*)alloc((size_t)cL * cN * cC * 4);
    unsigned short* seqb16  = (unsigned short*)alloc((size_t)cL * cN * cC * 2);
    unsigned short* WT      = (unsigned short*)alloc((size_t)cL * 1024 * 128 * 2);
    float*          bb      = (float*)alloc((size_t)cL * 1024 * 4);
    unsigned short* WihPf   = (unsigned short*)alloc((size_t)c4HL * cC * 2);
    unsigned short* WhhPf   = (unsigned short*)alloc((size_t)c4HL * cHL * 2);
    unsigned short* WihPb   = (unsigned short*)alloc((size_t)c4HL * cC * 2);
    unsigned short* WhhPb   = (unsigned short*)alloc((size_t)c4HL * cHL * 2);
    float*          biasPf  = (float*)alloc((size_t)c4HL * 4);
    float*          biasPb  = (float*)alloc((size_t)c4HL * 4);
    unsigned short* hf0     = (unsigned short*)alloc((size_t)cN * cHL * 2);
    unsigned short* hf1     = (unsigned short*)alloc((size_t)cN * cHL * 2);
    unsigned short* hbk0    = (unsigned short*)alloc((size_t)cN * cHL * 2);
    unsigned short* hbk1    = (unsigned short*)alloc((size_t)cN * cHL * 2);
    float*          cf      = (float*)alloc((size_t)cN * cHL * 4);
    float*          cbk     = (float*)alloc((size_t)cN * cHL * 4);
    float*          jks     = (float*)alloc((size_t)cL * cN * 4);
    float*          pooled  = (float*)alloc((size_t)cG * cC * 4);
    float*          cnt     = (float*)alloc((size_t)cG * 4);
    int*            offs    = (int*)alloc((size_t)(cN + 1) * 4);
    int*            cursor  = (int*)alloc((size_t)cN * 4);
    int*            src_csr = (int*)alloc((size_t)cE * 4);
    unsigned short* xlr     = (unsigned short*)alloc((size_t)cN * 1024 * 2);

    hipStream_t s = stream;

    // ---------------- CSR by dst (payload = src) ----------------
    fillI(cursor, cN, 0, s);
    hist_kernel<<<ceil_div(cE, 256), 256, 0, s>>>(dst, cursor);
    scan_kernel<<<1, 256, 0, s>>>(cursor, offs);
    copy_i32_kernel<<<ceil_div(cN, 256), 256, 0, s>>>(offs, cursor, cN);
    scatter_kernel<<<ceil_div(cE, 256), 256, 0, s>>>(src, dst, cursor, src_csr);

    // ---------------- weight prep (bf16) ----------------
    wproj_prep_kernel<<<ceil_div((long)cL * 1024 * 128, 256), 256, 0, s>>>(Wl, Wr, WT);
    bias_prep_kernel<<<ceil_div((long)cL * 1024, 256), 256, 0, s>>>(bl, br, bb);
    embw_prep_kernel<<<ceil_div((long)cC * cFin, 256), 256, 0, s>>>(emb_W, embWT);
    convB(x, x16, (long)cN * cFin, s);
    lstm_prep_kernel<<<ceil_div((long)c4HL * 449, 256), 256, 0, s>>>(
        Wih_f, Whh_f, bih_f, bhh_f, WihPf, WhhPf, biasPf);
    lstm_prep_kernel<<<ceil_div((long)c4HL * 449, 256), 256, 0, s>>>(
        Wih_b, Whh_b, bih_b, bhh_b, WihPb, WhhPb, biasPb);

    // ---------------- embedding (bf16 MFMA, direct bf16 out) ----------------
    launch_mfma<1>(x16, embWT, cFin, nullptr, nullptr, 0, emb_b, emb_b16, cN, cC, s);

    // ---------------- GAT layers ----------------
    for (int l = 0; l < cL; l++) {
        const unsigned short* hin = (l == 0) ? emb_b16 : seqb16 + (size_t)(l - 1) * cN * cC;
        launch_mfma<1>(hin, WT + (size_t)l * 1024 * 128, cC, nullptr, nullptr, 0,
                       bb + (size_t)l * 1024, xlr, cN, 1024, s);
        gat_fused_kernel<<<ceil_div((long)cN * 64, 256), 256, 0, s>>>(
            xlr, src_csr, offs, att_a + (size_t)l * cH * cC,
            conv_b + (size_t)l * cC, ln_w + (size_t)l * cC, ln_b + (size_t)l * cC,
            seq + (size_t)l * cN * cC, seqb16 + (size_t)l * cN * cC);
    }

    // ---------------- bidirectional LSTM (both directions per launch) -------
    fillF(jks, (long)cL * cN, 0.f, s);
    unsigned short* hfb[2]  = {hf0, hf1};
    unsigned short* hbb[2]  = {hbk0, hbk1};
    dim3 lg(c4HL >> 7, (cN + 127) >> 7, 2);   // 10 x 79 x 2
    for (int k = 0; k < cL; k++) {
        int cur = k & 1, prev = cur ^ 1;
        int t = cL - 1 - k;
        const unsigned short* A1f = seqb16 + (size_t)k * cN * cC;
        const unsigned short* A1b = seqb16 + (size_t)t * cN * cC;
        if (k == 0)
            gemm_lstm_dual_kernel<1><<<lg, 256, 0, s>>>(
                A1f, A1b, WihPf, WihPb, nullptr, nullptr, nullptr, nullptr,
                biasPf, biasPb, cf, cbk, hfb[cur], hbb[cur], jk_w,
                jks + (size_t)k * cN, jks + (size_t)t * cN);
        else
            gemm_lstm_dual_kernel<0><<<lg, 256, 0, s>>>(
                A1f, A1b, WihPf, WihPb, hfb[prev], hbb[prev], WhhPf, WhhPb,
                biasPf, biasPb, cf, cbk, hfb[cur], hbb[cur], jk_w,
                jks + (size_t)k * cN, jks + (size_t)t * cN);
    }

    // ---------------- JK softmax, pooling, fused head ----------------
    fillF(pooled, (long)cG * cC, 0.f, s);
    fillF(cnt, cG, 0.f, s);
    jk_pool_kernel<<<ceil_div((long)cN * 64, 256), 256, 0, s>>>(seq, jks, batch, pooled);
    count_kernel<<<ceil_div(cN, 256), 256, 0, s>>>(batch, cnt);
    div_pool_kernel<<<ceil_div((long)cG * 128, 256), 256, 0, s>>>(pooled, cnt);
    head_fused_kernel<<<dim3(ceil_div(cOUT, 256), cG / 4), 256, 0, s>>>(
        pooled, m1_w, m1_b, m2_w, m2_b, res_w, res_b, out);
}

// Round 8
// 704.358 us; speedup vs baseline: 5.5309x; 1.0133x over previous
//
#include <hip/hip_runtime.h>
#include <hip/hip_bf16.h>
#include <math.h>

// Problem constants (from reference)
constexpr int cN   = 10000;
constexpr int cE   = 120000;
constexpr int cFin = 64;
constexpr int cC   = 128;
constexpr int cH   = 4;
constexpr int cL   = 5;
constexpr int cG   = 500;
constexpr int cOUT = 1801;
constexpr int cHL  = 320;          // (L*C)/2
constexpr int c4HL = 4 * cHL;      // 1280

typedef short bf16x8 __attribute__((ext_vector_type(8)));
typedef float f32x4 __attribute__((ext_vector_type(4)));

__device__ inline unsigned short f2b(float x) {
    union { __hip_bfloat16 h; unsigned short u; } cv;
    cv.h = __float2bfloat16(x);
    return cv.u;
}
__device__ inline float b2f(unsigned short u) {
    union { unsigned int i; float f; } cv;
    cv.i = ((unsigned int)u) << 16;
    return cv.f;
}
__device__ inline float fsig(float x)  { return 1.f / (1.f + __expf(-x)); }
__device__ inline float ftanh(float x) { return 1.f - 2.f / (__expf(2.f * x) + 1.f); }

#define GLD16(g, l) __builtin_amdgcn_global_load_lds( \
    (const __attribute__((address_space(1))) unsigned int*)(g), \
    (__attribute__((address_space(3))) unsigned int*)(l), 16, 0, 0)

// ---------------- utility kernels ----------------
__global__ void fill_f32_kernel(float* __restrict__ p, long n, float v) {
    long i = (long)blockIdx.x * blockDim.x + threadIdx.x;
    if (i < n) p[i] = v;
}
__global__ void fill_i32_kernel(int* __restrict__ p, long n, int v) {
    long i = (long)blockIdx.x * blockDim.x + threadIdx.x;
    if (i < n) p[i] = v;
}
__global__ void copy_i32_kernel(const int* __restrict__ a, int* __restrict__ b, long n) {
    long i = (long)blockIdx.x * blockDim.x + threadIdx.x;
    if (i < n) b[i] = a[i];
}
__global__ void conv_bf16_kernel(const float* __restrict__ a, unsigned short* __restrict__ b, long n) {
    long i = (long)blockIdx.x * blockDim.x + threadIdx.x;
    if (i < n) b[i] = f2b(a[i]);
}
// Wl,Wr: [L][128][512] fp32 -> WT: [L][1024][128] bf16 (rows 0..511 = Wl^T, 512..1023 = Wr^T)
__global__ void wproj_prep_kernel(const float* __restrict__ Wl, const float* __restrict__ Wr,
                                  unsigned short* __restrict__ WT) {
    long i = (long)blockIdx.x * blockDim.x + threadIdx.x;
    if (i >= (long)cL * 1024 * 128) return;
    int k = i & 127;
    int n = (int)((i >> 7) & 1023);
    int l = (int)(i >> 17);
    const float* W = (n < 512) ? Wl : Wr;
    int nn = n & 511;
    WT[i] = f2b(W[(size_t)l * 65536 + (size_t)k * 512 + nn]);
}
// bl,br: [L][512] -> bb: [L][1024]
__global__ void bias_prep_kernel(const float* __restrict__ bl, const float* __restrict__ br,
                                 float* __restrict__ bb) {
    int i = blockIdx.x * blockDim.x + threadIdx.x;
    if (i >= cL * 1024) return;
    int n = i & 1023, l = i >> 10;
    bb[i] = (n < 512) ? bl[l * 512 + n] : br[l * 512 + (n - 512)];
}
// emb_W: [64][128] fp32 (KxN) -> embWT: [128][64] bf16 (NxK)
__global__ void embw_prep_kernel(const float* __restrict__ W, unsigned short* __restrict__ WT) {
    int i = blockIdx.x * blockDim.x + threadIdx.x;
    if (i >= cC * cFin) return;
    int k = i & 63, n = i >> 6;
    WT[i] = f2b(W[(size_t)k * cC + n]);
}
// LSTM weights -> gate-interleaved rows: p = (u>>4)*64 + g*16 + (u&15), r = g*320+u
__global__ void lstm_prep_kernel(const float* __restrict__ Wih, const float* __restrict__ Whh,
                                 const float* __restrict__ bih, const float* __restrict__ bhh,
                                 unsigned short* __restrict__ WihP, unsigned short* __restrict__ WhhP,
                                 float* __restrict__ biasP) {
    long i = (long)blockIdx.x * blockDim.x + threadIdx.x;   // over 1280*449
    if (i >= (long)c4HL * 449) return;
    int p = (int)(i / 449), c = (int)(i % 449);
    int u = (p >> 6) * 16 + (p & 15);
    int g = (p >> 4) & 3;
    int r = g * cHL + u;
    if (c < cC)       WihP[(size_t)p * cC + c] = f2b(Wih[(size_t)r * cC + c]);
    else if (c < 448) WhhP[(size_t)p * cHL + (c - cC)] = f2b(Whh[(size_t)r * cHL + (c - cC)]);
    else              biasP[p] = bih[r] + bhh[r];
}

// ---------------- CSR build (by dst), payload = src node ----------------
__global__ void hist_kernel(const int* __restrict__ dst, int* __restrict__ count) {
    int i = blockIdx.x * blockDim.x + threadIdx.x;
    if (i < cE) atomicAdd(&count[dst[i]], 1);
}
__global__ void scan_kernel(const int* __restrict__ count, int* __restrict__ offs) {
    __shared__ int part[256];
    const int tid = threadIdx.x;
    const int CH = (cN + 255) / 256;
    int base = tid * CH;
    int s = 0;
    for (int i = 0; i < CH; i++) {
        int idx = base + i;
        if (idx < cN) s += count[idx];
    }
    part[tid] = s;
    __syncthreads();
    for (int d = 1; d < 256; d <<= 1) {
        int v = 0;
        if (tid >= d) v = part[tid - d];
        __syncthreads();
        if (tid >= d) part[tid] += v;
        __syncthreads();
    }
    int prefix = (tid == 0) ? 0 : part[tid - 1];
    for (int i = 0; i < CH; i++) {
        int idx = base + i;
        if (idx < cN) { offs[idx] = prefix; prefix += count[idx]; }
    }
    if (tid == 255) offs[cN] = prefix;
}
__global__ void scatter_kernel(const int* __restrict__ src, const int* __restrict__ dst,
                               int* __restrict__ cursor, int* __restrict__ src_csr) {
    int i = blockIdx.x * blockDim.x + threadIdx.x;
    if (i < cE) {
        int pos = atomicAdd(&cursor[dst[i]], 1);
        src_csr[pos] = src[i];
    }
}

// ---------------- bf16 MFMA GEMM ----------------
// C[M,N] = A@B^T (+bias). 128x128 tile, BK=32, 4 waves, mfma_f32_16x16x32_bf16.
// SWZ=1: 1D grid, XCD-aware group swizzle — all nbn column-blocks of one
// row-panel land on the same XCD (bid&7) so A re-reads hit its L2.
template<int HASBIAS, int OUTB, int SWZ>
__global__ __launch_bounds__(256)
void gemm_mfma_kernel(const unsigned short* __restrict__ A1, const unsigned short* __restrict__ B1, int k1,
                      const unsigned short* __restrict__ A2, const unsigned short* __restrict__ B2, int k2,
                      const float* __restrict__ bias, void* __restrict__ Cout, int M, int N, int nbn) {
    int bm, bn;
    if (SWZ) {
        int bid = blockIdx.x;
        int xcd = bid & 7, j = bid >> 3;
        int g   = (j / nbn) * 8 + xcd;
        bm = g << 7;
        bn = (j % nbn) << 7;
        if (bm >= M) return;   // padded group: whole block exits (pre-barrier)
    } else {
        bm = blockIdx.y << 7;
        bn = blockIdx.x << 7;
    }
    __shared__ unsigned short lds[2][2][128 * 32];
    const int tid  = threadIdx.x;
    const int lane = tid & 63;
    const int wave = tid >> 6;
    const int wr = (wave >> 1) << 6;
    const int wc = (wave & 1) << 6;
    const int ns1 = k1 >> 5, ns2 = k2 >> 5, ns = ns1 + ns2;

    const int lrow = lane >> 2;
    const int lke  = (lane & 3) << 3;

    auto stage = [&](int s, int buf) {
        const unsigned short *Ab, *Bb;
        int stride, koff;
        if (s < ns1) { Ab = A1; Bb = B1; stride = k1; koff = s << 5; }
        else         { Ab = A2; Bb = B2; stride = k2; koff = (s - ns1) << 5; }
#pragma unroll
        for (int r = 0; r < 2; r++) {
            int ch  = wave * 2 + r;
            int row = ch * 16 + lrow;
            int ga  = bm + row; if (ga >= M) ga = M - 1;
            GLD16(Ab + (size_t)ga * stride + koff + lke, &lds[buf][0][ch * 512]);
            GLD16(Bb + (size_t)(bn + row) * stride + koff + lke, &lds[buf][1][ch * 512]);
        }
    };

    f32x4 acc[4][4];
#pragma unroll
    for (int i = 0; i < 4; i++)
#pragma unroll
        for (int j = 0; j < 4; j++) acc[i][j] = (f32x4){0.f, 0.f, 0.f, 0.f};

    stage(0, 0);
    const int ko  = (lane >> 4) << 3;
    const int rla = lane & 15;
    for (int s = 0; s < ns; s++) {
        int buf = s & 1;
        __syncthreads();
        if (s + 1 < ns) stage(s + 1, buf ^ 1);
        bf16x8 af[4], bff[4];
#pragma unroll
        for (int f = 0; f < 4; f++) {
            af[f]  = *(const bf16x8*)&lds[buf][0][(wr + f * 16 + rla) * 32 + ko];
            bff[f] = *(const bf16x8*)&lds[buf][1][(wc + f * 16 + rla) * 32 + ko];
        }
#pragma unroll
        for (int i = 0; i < 4; i++)
#pragma unroll
            for (int j = 0; j < 4; j++)
                acc[i][j] = __builtin_amdgcn_mfma_f32_16x16x32_bf16(af[i], bff[j], acc[i][j], 0, 0, 0);
    }

#pragma unroll
    for (int i = 0; i < 4; i++) {
#pragma unroll
        for (int v = 0; v < 4; v++) {
            int m = bm + wr + i * 16 + ((lane >> 4) << 2) + v;
            if (m < M) {
#pragma unroll
                for (int j = 0; j < 4; j++) {
                    int n = bn + wc + j * 16 + rla;
                    float val = acc[i][j][v];
                    if (HASBIAS) val += bias[n];
                    if (OUTB) ((unsigned short*)Cout)[(size_t)m * N + n] = f2b(val);
                    else      ((float*)Cout)[(size_t)m * N + n] = val;
                }
            }
        }
    }
}

// ---------------- dual-direction LSTM step: GEMM + fused cell + JK ----------
// 1D grid, 1600 blocks: bid -> xcd=bid&7, j=bid>>3; g=(j/20)*8+xcd (row panel,
// padded to 80), inner=j%20 -> bn=(inner%10)*128, z=inner/10 (direction).
// All 20 blocks sharing a row-panel (A-tile) run on one XCD -> A L2-resident.
template<int FIRST>
__global__ __launch_bounds__(256)
void gemm_lstm_dual_kernel(const unsigned short* __restrict__ A1f, const unsigned short* __restrict__ A1b,
                           const unsigned short* __restrict__ Bihf, const unsigned short* __restrict__ Bihb,
                           const unsigned short* __restrict__ A2f, const unsigned short* __restrict__ A2b,
                           const unsigned short* __restrict__ Bhhf, const unsigned short* __restrict__ Bhhb,
                           const float* __restrict__ biasPf, const float* __restrict__ biasPb,
                           float* __restrict__ cff, float* __restrict__ cbb,
                           unsigned short* __restrict__ hOutf, unsigned short* __restrict__ hOutb,
                           const float* __restrict__ jkw,
                           float* __restrict__ scoref, float* __restrict__ scoreb) {
    constexpr int M = cN, k1 = cC, k2 = FIRST ? 0 : cHL;
    const int bid = blockIdx.x;
    const int xcd = bid & 7, jj = bid >> 3;
    const int g     = (jj / 20) * 8 + xcd;
    const int inner = jj % 20;
    const int bm = g << 7;
    if (bm >= M) return;                 // padded group: uniform pre-barrier exit
    const int bn = (inner % 10) << 7;
    const int z  = inner / 10;

    const unsigned short* A1 = z ? A1b : A1f;
    const unsigned short* B1 = z ? Bihb : Bihf;
    const unsigned short* A2 = z ? A2b : A2f;
    const unsigned short* B2 = z ? Bhhb : Bhhf;
    const float* biasP = z ? biasPb : biasPf;
    float* cbuf = z ? cbb : cff;
    unsigned short* hOut = z ? hOutb : hOutf;
    const float* jkwz = jkw + (z ? cHL : 0);
    float* score_t = z ? scoreb : scoref;

    __shared__ unsigned short lds[2][2][128 * 32];
    const int tid  = threadIdx.x;
    const int lane = tid & 63;
    const int wave = tid >> 6;
    const int wr = (wave >> 1) << 6;
    const int wc = (wave & 1) << 6;
    const int ns1 = k1 >> 5, ns2 = k2 >> 5, ns = ns1 + ns2;

    const int lrow = lane >> 2;
    const int lke  = (lane & 3) << 3;

    auto stage = [&](int s, int buf) {
        const unsigned short *Ab, *Bb;
        int stride, koff;
        if (s < ns1) { Ab = A1; Bb = B1; stride = k1; koff = s << 5; }
        else         { Ab = A2; Bb = B2; stride = k2; koff = (s - ns1) << 5; }
#pragma unroll
        for (int r = 0; r < 2; r++) {
            int ch  = wave * 2 + r;
            int row = ch * 16 + lrow;
            int ga  = bm + row; if (ga >= M) ga = M - 1;
            GLD16(Ab + (size_t)ga * stride + koff + lke, &lds[buf][0][ch * 512]);
            GLD16(Bb + (size_t)(bn + row) * stride + koff + lke, &lds[buf][1][ch * 512]);
        }
    };

    f32x4 acc[4][4];
#pragma unroll
    for (int i = 0; i < 4; i++)
#pragma unroll
        for (int j = 0; j < 4; j++) acc[i][j] = (f32x4){0.f, 0.f, 0.f, 0.f};

    stage(0, 0);
    const int ko  = (lane >> 4) << 3;
    const int rla = lane & 15;
    for (int s = 0; s < ns; s++) {
        int buf = s & 1;
        __syncthreads();
        if (s + 1 < ns) stage(s + 1, buf ^ 1);
        bf16x8 af[4], bff[4];
#pragma unroll
        for (int f = 0; f < 4; f++) {
            af[f]  = *(const bf16x8*)&lds[buf][0][(wr + f * 16 + rla) * 32 + ko];
            bff[f] = *(const bf16x8*)&lds[buf][1][(wc + f * 16 + rla) * 32 + ko];
        }
#pragma unroll
        for (int i = 0; i < 4; i++)
#pragma unroll
            for (int j = 0; j < 4; j++)
                acc[i][j] = __builtin_amdgcn_mfma_f32_16x16x32_bf16(af[i], bff[j], acc[i][j], 0, 0, 0);
    }

    // gate-fused epilogue (fast sigmoid/tanh via v_exp_f32)
    float bias4[4];
#pragma unroll
    for (int j = 0; j < 4; j++) bias4[j] = biasP[bn + wc + j * 16 + rla];
    const int u = ((bn + wc) >> 6) * 16 + rla;
    const float jw = jkwz[u];

#pragma unroll
    for (int i = 0; i < 4; i++) {
#pragma unroll
        for (int v = 0; v < 4; v++) {
            int m = bm + wr + i * 16 + ((lane >> 4) << 2) + v;
            bool ok = (m < M);                      // uniform across rla group
            float gi = acc[i][0][v] + bias4[0];
            float gf = acc[i][1][v] + bias4[1];
            float gg = acc[i][2][v] + bias4[2];
            float go = acc[i][3][v] + bias4[3];
            float si = fsig(gi);
            float sf = fsig(gf);
            float so = fsig(go);
            float tg = ftanh(gg);
            size_t idx = (size_t)m * cHL + u;
            float cold = (FIRST || !ok) ? 0.f : cbuf[idx];
            float cc = sf * cold + si * tg;
            float hh = so * ftanh(cc);
            if (ok) { cbuf[idx] = cc; hOut[idx] = f2b(hh); }
            float part = ok ? hh * jw : 0.f;
#pragma unroll
            for (int o = 1; o < 16; o <<= 1) part += __shfl_xor(part, o);
            if (rla == 0 && ok) atomicAdd(&score_t[m], part);
        }
    }
}

// ---------------- fused GAT layer: one wave per node ----------------
__global__ __launch_bounds__(256)
void gat_fused_kernel(const unsigned short* __restrict__ xlr, const int* __restrict__ src_csr,
                      const int* __restrict__ offs, const float* __restrict__ att,
                      const float* __restrict__ conv_b, const float* __restrict__ lnw,
                      const float* __restrict__ lnb, float* __restrict__ seq_l,
                      unsigned short* __restrict__ seqb_l) {
    const int wv   = (blockIdx.x * blockDim.x + threadIdx.x) >> 6;  // node
    const int lane = threadIdx.x & 63;
    if (wv >= cN) return;
    const int h   = lane >> 4;
    const int cb  = (lane & 15) << 3;

    bf16x8 xrv = *(const bf16x8*)&xlr[(size_t)wv * 1024 + 512 + lane * 8];
    float xr[8], av[8];
#pragma unroll
    for (int k = 0; k < 8; k++) {
        xr[k] = b2f((unsigned short)xrv[k]);
        av[k] = att[h * 128 + cb + k];
    }

    float m = -INFINITY, l = 0.f;
    float acc[8];
#pragma unroll
    for (int k = 0; k < 8; k++) acc[k] = 0.f;

    const int beg = offs[wv], end = offs[wv + 1];
    int j = beg;
    for (; j + 1 < end; j += 2) {
        int s0 = src_csr[j], s1 = src_csr[j + 1];
        bf16x8 xv0 = *(const bf16x8*)&xlr[(size_t)s0 * 1024 + lane * 8];
        bf16x8 xv1 = *(const bf16x8*)&xlr[(size_t)s1 * 1024 + lane * 8];
        float x0[8], x1[8], sc0 = 0.f, sc1 = 0.f;
#pragma unroll
        for (int k = 0; k < 8; k++) {
            x0[k] = b2f((unsigned short)xv0[k]);
            float v0 = x0[k] + xr[k];
            v0 = v0 > 0.f ? v0 : 0.2f * v0;
            sc0 = fmaf(v0, av[k], sc0);
            x1[k] = b2f((unsigned short)xv1[k]);
            float v1 = x1[k] + xr[k];
            v1 = v1 > 0.f ? v1 : 0.2f * v1;
            sc1 = fmaf(v1, av[k], sc1);
        }
#pragma unroll
        for (int o = 1; o < 16; o <<= 1) {
            sc0 += __shfl_xor(sc0, o);
            sc1 += __shfl_xor(sc1, o);
        }
        float mn = fmaxf(m, fmaxf(sc0, sc1));
        float r  = __expf(m - mn);
        float p0 = __expf(sc0 - mn);
        float p1 = __expf(sc1 - mn);
        l = l * r + p0 + p1;
#pragma unroll
        for (int k = 0; k < 8; k++)
            acc[k] = fmaf(acc[k], r, fmaf(p0, x0[k], p1 * x1[k]));
        m = mn;
    }
    if (j < end) {
        int s0 = src_csr[j];
        bf16x8 xv = *(const bf16x8*)&xlr[(size_t)s0 * 1024 + lane * 8];
        float x[8], sc = 0.f;
#pragma unroll
        for (int k = 0; k < 8; k++) {
            x[k] = b2f((unsigned short)xv[k]);
            float v = x[k] + xr[k];
            v = v > 0.f ? v : 0.2f * v;
            sc = fmaf(v, av[k], sc);
        }
#pragma unroll
        for (int o = 1; o < 16; o <<= 1) sc += __shfl_xor(sc, o);
        float mn = fmaxf(m, sc);
        float r  = __expf(m - mn);
        float p  = __expf(sc - mn);
        l = l * r + p;
#pragma unroll
        for (int k = 0; k < 8; k++) acc[k] = fmaf(acc[k], r, p * x[k]);
        m = mn;
    }
    float inv = 1.f / (l + 1e-16f);

#pragma unroll
    for (int k = 0; k < 8; k++) {
        float v = acc[k] * inv;
        v += __shfl_xor(v, 16);
        v += __shfl_xor(v, 32);
        acc[k] = 0.25f * v + conv_b[cb + k];
    }
    float ssum = 0.f;
#pragma unroll
    for (int k = 0; k < 8; k++) ssum += acc[k];
#pragma unroll
    for (int o = 1; o < 16; o <<= 1) ssum += __shfl_xor(ssum, o);
    float mu = ssum * (1.f / 128.f);
    float vs = 0.f;
#pragma unroll
    for (int k = 0; k < 8; k++) { float d = acc[k] - mu; vs = fmaf(d, d, vs); }
#pragma unroll
    for (int o = 1; o < 16; o <<= 1) vs += __shfl_xor(vs, o);
    float rstd = 1.f / sqrtf(vs * (1.f / 128.f) + 1e-5f);

    float outv[8];
#pragma unroll
    for (int k = 0; k < 8; k++)
        outv[k] = (acc[k] - mu) * rstd * lnw[cb + k] + lnb[cb + k];

    if (h == 0) {
        size_t b = (size_t)wv * 128 + cb;
        float4 o0 = make_float4(outv[0], outv[1], outv[2], outv[3]);
        float4 o1 = make_float4(outv[4], outv[5], outv[6], outv[7]);
        *(float4*)&seq_l[b]     = o0;
        *(float4*)&seq_l[b + 4] = o1;
        bf16x8 ob;
#pragma unroll
        for (int k = 0; k < 8; k++) ob[k] = (short)f2b(outv[k]);
        *(bf16x8*)&seqb_l[b] = ob;
    }
}

// ---------------- JK softmax + mean pooling ----------------
__global__ void jk_pool_kernel(const float* __restrict__ seq, const float* __restrict__ score,
                               const int* __restrict__ batch, float* __restrict__ pooled) {
    int wid = (blockIdx.x * blockDim.x + threadIdx.x) >> 6;
    int lane = threadIdx.x & 63;
    if (wid >= cN) return;
    float s[cL], mx = -INFINITY;
#pragma unroll
    for (int l = 0; l < cL; l++) { s[l] = score[(size_t)l * cN + wid]; mx = fmaxf(mx, s[l]); }
    float se = 0.f;
#pragma unroll
    for (int l = 0; l < cL; l++) { s[l] = __expf(s[l] - mx); se += s[l]; }
    float inv = 1.f / se;
    int g = batch[wid];
    float acc0 = 0.f, acc1 = 0.f;
#pragma unroll
    for (int l = 0; l < cL; l++) {
        const float* sp = seq + ((size_t)l * cN + wid) * 128;
        float w = s[l] * inv;
        acc0 += w * sp[lane];
        acc1 += w * sp[lane + 64];
    }
    atomicAdd(&pooled[(size_t)g * 128 + lane], acc0);
    atomicAdd(&pooled[(size_t)g * 128 + lane + 64], acc1);
}

__global__ void count_kernel(const int* __restrict__ batch, float* __restrict__ cnt) {
    int i = blockIdx.x * blockDim.x + threadIdx.x;
    if (i < cN) atomicAdd(&cnt[batch[i]], 1.f);
}

__global__ void div_pool_kernel(float* __restrict__ pooled, const float* __restrict__ cnt) {
    int i = blockIdx.x * blockDim.x + threadIdx.x;
    if (i < cG * 128) pooled[i] /= fmaxf(cnt[i >> 7], 1.f);
}

// ---------------- fused MLP head ----------------
__global__ __launch_bounds__(256)
void head_fused_kernel(const float* __restrict__ pooled,
                       const float* __restrict__ m1_w, const float* __restrict__ m1_b,
                       const float* __restrict__ m2_w, const float* __restrict__ m2_b,
                       const float* __restrict__ res_w, const float* __restrict__ res_b,
                       float* __restrict__ out) {
    __shared__ float pl[4][128];
    __shared__ float hd[4][128];
    const int tid = threadIdx.x;
    const int r0 = blockIdx.y << 2;
    const int c0 = blockIdx.x << 8;
#pragma unroll
    for (int e = tid; e < 512; e += 256) {
        int r = e >> 7, k = e & 127;
        pl[r][k] = pooled[(size_t)(r0 + r) * 128 + k];
    }
    __syncthreads();
#pragma unroll
    for (int e = tid; e < 512; e += 256) {
        int r = e >> 7, n = e & 127;
        float acc = m1_b[n];
#pragma unroll 8
        for (int k = 0; k < 128; k++) acc = fmaf(pl[r][k], m1_w[k * 128 + n], acc);
        hd[r][n] = fmaxf(acc, 0.f);
    }
    __syncthreads();
    int col = c0 + tid;
    if (col >= cOUT) return;
    float b = m2_b[col] + res_b[col];
    float acc[4] = {b, b, b, b};
    for (int k = 0; k < 128; k++) {
        float w2 = m2_w[(size_t)k * cOUT + col];
        float wr = res_w[(size_t)k * cOUT + col];
#pragma unroll
        for (int r = 0; r < 4; r++)
            acc[r] = fmaf(hd[r][k], w2, fmaf(pl[r][k], wr, acc[r]));
    }
#pragma unroll
    for (int r = 0; r < 4; r++)
        out[(size_t)(r0 + r) * cOUT + col] = acc[r];
}

// ---------------- launch helpers ----------------
static inline int ceil_div(long a, long b) { return (int)((a + b - 1) / b); }

// non-swizzled (embedding: single column block)
template<int OUTB>
static void launch_mfma(const unsigned short* A1, const unsigned short* B1, int k1,
                        const unsigned short* A2, const unsigned short* B2, int k2,
                        const float* bias, void* C, int M, int N, hipStream_t s) {
    dim3 g((N + 127) >> 7, (M + 127) >> 7);
    if (bias) gemm_mfma_kernel<1, OUTB, 0><<<g, 256, 0, s>>>(A1, B1, k1, A2, B2, k2, bias, C, M, N, 0);
    else      gemm_mfma_kernel<0, OUTB, 0><<<g, 256, 0, s>>>(A1, B1, k1, A2, B2, k2, bias, C, M, N, 0);
}
// XCD-swizzled (proj GEMM: nbn column blocks share a row panel)
template<int OUTB>
static void launch_mfma_swz(const unsigned short* A1, const unsigned short* B1, int k1,
                            const float* bias, void* C, int M, int N, hipStream_t s) {
    int nbn = N >> 7;
    int groups = ((((M + 127) >> 7) + 7) / 8) * 8;   // pad to multiple of 8
    dim3 g(groups * nbn);
    gemm_mfma_kernel<1, OUTB, 1><<<g, 256, 0, s>>>(A1, B1, k1, nullptr, nullptr, 0, bias, C, M, N, nbn);
}

static void fillF(float* p, long n, float v, hipStream_t s) {
    fill_f32_kernel<<<ceil_div(n, 256), 256, 0, s>>>(p, n, v);
}
static void fillI(int* p, long n, int v, hipStream_t s) {
    fill_i32_kernel<<<ceil_div(n, 256), 256, 0, s>>>(p, n, v);
}
static void convB(const float* a, unsigned short* b, long n, hipStream_t s) {
    conv_bf16_kernel<<<ceil_div(n, 256), 256, 0, s>>>(a, b, n);
}

extern "C" void kernel_launch(void* const* d_in, const int* in_sizes, int n_in,
                              void* d_out, int out_size, void* d_ws, size_t ws_size,
                              hipStream_t stream) {
    const float* x      = (const float*)d_in[0];
    const int*   ei     = (const int*)d_in[1];
    const int*   batch  = (const int*)d_in[2];
    const float* emb_W  = (const float*)d_in[3];
    const float* emb_b  = (const float*)d_in[4];
    const float* Wl     = (const float*)d_in[5];
    const float* bl     = (const float*)d_in[6];
    const float* Wr     = (const float*)d_in[7];
    const float* br     = (const float*)d_in[8];
    const float* att_a  = (const float*)d_in[9];
    const float* conv_b = (const float*)d_in[10];
    const float* ln_w   = (const float*)d_in[11];
    const float* ln_b   = (const float*)d_in[12];
    const float* Wih_f  = (const float*)d_in[13];
    const float* Whh_f  = (const float*)d_in[14];
    const float* bih_f  = (const float*)d_in[15];
    const float* bhh_f  = (const float*)d_in[16];
    const float* Wih_b  = (const float*)d_in[17];
    const float* Whh_b  = (const float*)d_in[18];
    const float* bih_b  = (const float*)d_in[19];
    const float* bhh_b  = (const float*)d_in[20];
    const float* jk_w   = (const float*)d_in[21];
    // d_in[22] = jk_b: constant across L -> softmax-invariant, unused
    const float* m1_w   = (const float*)d_in[23];
    const float* m1_b   = (const float*)d_in[24];
    const float* m2_w   = (const float*)d_in[25];
    const float* m2_b   = (const float*)d_in[26];
    const float* res_w  = (const float*)d_in[27];
    const float* res_b  = (const float*)d_in[28];
    float* out = (float*)d_out;

    const int* src = ei;
    const int* dst = ei + cE;

    // ---------------- workspace layout ----------------
    char* ws = (char*)d_ws;
    size_t off = 0;
    auto alloc = [&](size_t bytes) -> char* {
        size_t o = (off + 255) & ~(size_t)255;
        off = o + bytes;
        return ws + o;
    };
    unsigned short* x16     = (unsigned short*)alloc((size_t)cN * cFin * 2);
    unsigned short* embWT   = (unsigned short*)alloc((size_t)cC * cFin * 2);
    unsigned short* emb_b16 = (unsigned short*)alloc((size_t)cN * cC * 2);
    float*          seq     = (float*)alloc((size_t)cL * cN * cC * 4);
    unsigned short* seqb16  = (unsigned short*)alloc((size_t)cL * cN * cC * 2);
    unsigned short* WT      = (unsigned short*)alloc((size_t)cL * 1024 * 128 * 2);
    float*          bb      = (float*)alloc((size_t)cL * 1024 * 4);
    unsigned short* WihPf   = (unsigned short*)alloc((size_t)c4HL * cC * 2);
    unsigned short* WhhPf   = (unsigned short*)alloc((size_t)c4HL * cHL * 2);
    unsigned short* WihPb   = (unsigned short*)alloc((size_t)c4HL * cC * 2);
    unsigned short* WhhPb   = (unsigned short*)alloc((size_t)c4HL * cHL * 2);
    float*          biasPf  = (float*)alloc((size_t)c4HL * 4);
    float*          biasPb  = (float*)alloc((size_t)c4HL * 4);
    unsigned short* hf0     = (unsigned short*)alloc((size_t)cN * cHL * 2);
    unsigned short* hf1     = (unsigned short*)alloc((size_t)cN * cHL * 2);
    unsigned short* hbk0    = (unsigned short*)alloc((size_t)cN * cHL * 2);
    unsigned short* hbk1    = (unsigned short*)alloc((size_t)cN * cHL * 2);
    float*          cf      = (float*)alloc((size_t)cN * cHL * 4);
    float*          cbk     = (float*)alloc((size_t)cN * cHL * 4);
    float*          jks     = (float*)alloc((size_t)cL * cN * 4);
    float*          pooled  = (float*)alloc((size_t)cG * cC * 4);
    float*          cnt     = (float*)alloc((size_t)cG * 4);
    int*            offs    = (int*)alloc((size_t)(cN + 1) * 4);
    int*            cursor  = (int*)alloc((size_t)cN * 4);
    int*            src_csr = (int*)alloc((size_t)cE * 4);
    unsigned short* xlr     = (unsigned short*)alloc((size_t)cN * 1024 * 2);

    hipStream_t s = stream;

    // ---------------- CSR by dst (payload = src) ----------------
    fillI(cursor, cN, 0, s);
    hist_kernel<<<ceil_div(cE, 256), 256, 0, s>>>(dst, cursor);
    scan_kernel<<<1, 256, 0, s>>>(cursor, offs);
    copy_i32_kernel<<<ceil_div(cN, 256), 256, 0, s>>>(offs, cursor, cN);
    scatter_kernel<<<ceil_div(cE, 256), 256, 0, s>>>(src, dst, cursor, src_csr);

    // ---------------- weight prep (bf16) ----------------
    wproj_prep_kernel<<<ceil_div((long)cL * 1024 * 128, 256), 256, 0, s>>>(Wl, Wr, WT);
    bias_prep_kernel<<<ceil_div((long)cL * 1024, 256), 256, 0, s>>>(bl, br, bb);
    embw_prep_kernel<<<ceil_div((long)cC * cFin, 256), 256, 0, s>>>(emb_W, embWT);
    convB(x, x16, (long)cN * cFin, s);
    lstm_prep_kernel<<<ceil_div((long)c4HL * 449, 256), 256, 0, s>>>(
        Wih_f, Whh_f, bih_f, bhh_f, WihPf, WhhPf, biasPf);
    lstm_prep_kernel<<<ceil_div((long)c4HL * 449, 256), 256, 0, s>>>(
        Wih_b, Whh_b, bih_b, bhh_b, WihPb, WhhPb, biasPb);

    // ---------------- embedding (bf16 MFMA, direct bf16 out) ----------------
    launch_mfma<1>(x16, embWT, cFin, nullptr, nullptr, 0, emb_b, emb_b16, cN, cC, s);

    // ---------------- GAT layers ----------------
    for (int l = 0; l < cL; l++) {
        const unsigned short* hin = (l == 0) ? emb_b16 : seqb16 + (size_t)(l - 1) * cN * cC;
        launch_mfma_swz<1>(hin, WT + (size_t)l * 1024 * 128, cC,
                           bb + (size_t)l * 1024, xlr, cN, 1024, s);
        gat_fused_kernel<<<ceil_div((long)cN * 64, 256), 256, 0, s>>>(
            xlr, src_csr, offs, att_a + (size_t)l * cH * cC,
            conv_b + (size_t)l * cC, ln_w + (size_t)l * cC, ln_b + (size_t)l * cC,
            seq + (size_t)l * cN * cC, seqb16 + (size_t)l * cN * cC);
    }

    // ---------------- bidirectional LSTM (both directions per launch) -------
    fillF(jks, (long)cL * cN, 0.f, s);
    unsigned short* hfb[2]  = {hf0, hf1};
    unsigned short* hbb[2]  = {hbk0, hbk1};
    dim3 lg(80 * 20);   // 80 row-groups (padded) x 10 bn x 2 dir, XCD-swizzled
    for (int k = 0; k < cL; k++) {
        int cur = k & 1, prev = cur ^ 1;
        int t = cL - 1 - k;
        const unsigned short* A1f = seqb16 + (size_t)k * cN * cC;
        const unsigned short* A1b = seqb16 + (size_t)t * cN * cC;
        if (k == 0)
            gemm_lstm_dual_kernel<1><<<lg, 256, 0, s>>>(
                A1f, A1b, WihPf, WihPb, nullptr, nullptr, nullptr, nullptr,
                biasPf, biasPb, cf, cbk, hfb[cur], hbb[cur], jk_w,
                jks + (size_t)k * cN, jks + (size_t)t * cN);
        else
            gemm_lstm_dual_kernel<0><<<lg, 256, 0, s>>>(
                A1f, A1b, WihPf, WihPb, hfb[prev], hbb[prev], WhhPf, WhhPb,
                biasPf, biasPb, cf, cbk, hfb[cur], hbb[cur], jk_w,
                jks + (size_t)k * cN, jks + (size_t)t * cN);
    }

    // ---------------- JK softmax, pooling, fused head ----------------
    fillF(pooled, (long)cG * cC, 0.f, s);
    fillF(cnt, cG, 0.f, s);
    jk_pool_kernel<<<ceil_div((long)cN * 64, 256), 256, 0, s>>>(seq, jks, batch, pooled);
    count_kernel<<<ceil_div(cN, 256), 256, 0, s>>>(batch, cnt);
    div_pool_kernel<<<ceil_div((long)cG * 128, 256), 256, 0, s>>>(pooled, cnt);
    head_fused_kernel<<<dim3(ceil_div(cOUT, 256), cG / 4), 256, 0, s>>>(
        pooled, m1_w, m1_b, m2_w, m2_b, res_w, res_b, out);
}

// Round 9
// 698.918 us; speedup vs baseline: 5.5740x; 1.0078x over previous
//
#include <hip/hip_runtime.h>
#include <hip/hip_bf16.h>
#include <math.h>

// Problem constants (from reference)
constexpr int cN   = 10000;
constexpr int cE   = 120000;
constexpr int cFin = 64;
constexpr int cC   = 128;
constexpr int cH   = 4;
constexpr int cL   = 5;
constexpr int cG   = 500;
constexpr int cOUT = 1801;
constexpr int cHL  = 320;          // (L*C)/2
constexpr int c4HL = 4 * cHL;      // 1280

typedef short bf16x8 __attribute__((ext_vector_type(8)));
typedef float f32x4 __attribute__((ext_vector_type(4)));

__device__ inline unsigned short f2b(float x) {
    union { __hip_bfloat16 h; unsigned short u; } cv;
    cv.h = __float2bfloat16(x);
    return cv.u;
}
__device__ inline float b2f(unsigned short u) {
    union { unsigned int i; float f; } cv;
    cv.i = ((unsigned int)u) << 16;
    return cv.f;
}
__device__ inline float fsig(float x)  { return 1.f / (1.f + __expf(-x)); }
__device__ inline float ftanh(float x) { return 1.f - 2.f / (__expf(2.f * x) + 1.f); }

#define GLD16(g, l) __builtin_amdgcn_global_load_lds( \
    (const __attribute__((address_space(1))) unsigned int*)(g), \
    (__attribute__((address_space(3))) unsigned int*)(l), 16, 0, 0)

// ---------------- utility kernels ----------------
__global__ void fill_f32_kernel(float* __restrict__ p, long n, float v) {
    long i = (long)blockIdx.x * blockDim.x + threadIdx.x;
    if (i < n) p[i] = v;
}
__global__ void fill_i32_kernel(int* __restrict__ p, long n, int v) {
    long i = (long)blockIdx.x * blockDim.x + threadIdx.x;
    if (i < n) p[i] = v;
}
__global__ void copy_i32_kernel(const int* __restrict__ a, int* __restrict__ b, long n) {
    long i = (long)blockIdx.x * blockDim.x + threadIdx.x;
    if (i < n) b[i] = a[i];
}
__global__ void conv_bf16_kernel(const float* __restrict__ a, unsigned short* __restrict__ b, long n) {
    long i = (long)blockIdx.x * blockDim.x + threadIdx.x;
    if (i < n) b[i] = f2b(a[i]);
}
// Wl,Wr: [L][128][512] fp32 -> WT: [L][1024][128] bf16 (rows 0..511 = Wl^T, 512..1023 = Wr^T)
__global__ void wproj_prep_kernel(const float* __restrict__ Wl, const float* __restrict__ Wr,
                                  unsigned short* __restrict__ WT) {
    long i = (long)blockIdx.x * blockDim.x + threadIdx.x;
    if (i >= (long)cL * 1024 * 128) return;
    int k = i & 127;
    int n = (int)((i >> 7) & 1023);
    int l = (int)(i >> 17);
    const float* W = (n < 512) ? Wl : Wr;
    int nn = n & 511;
    WT[i] = f2b(W[(size_t)l * 65536 + (size_t)k * 512 + nn]);
}
// bl,br: [L][512] -> bb: [L][1024]
__global__ void bias_prep_kernel(const float* __restrict__ bl, const float* __restrict__ br,
                                 float* __restrict__ bb) {
    int i = blockIdx.x * blockDim.x + threadIdx.x;
    if (i >= cL * 1024) return;
    int n = i & 1023, l = i >> 10;
    bb[i] = (n < 512) ? bl[l * 512 + n] : br[l * 512 + (n - 512)];
}
// emb_W: [64][128] fp32 (KxN) -> embWT: [128][64] bf16 (NxK)
__global__ void embw_prep_kernel(const float* __restrict__ W, unsigned short* __restrict__ WT) {
    int i = blockIdx.x * blockDim.x + threadIdx.x;
    if (i >= cC * cFin) return;
    int k = i & 63, n = i >> 6;
    WT[i] = f2b(W[(size_t)k * cC + n]);
}
// LSTM weights -> gate-interleaved rows: p = (u>>4)*64 + g*16 + (u&15), r = g*320+u
__global__ void lstm_prep_kernel(const float* __restrict__ Wih, const float* __restrict__ Whh,
                                 const float* __restrict__ bih, const float* __restrict__ bhh,
                                 unsigned short* __restrict__ WihP, unsigned short* __restrict__ WhhP,
                                 float* __restrict__ biasP) {
    long i = (long)blockIdx.x * blockDim.x + threadIdx.x;   // over 1280*449
    if (i >= (long)c4HL * 449) return;
    int p = (int)(i / 449), c = (int)(i % 449);
    int u = (p >> 6) * 16 + (p & 15);
    int g = (p >> 4) & 3;
    int r = g * cHL + u;
    if (c < cC)       WihP[(size_t)p * cC + c] = f2b(Wih[(size_t)r * cC + c]);
    else if (c < 448) WhhP[(size_t)p * cHL + (c - cC)] = f2b(Whh[(size_t)r * cHL + (c - cC)]);
    else              biasP[p] = bih[r] + bhh[r];
}

// ---------------- CSR build (by dst), payload = src node ----------------
__global__ void hist_kernel(const int* __restrict__ dst, int* __restrict__ count) {
    int i = blockIdx.x * blockDim.x + threadIdx.x;
    if (i < cE) atomicAdd(&count[dst[i]], 1);
}
__global__ void scan_kernel(const int* __restrict__ count, int* __restrict__ offs) {
    __shared__ int part[256];
    const int tid = threadIdx.x;
    const int CH = (cN + 255) / 256;
    int base = tid * CH;
    int s = 0;
    for (int i = 0; i < CH; i++) {
        int idx = base + i;
        if (idx < cN) s += count[idx];
    }
    part[tid] = s;
    __syncthreads();
    for (int d = 1; d < 256; d <<= 1) {
        int v = 0;
        if (tid >= d) v = part[tid - d];
        __syncthreads();
        if (tid >= d) part[tid] += v;
        __syncthreads();
    }
    int prefix = (tid == 0) ? 0 : part[tid - 1];
    for (int i = 0; i < CH; i++) {
        int idx = base + i;
        if (idx < cN) { offs[idx] = prefix; prefix += count[idx]; }
    }
    if (tid == 255) offs[cN] = prefix;
}
__global__ void scatter_kernel(const int* __restrict__ src, const int* __restrict__ dst,
                               int* __restrict__ cursor, int* __restrict__ src_csr) {
    int i = blockIdx.x * blockDim.x + threadIdx.x;
    if (i < cE) {
        int pos = atomicAdd(&cursor[dst[i]], 1);
        src_csr[pos] = src[i];
    }
}

// ---------------- bf16 MFMA GEMM (128x128, 4 waves) ----------------
// SWZ=1: 1D grid, XCD-aware group swizzle.
template<int HASBIAS, int OUTB, int SWZ>
__global__ __launch_bounds__(256)
void gemm_mfma_kernel(const unsigned short* __restrict__ A1, const unsigned short* __restrict__ B1, int k1,
                      const unsigned short* __restrict__ A2, const unsigned short* __restrict__ B2, int k2,
                      const float* __restrict__ bias, void* __restrict__ Cout, int M, int N, int nbn) {
    int bm, bn;
    if (SWZ) {
        int bid = blockIdx.x;
        int xcd = bid & 7, j = bid >> 3;
        int g   = (j / nbn) * 8 + xcd;
        bm = g << 7;
        bn = (j % nbn) << 7;
        if (bm >= M) return;   // padded group: whole block exits (pre-barrier)
    } else {
        bm = blockIdx.y << 7;
        bn = blockIdx.x << 7;
    }
    __shared__ unsigned short lds[2][2][128 * 32];
    const int tid  = threadIdx.x;
    const int lane = tid & 63;
    const int wave = tid >> 6;
    const int wr = (wave >> 1) << 6;
    const int wc = (wave & 1) << 6;
    const int ns1 = k1 >> 5, ns2 = k2 >> 5, ns = ns1 + ns2;

    const int lrow = lane >> 2;
    const int lke  = (lane & 3) << 3;

    auto stage = [&](int s, int buf) {
        const unsigned short *Ab, *Bb;
        int stride, koff;
        if (s < ns1) { Ab = A1; Bb = B1; stride = k1; koff = s << 5; }
        else         { Ab = A2; Bb = B2; stride = k2; koff = (s - ns1) << 5; }
#pragma unroll
        for (int r = 0; r < 2; r++) {
            int ch  = wave * 2 + r;
            int row = ch * 16 + lrow;
            int ga  = bm + row; if (ga >= M) ga = M - 1;
            GLD16(Ab + (size_t)ga * stride + koff + lke, &lds[buf][0][ch * 512]);
            GLD16(Bb + (size_t)(bn + row) * stride + koff + lke, &lds[buf][1][ch * 512]);
        }
    };

    f32x4 acc[4][4];
#pragma unroll
    for (int i = 0; i < 4; i++)
#pragma unroll
        for (int j = 0; j < 4; j++) acc[i][j] = (f32x4){0.f, 0.f, 0.f, 0.f};

    stage(0, 0);
    const int ko  = (lane >> 4) << 3;
    const int rla = lane & 15;
    for (int s = 0; s < ns; s++) {
        int buf = s & 1;
        __syncthreads();
        if (s + 1 < ns) stage(s + 1, buf ^ 1);
        bf16x8 af[4], bff[4];
#pragma unroll
        for (int f = 0; f < 4; f++) {
            af[f]  = *(const bf16x8*)&lds[buf][0][(wr + f * 16 + rla) * 32 + ko];
            bff[f] = *(const bf16x8*)&lds[buf][1][(wc + f * 16 + rla) * 32 + ko];
        }
#pragma unroll
        for (int i = 0; i < 4; i++)
#pragma unroll
            for (int j = 0; j < 4; j++)
                acc[i][j] = __builtin_amdgcn_mfma_f32_16x16x32_bf16(af[i], bff[j], acc[i][j], 0, 0, 0);
    }

#pragma unroll
    for (int i = 0; i < 4; i++) {
#pragma unroll
        for (int v = 0; v < 4; v++) {
            int m = bm + wr + i * 16 + ((lane >> 4) << 2) + v;
            if (m < M) {
#pragma unroll
                for (int j = 0; j < 4; j++) {
                    int n = bn + wc + j * 16 + rla;
                    float val = acc[i][j][v];
                    if (HASBIAS) val += bias[n];
                    if (OUTB) ((unsigned short*)Cout)[(size_t)m * N + n] = f2b(val);
                    else      ((float*)Cout)[(size_t)m * N + n] = val;
                }
            }
        }
    }
}

// ---------------- dual-direction LSTM step: 128x256 tile, 8 waves -----------
// Grid 800: bid -> xcd=bid&7, jj=bid>>3; g=(jj/10)*8+xcd (row panel, padded
// to 80); inner=jj%10 -> bn=(inner%5)*256, z=inner/5 (direction).
// 8 waves as 2(row) x 4(col), 64x64 each -> 128 MFMA per K-step per block.
// Gate-interleaved cols: lane's j=0..3 are gates i,f,g,o of unit
// u = ((bn+wc)>>6)*16 + rla (same formula as 128x128 version).
template<int FIRST>
__global__ __launch_bounds__(512)
void gemm_lstm_dual_kernel(const unsigned short* __restrict__ A1f, const unsigned short* __restrict__ A1b,
                           const unsigned short* __restrict__ Bihf, const unsigned short* __restrict__ Bihb,
                           const unsigned short* __restrict__ A2f, const unsigned short* __restrict__ A2b,
                           const unsigned short* __restrict__ Bhhf, const unsigned short* __restrict__ Bhhb,
                           const float* __restrict__ biasPf, const float* __restrict__ biasPb,
                           float* __restrict__ cff, float* __restrict__ cbb,
                           unsigned short* __restrict__ hOutf, unsigned short* __restrict__ hOutb,
                           const float* __restrict__ jkw,
                           float* __restrict__ scoref, float* __restrict__ scoreb) {
    constexpr int M = cN, k1 = cC, k2 = FIRST ? 0 : cHL;
    const int bid = blockIdx.x;
    const int xcd = bid & 7, jj = bid >> 3;
    const int g     = (jj / 10) * 8 + xcd;
    const int inner = jj % 10;
    const int bm = g << 7;
    if (bm >= M) return;                 // padded group: uniform pre-barrier exit
    const int bn = (inner % 5) << 8;     // 0..1024 step 256
    const int z  = inner / 5;

    const unsigned short* A1 = z ? A1b : A1f;
    const unsigned short* B1 = z ? Bihb : Bihf;
    const unsigned short* A2 = z ? A2b : A2f;
    const unsigned short* B2 = z ? Bhhb : Bhhf;
    const float* biasP = z ? biasPb : biasPf;
    float* cbuf = z ? cbb : cff;
    unsigned short* hOut = z ? hOutb : hOutf;
    const float* jkwz = jkw + (z ? cHL : 0);
    float* score_t = z ? scoreb : scoref;

    __shared__ unsigned short ldsA[2][128 * 32];
    __shared__ unsigned short ldsB[2][256 * 32];
    const int tid  = threadIdx.x;
    const int lane = tid & 63;
    const int wave = tid >> 6;           // 0..7
    const int wr = (wave >> 2) << 6;     // 0 or 64
    const int wc = (wave & 3) << 6;      // 0,64,128,192
    const int ns1 = k1 >> 5, ns2 = k2 >> 5, ns = ns1 + ns2;

    const int lrow = lane >> 2;
    const int lke  = (lane & 3) << 3;

    auto stage = [&](int s, int buf) {
        const unsigned short *Ab, *Bb;
        int stride, koff;
        if (s < ns1) { Ab = A1; Bb = B1; stride = k1; koff = s << 5; }
        else         { Ab = A2; Bb = B2; stride = k2; koff = (s - ns1) << 5; }
        // A: 128 rows, 8 waves x 16 rows
        {
            int row = wave * 16 + lrow;
            int ga  = bm + row; if (ga >= M) ga = M - 1;
            GLD16(Ab + (size_t)ga * stride + koff + lke, &ldsA[buf][wave * 512]);
        }
        // B: 256 rows, 8 waves x 2 x 16 rows
#pragma unroll
        for (int r = 0; r < 2; r++) {
            int ch  = wave * 2 + r;
            int row = ch * 16 + lrow;
            GLD16(Bb + (size_t)(bn + row) * stride + koff + lke, &ldsB[buf][ch * 512]);
        }
    };

    f32x4 acc[4][4];
#pragma unroll
    for (int i = 0; i < 4; i++)
#pragma unroll
        for (int j = 0; j < 4; j++) acc[i][j] = (f32x4){0.f, 0.f, 0.f, 0.f};

    stage(0, 0);
    const int ko  = (lane >> 4) << 3;
    const int rla = lane & 15;
    for (int s = 0; s < ns; s++) {
        int buf = s & 1;
        __syncthreads();
        if (s + 1 < ns) stage(s + 1, buf ^ 1);
        bf16x8 af[4], bff[4];
#pragma unroll
        for (int f = 0; f < 4; f++) {
            af[f]  = *(const bf16x8*)&ldsA[buf][(wr + f * 16 + rla) * 32 + ko];
            bff[f] = *(const bf16x8*)&ldsB[buf][(wc + f * 16 + rla) * 32 + ko];
        }
#pragma unroll
        for (int i = 0; i < 4; i++)
#pragma unroll
            for (int j = 0; j < 4; j++)
                acc[i][j] = __builtin_amdgcn_mfma_f32_16x16x32_bf16(af[i], bff[j], acc[i][j], 0, 0, 0);
    }

    // gate-fused epilogue (fast sigmoid/tanh via v_exp_f32)
    float bias4[4];
#pragma unroll
    for (int j = 0; j < 4; j++) bias4[j] = biasP[bn + wc + j * 16 + rla];
    const int u = ((bn + wc) >> 6) * 16 + rla;
    const float jw = jkwz[u];

#pragma unroll
    for (int i = 0; i < 4; i++) {
#pragma unroll
        for (int v = 0; v < 4; v++) {
            int m = bm + wr + i * 16 + ((lane >> 4) << 2) + v;
            bool ok = (m < M);                      // uniform across rla group
            float gi = acc[i][0][v] + bias4[0];
            float gf = acc[i][1][v] + bias4[1];
            float gg = acc[i][2][v] + bias4[2];
            float go = acc[i][3][v] + bias4[3];
            float si = fsig(gi);
            float sf = fsig(gf);
            float so = fsig(go);
            float tg = ftanh(gg);
            size_t idx = (size_t)m * cHL + u;
            float cold = (FIRST || !ok) ? 0.f : cbuf[idx];
            float cc = sf * cold + si * tg;
            float hh = so * ftanh(cc);
            if (ok) { cbuf[idx] = cc; hOut[idx] = f2b(hh); }
            float part = ok ? hh * jw : 0.f;
#pragma unroll
            for (int o = 1; o < 16; o <<= 1) part += __shfl_xor(part, o);
            if (rla == 0 && ok) atomicAdd(&score_t[m], part);
        }
    }
}

// ---------------- fused GAT layer: one wave per node ----------------
__global__ __launch_bounds__(256)
void gat_fused_kernel(const unsigned short* __restrict__ xlr, const int* __restrict__ src_csr,
                      const int* __restrict__ offs, const float* __restrict__ att,
                      const float* __restrict__ conv_b, const float* __restrict__ lnw,
                      const float* __restrict__ lnb, float* __restrict__ seq_l,
                      unsigned short* __restrict__ seqb_l) {
    const int wv   = (blockIdx.x * blockDim.x + threadIdx.x) >> 6;  // node
    const int lane = threadIdx.x & 63;
    if (wv >= cN) return;
    const int h   = lane >> 4;
    const int cb  = (lane & 15) << 3;

    bf16x8 xrv = *(const bf16x8*)&xlr[(size_t)wv * 1024 + 512 + lane * 8];
    float xr[8], av[8];
#pragma unroll
    for (int k = 0; k < 8; k++) {
        xr[k] = b2f((unsigned short)xrv[k]);
        av[k] = att[h * 128 + cb + k];
    }

    float m = -INFINITY, l = 0.f;
    float acc[8];
#pragma unroll
    for (int k = 0; k < 8; k++) acc[k] = 0.f;

    const int beg = offs[wv], end = offs[wv + 1];
    int j = beg;
    for (; j + 1 < end; j += 2) {
        int s0 = src_csr[j], s1 = src_csr[j + 1];
        bf16x8 xv0 = *(const bf16x8*)&xlr[(size_t)s0 * 1024 + lane * 8];
        bf16x8 xv1 = *(const bf16x8*)&xlr[(size_t)s1 * 1024 + lane * 8];
        float x0[8], x1[8], sc0 = 0.f, sc1 = 0.f;
#pragma unroll
        for (int k = 0; k < 8; k++) {
            x0[k] = b2f((unsigned short)xv0[k]);
            float v0 = x0[k] + xr[k];
            v0 = v0 > 0.f ? v0 : 0.2f * v0;
            sc0 = fmaf(v0, av[k], sc0);
            x1[k] = b2f((unsigned short)xv1[k]);
            float v1 = x1[k] + xr[k];
            v1 = v1 > 0.f ? v1 : 0.2f * v1;
            sc1 = fmaf(v1, av[k], sc1);
        }
#pragma unroll
        for (int o = 1; o < 16; o <<= 1) {
            sc0 += __shfl_xor(sc0, o);
            sc1 += __shfl_xor(sc1, o);
        }
        float mn = fmaxf(m, fmaxf(sc0, sc1));
        float r  = __expf(m - mn);
        float p0 = __expf(sc0 - mn);
        float p1 = __expf(sc1 - mn);
        l = l * r + p0 + p1;
#pragma unroll
        for (int k = 0; k < 8; k++)
            acc[k] = fmaf(acc[k], r, fmaf(p0, x0[k], p1 * x1[k]));
        m = mn;
    }
    if (j < end) {
        int s0 = src_csr[j];
        bf16x8 xv = *(const bf16x8*)&xlr[(size_t)s0 * 1024 + lane * 8];
        float x[8], sc = 0.f;
#pragma unroll
        for (int k = 0; k < 8; k++) {
            x[k] = b2f((unsigned short)xv[k]);
            float v = x[k] + xr[k];
            v = v > 0.f ? v : 0.2f * v;
            sc = fmaf(v, av[k], sc);
        }
#pragma unroll
        for (int o = 1; o < 16; o <<= 1) sc += __shfl_xor(sc, o);
        float mn = fmaxf(m, sc);
        float r  = __expf(m - mn);
        float p  = __expf(sc - mn);
        l = l * r + p;
#pragma unroll
        for (int k = 0; k < 8; k++) acc[k] = fmaf(acc[k], r, p * x[k]);
        m = mn;
    }
    float inv = 1.f / (l + 1e-16f);

#pragma unroll
    for (int k = 0; k < 8; k++) {
        float v = acc[k] * inv;
        v += __shfl_xor(v, 16);
        v += __shfl_xor(v, 32);
        acc[k] = 0.25f * v + conv_b[cb + k];
    }
    float ssum = 0.f;
#pragma unroll
    for (int k = 0; k < 8; k++) ssum += acc[k];
#pragma unroll
    for (int o = 1; o < 16; o <<= 1) ssum += __shfl_xor(ssum, o);
    float mu = ssum * (1.f / 128.f);
    float vs = 0.f;
#pragma unroll
    for (int k = 0; k < 8; k++) { float d = acc[k] - mu; vs = fmaf(d, d, vs); }
#pragma unroll
    for (int o = 1; o < 16; o <<= 1) vs += __shfl_xor(vs, o);
    float rstd = 1.f / sqrtf(vs * (1.f / 128.f) + 1e-5f);

    float outv[8];
#pragma unroll
    for (int k = 0; k < 8; k++)
        outv[k] = (acc[k] - mu) * rstd * lnw[cb + k] + lnb[cb + k];

    if (h == 0) {
        size_t b = (size_t)wv * 128 + cb;
        float4 o0 = make_float4(outv[0], outv[1], outv[2], outv[3]);
        float4 o1 = make_float4(outv[4], outv[5], outv[6], outv[7]);
        *(float4*)&seq_l[b]     = o0;
        *(float4*)&seq_l[b + 4] = o1;
        bf16x8 ob;
#pragma unroll
        for (int k = 0; k < 8; k++) ob[k] = (short)f2b(outv[k]);
        *(bf16x8*)&seqb_l[b] = ob;
    }
}

// ---------------- JK softmax + mean pooling ----------------
__global__ void jk_pool_kernel(const float* __restrict__ seq, const float* __restrict__ score,
                               const int* __restrict__ batch, float* __restrict__ pooled) {
    int wid = (blockIdx.x * blockDim.x + threadIdx.x) >> 6;
    int lane = threadIdx.x & 63;
    if (wid >= cN) return;
    float s[cL], mx = -INFINITY;
#pragma unroll
    for (int l = 0; l < cL; l++) { s[l] = score[(size_t)l * cN + wid]; mx = fmaxf(mx, s[l]); }
    float se = 0.f;
#pragma unroll
    for (int l = 0; l < cL; l++) { s[l] = __expf(s[l] - mx); se += s[l]; }
    float inv = 1.f / se;
    int g = batch[wid];
    float acc0 = 0.f, acc1 = 0.f;
#pragma unroll
    for (int l = 0; l < cL; l++) {
        const float* sp = seq + ((size_t)l * cN + wid) * 128;
        float w = s[l] * inv;
        acc0 += w * sp[lane];
        acc1 += w * sp[lane + 64];
    }
    atomicAdd(&pooled[(size_t)g * 128 + lane], acc0);
    atomicAdd(&pooled[(size_t)g * 128 + lane + 64], acc1);
}

__global__ void count_kernel(const int* __restrict__ batch, float* __restrict__ cnt) {
    int i = blockIdx.x * blockDim.x + threadIdx.x;
    if (i < cN) atomicAdd(&cnt[batch[i]], 1.f);
}

__global__ void div_pool_kernel(float* __restrict__ pooled, const float* __restrict__ cnt) {
    int i = blockIdx.x * blockDim.x + threadIdx.x;
    if (i < cG * 128) pooled[i] /= fmaxf(cnt[i >> 7], 1.f);
}

// ---------------- fused MLP head ----------------
__global__ __launch_bounds__(256)
void head_fused_kernel(const float* __restrict__ pooled,
                       const float* __restrict__ m1_w, const float* __restrict__ m1_b,
                       const float* __restrict__ m2_w, const float* __restrict__ m2_b,
                       const float* __restrict__ res_w, const float* __restrict__ res_b,
                       float* __restrict__ out) {
    __shared__ float pl[4][128];
    __shared__ float hd[4][128];
    const int tid = threadIdx.x;
    const int r0 = blockIdx.y << 2;
    const int c0 = blockIdx.x << 8;
#pragma unroll
    for (int e = tid; e < 512; e += 256) {
        int r = e >> 7, k = e & 127;
        pl[r][k] = pooled[(size_t)(r0 + r) * 128 + k];
    }
    __syncthreads();
#pragma unroll
    for (int e = tid; e < 512; e += 256) {
        int r = e >> 7, n = e & 127;
        float acc = m1_b[n];
#pragma unroll 8
        for (int k = 0; k < 128; k++) acc = fmaf(pl[r][k], m1_w[k * 128 + n], acc);
        hd[r][n] = fmaxf(acc, 0.f);
    }
    __syncthreads();
    int col = c0 + tid;
    if (col >= cOUT) return;
    float b = m2_b[col] + res_b[col];
    float acc[4] = {b, b, b, b};
    for (int k = 0; k < 128; k++) {
        float w2 = m2_w[(size_t)k * cOUT + col];
        float wr = res_w[(size_t)k * cOUT + col];
#pragma unroll
        for (int r = 0; r < 4; r++)
            acc[r] = fmaf(hd[r][k], w2, fmaf(pl[r][k], wr, acc[r]));
    }
#pragma unroll
    for (int r = 0; r < 4; r++)
        out[(size_t)(r0 + r) * cOUT + col] = acc[r];
}

// ---------------- launch helpers ----------------
static inline int ceil_div(long a, long b) { return (int)((a + b - 1) / b); }

// non-swizzled (embedding: single column block)
template<int OUTB>
static void launch_mfma(const unsigned short* A1, const unsigned short* B1, int k1,
                        const unsigned short* A2, const unsigned short* B2, int k2,
                        const float* bias, void* C, int M, int N, hipStream_t s) {
    dim3 g((N + 127) >> 7, (M + 127) >> 7);
    if (bias) gemm_mfma_kernel<1, OUTB, 0><<<g, 256, 0, s>>>(A1, B1, k1, A2, B2, k2, bias, C, M, N, 0);
    else      gemm_mfma_kernel<0, OUTB, 0><<<g, 256, 0, s>>>(A1, B1, k1, A2, B2, k2, bias, C, M, N, 0);
}
// XCD-swizzled (proj GEMM: nbn column blocks share a row panel)
template<int OUTB>
static void launch_mfma_swz(const unsigned short* A1, const unsigned short* B1, int k1,
                            const float* bias, void* C, int M, int N, hipStream_t s) {
    int nbn = N >> 7;
    int groups = ((((M + 127) >> 7) + 7) / 8) * 8;   // pad to multiple of 8
    dim3 g(groups * nbn);
    gemm_mfma_kernel<1, OUTB, 1><<<g, 256, 0, s>>>(A1, B1, k1, nullptr, nullptr, 0, bias, C, M, N, nbn);
}

static void fillF(float* p, long n, float v, hipStream_t s) {
    fill_f32_kernel<<<ceil_div(n, 256), 256, 0, s>>>(p, n, v);
}
static void fillI(int* p, long n, int v, hipStream_t s) {
    fill_i32_kernel<<<ceil_div(n, 256), 256, 0, s>>>(p, n, v);
}
static void convB(const float* a, unsigned short* b, long n, hipStream_t s) {
    conv_bf16_kernel<<<ceil_div(n, 256), 256, 0, s>>>(a, b, n);
}

extern "C" void kernel_launch(void* const* d_in, const int* in_sizes, int n_in,
                              void* d_out, int out_size, void* d_ws, size_t ws_size,
                              hipStream_t stream) {
    const float* x      = (const float*)d_in[0];
    const int*   ei     = (const int*)d_in[1];
    const int*   batch  = (const int*)d_in[2];
    const float* emb_W  = (const float*)d_in[3];
    const float* emb_b  = (const float*)d_in[4];
    const float* Wl     = (const float*)d_in[5];
    const float* bl     = (const float*)d_in[6];
    const float* Wr     = (const float*)d_in[7];
    const float* br     = (const float*)d_in[8];
    const float* att_a  = (const float*)d_in[9];
    const float* conv_b = (const float*)d_in[10];
    const float* ln_w   = (const float*)d_in[11];
    const float* ln_b   = (const float*)d_in[12];
    const float* Wih_f  = (const float*)d_in[13];
    const float* Whh_f  = (const float*)d_in[14];
    const float* bih_f  = (const float*)d_in[15];
    const float* bhh_f  = (const float*)d_in[16];
    const float* Wih_b  = (const float*)d_in[17];
    const float* Whh_b  = (const float*)d_in[18];
    const float* bih_b  = (const float*)d_in[19];
    const float* bhh_b  = (const float*)d_in[20];
    const float* jk_w   = (const float*)d_in[21];
    // d_in[22] = jk_b: constant across L -> softmax-invariant, unused
    const float* m1_w   = (const float*)d_in[23];
    const float* m1_b   = (const float*)d_in[24];
    const float* m2_w   = (const float*)d_in[25];
    const float* m2_b   = (const float*)d_in[26];
    const float* res_w  = (const float*)d_in[27];
    const float* res_b  = (const float*)d_in[28];
    float* out = (float*)d_out;

    const int* src = ei;
    const int* dst = ei + cE;

    // ---------------- workspace layout ----------------
    char* ws = (char*)d_ws;
    size_t off = 0;
    auto alloc = [&](size_t bytes) -> char* {
        size_t o = (off + 255) & ~(size_t)255;
        off = o + bytes;
        return ws + o;
    };
    unsigned short* x16     = (unsigned short*)alloc((size_t)cN * cFin * 2);
    unsigned short* embWT   = (unsigned short*)alloc((size_t)cC * cFin * 2);
    unsigned short* emb_b16 = (unsigned short*)alloc((size_t)cN * cC * 2);
    float*          seq     = (float*)alloc((size_t)cL * cN * cC * 4);
    unsigned short* seqb16  = (unsigned short*)alloc((size_t)cL * cN * cC * 2);
    unsigned short* WT      = (unsigned short*)alloc((size_t)cL * 1024 * 128 * 2);
    float*          bb      = (float*)alloc((size_t)cL * 1024 * 4);
    unsigned short* WihPf   = (unsigned short*)alloc((size_t)c4HL * cC * 2);
    unsigned short* WhhPf   = (unsigned short*)alloc((size_t)c4HL * cHL * 2);
    unsigned short* WihPb   = (unsigned short*)alloc((size_t)c4HL * cC * 2);
    unsigned short* WhhPb   = (unsigned short*)alloc((size_t)c4HL * cHL * 2);
    float*          biasPf  = (float*)alloc((size_t)c4HL * 4);
    float*          biasPb  = (float*)alloc((size_t)c4HL * 4);
    unsigned short* hf0     = (unsigned short*)alloc((size_t)cN * cHL * 2);
    unsigned short* hf1     = (unsigned short*)alloc((size_t)cN * cHL * 2);
    unsigned short* hbk0    = (unsigned short*)alloc((size_t)cN * cHL * 2);
    unsigned short* hbk1    = (unsigned short*)alloc((size_t)cN * cHL * 2);
    float*          cf      = (float*)alloc((size_t)cN * cHL * 4);
    float*          cbk     = (float*)alloc((size_t)cN * cHL * 4);
    float*          jks     = (float*)alloc((size_t)cL * cN * 4);
    float*          pooled  = (float*)alloc((size_t)cG * cC * 4);
    float*          cnt     = (float*)alloc((size_t)cG * 4);
    int*            offs    = (int*)alloc((size_t)(cN + 1) * 4);
    int*            cursor  = (int*)alloc((size_t)cN * 4);
    int*            src_csr = (int*)alloc((size_t)cE * 4);
    unsigned short* xlr     = (unsigned short*)alloc((size_t)cN * 1024 * 2);

    hipStream_t s = stream;

    // ---------------- CSR by dst (payload = src) ----------------
    fillI(cursor, cN, 0, s);
    hist_kernel<<<ceil_div(cE, 256), 256, 0, s>>>(dst, cursor);
    scan_kernel<<<1, 256, 0, s>>>(cursor, offs);
    copy_i32_kernel<<<ceil_div(cN, 256), 256, 0, s>>>(offs, cursor, cN);
    scatter_kernel<<<ceil_div(cE, 256), 256, 0, s>>>(src, dst, cursor, src_csr);

    // ---------------- weight prep (bf16) ----------------
    wproj_prep_kernel<<<ceil_div((long)cL * 1024 * 128, 256), 256, 0, s>>>(Wl, Wr, WT);
    bias_prep_kernel<<<ceil_div((long)cL * 1024, 256), 256, 0, s>>>(bl, br, bb);
    embw_prep_kernel<<<ceil_div((long)cC * cFin, 256), 256, 0, s>>>(emb_W, embWT);
    convB(x, x16, (long)cN * cFin, s);
    lstm_prep_kernel<<<ceil_div((long)c4HL * 449, 256), 256, 0, s>>>(
        Wih_f, Whh_f, bih_f, bhh_f, WihPf, WhhPf, biasPf);
    lstm_prep_kernel<<<ceil_div((long)c4HL * 449, 256), 256, 0, s>>>(
        Wih_b, Whh_b, bih_b, bhh_b, WihPb, WhhPb, biasPb);

    // ---------------- embedding (bf16 MFMA, direct bf16 out) ----------------
    launch_mfma<1>(x16, embWT, cFin, nullptr, nullptr, 0, emb_b, emb_b16, cN, cC, s);

    // ---------------- GAT layers ----------------
    for (int l = 0; l < cL; l++) {
        const unsigned short* hin = (l == 0) ? emb_b16 : seqb16 + (size_t)(l - 1) * cN * cC;
        launch_mfma_swz<1>(hin, WT + (size_t)l * 1024 * 128, cC,
                           bb + (size_t)l * 1024, xlr, cN, 1024, s);
        gat_fused_kernel<<<ceil_div((long)cN * 64, 256), 256, 0, s>>>(
            xlr, src_csr, offs, att_a + (size_t)l * cH * cC,
            conv_b + (size_t)l * cC, ln_w + (size_t)l * cC, ln_b + (size_t)l * cC,
            seq + (size_t)l * cN * cC, seqb16 + (size_t)l * cN * cC);
    }

    // ---------------- bidirectional LSTM (both directions per launch) -------
    fillF(jks, (long)cL * cN, 0.f, s);
    unsigned short* hfb[2]  = {hf0, hf1};
    unsigned short* hbb[2]  = {hbk0, hbk1};
    dim3 lg(80 * 10);   // 80 row-groups (padded) x 5 bn x 2 dir, XCD-swizzled
    for (int k = 0; k < cL; k++) {
        int cur = k & 1, prev = cur ^ 1;
        int t = cL - 1 - k;
        const unsigned short* A1f = seqb16 + (size_t)k * cN * cC;
        const unsigned short* A1b = seqb16 + (size_t)t * cN * cC;
        if (k == 0)
            gemm_lstm_dual_kernel<1><<<lg, 512, 0, s>>>(
                A1f, A1b, WihPf, WihPb, nullptr, nullptr, nullptr, nullptr,
                biasPf, biasPb, cf, cbk, hfb[cur], hbb[cur], jk_w,
                jks + (size_t)k * cN, jks + (size_t)t * cN);
        else
            gemm_lstm_dual_kernel<0><<<lg, 512, 0, s>>>(
                A1f, A1b, WihPf, WihPb, hfb[prev], hbb[prev], WhhPf, WhhPb,
                biasPf, biasPb, cf, cbk, hfb[cur], hbb[cur], jk_w,
                jks + (size_t)k * cN, jks + (size_t)t * cN);
    }

    // ---------------- JK softmax, pooling, fused head ----------------
    fillF(pooled, (long)cG * cC, 0.f, s);
    fillF(cnt, cG, 0.f, s);
    jk_pool_kernel<<<ceil_div((long)cN * 64, 256), 256, 0, s>>>(seq, jks, batch, pooled);
    count_kernel<<<ceil_div(cN, 256), 256, 0, s>>>(batch, cnt);
    div_pool_kernel<<<ceil_div((long)cG * 128, 256), 256, 0, s>>>(pooled, cnt);
    head_fused_kernel<<<dim3(ceil_div(cOUT, 256), cG / 4), 256, 0, s>>>(
        pooled, m1_w, m1_b, m2_w, m2_b, res_w, res_b, out);
}

// Round 11
// 683.463 us; speedup vs baseline: 5.7000x; 1.0226x over previous
//
#include <hip/hip_runtime.h>
#include <hip/hip_bf16.h>
#include <math.h>

// Problem constants (from reference)
constexpr int cN   = 10000;
constexpr int cE   = 120000;
constexpr int cFin = 64;
constexpr int cC   = 128;
constexpr int cH   = 4;
constexpr int cL   = 5;
constexpr int cG   = 500;
constexpr int cOUT = 1801;
constexpr int cHL  = 320;          // (L*C)/2
constexpr int c4HL = 4 * cHL;      // 1280
constexpr int cP   = 2 * c4HL;     // 2560 (fwd|bwd gate cols)

typedef short bf16x8 __attribute__((ext_vector_type(8)));
typedef float f32x4 __attribute__((ext_vector_type(4)));

__device__ inline unsigned short f2b(float x) {
    union { __hip_bfloat16 h; unsigned short u; } cv;
    cv.h = __float2bfloat16(x);
    return cv.u;
}
__device__ inline float b2f(unsigned short u) {
    union { unsigned int i; float f; } cv;
    cv.i = ((unsigned int)u) << 16;
    return cv.f;
}
__device__ inline float fsig(float x)  { return 1.f / (1.f + __expf(-x)); }
__device__ inline float ftanh(float x) { return 1.f - 2.f / (__expf(2.f * x) + 1.f); }

#define GLD16(g, l) __builtin_amdgcn_global_load_lds( \
    (const __attribute__((address_space(1))) unsigned int*)(g), \
    (__attribute__((address_space(3))) unsigned int*)(l), 16, 0, 0)

// ---------------- utility kernels ----------------
__global__ void fill_i32_kernel(int* __restrict__ p, long n, int v) {
    long i = (long)blockIdx.x * blockDim.x + threadIdx.x;
    if (i < n) p[i] = v;
}
__global__ void copy_i32_kernel(const int* __restrict__ a, int* __restrict__ b, long n) {
    long i = (long)blockIdx.x * blockDim.x + threadIdx.x;
    if (i < n) b[i] = a[i];
}
__global__ void conv_bf16_kernel(const float* __restrict__ a, unsigned short* __restrict__ b, long n) {
    long i = (long)blockIdx.x * blockDim.x + threadIdx.x;
    if (i < n) b[i] = f2b(a[i]);
}
// zero jks(50000) | pooled(64000) | cnt(500) in one launch
__global__ void init_tail_kernel(float* __restrict__ jks, float* __restrict__ pooled,
                                 float* __restrict__ cnt) {
    long i = (long)blockIdx.x * blockDim.x + threadIdx.x;
    if (i < (long)cL * cN) jks[i] = 0.f;
    else if (i < (long)cL * cN + cG * cC) pooled[i - (long)cL * cN] = 0.f;
    else if (i < (long)cL * cN + cG * cC + cG) cnt[i - (long)cL * cN - cG * cC] = 0.f;
}
// Wl,Wr: [L][128][512] fp32 -> WT: [L][1024][128] bf16 (rows 0..511 = Wl^T, 512..1023 = Wr^T)
__global__ void wproj_prep_kernel(const float* __restrict__ Wl, const float* __restrict__ Wr,
                                  unsigned short* __restrict__ WT) {
    long i = (long)blockIdx.x * blockDim.x + threadIdx.x;
    if (i >= (long)cL * 1024 * 128) return;
    int k = i & 127;
    int n = (int)((i >> 7) & 1023);
    int l = (int)(i >> 17);
    const float* W = (n < 512) ? Wl : Wr;
    int nn = n & 511;
    WT[i] = f2b(W[(size_t)l * 65536 + (size_t)k * 512 + nn]);
}
// bl,br: [L][512] -> bb: [L][1024]
__global__ void bias_prep_kernel(const float* __restrict__ bl, const float* __restrict__ br,
                                 float* __restrict__ bb) {
    int i = blockIdx.x * blockDim.x + threadIdx.x;
    if (i >= cL * 1024) return;
    int n = i & 1023, l = i >> 10;
    bb[i] = (n < 512) ? bl[l * 512 + n] : br[l * 512 + (n - 512)];
}
// emb_W: [64][128] fp32 (KxN) -> embWT: [128][64] bf16 (NxK)
__global__ void embw_prep_kernel(const float* __restrict__ W, unsigned short* __restrict__ WT) {
    int i = blockIdx.x * blockDim.x + threadIdx.x;
    if (i >= cC * cFin) return;
    int k = i & 63, n = i >> 6;
    WT[i] = f2b(W[(size_t)k * cC + n]);
}
// LSTM weights -> gate-interleaved rows: p = (u>>4)*64 + g*16 + (u&15), r = g*320+u
__global__ void lstm_prep_kernel(const float* __restrict__ Wih, const float* __restrict__ Whh,
                                 const float* __restrict__ bih, const float* __restrict__ bhh,
                                 unsigned short* __restrict__ WihP, unsigned short* __restrict__ WhhP,
                                 float* __restrict__ biasP) {
    long i = (long)blockIdx.x * blockDim.x + threadIdx.x;   // over 1280*449
    if (i >= (long)c4HL * 449) return;
    int p = (int)(i / 449), c = (int)(i % 449);
    int u = (p >> 6) * 16 + (p & 15);
    int g = (p >> 4) & 3;
    int r = g * cHL + u;
    if (c < cC)       WihP[(size_t)p * cC + c] = f2b(Wih[(size_t)r * cC + c]);
    else if (c < 448) WhhP[(size_t)p * cHL + (c - cC)] = f2b(Whh[(size_t)r * cHL + (c - cC)]);
    else              biasP[p] = bih[r] + bhh[r];
}

// ---------------- CSR build (by dst), payload = src node ----------------
__global__ void hist_kernel(const int* __restrict__ dst, int* __restrict__ count) {
    int i = blockIdx.x * blockDim.x + threadIdx.x;
    if (i < cE) atomicAdd(&count[dst[i]], 1);
}
__global__ void scan_kernel(const int* __restrict__ count, int* __restrict__ offs) {
    __shared__ int part[256];
    const int tid = threadIdx.x;
    const int CH = (cN + 255) / 256;
    int base = tid * CH;
    int s = 0;
    for (int i = 0; i < CH; i++) {
        int idx = base + i;
        if (idx < cN) s += count[idx];
    }
    part[tid] = s;
    __syncthreads();
    for (int d = 1; d < 256; d <<= 1) {
        int v = 0;
        if (tid >= d) v = part[tid - d];
        __syncthreads();
        if (tid >= d) part[tid] += v;
        __syncthreads();
    }
    int prefix = (tid == 0) ? 0 : part[tid - 1];
    for (int i = 0; i < CH; i++) {
        int idx = base + i;
        if (idx < cN) { offs[idx] = prefix; prefix += count[idx]; }
    }
    if (tid == 255) offs[cN] = prefix;
}
__global__ void scatter_kernel(const int* __restrict__ src, const int* __restrict__ dst,
                               int* __restrict__ cursor, int* __restrict__ src_csr) {
    int i = blockIdx.x * blockDim.x + threadIdx.x;
    if (i < cE) {
        int pos = atomicAdd(&cursor[dst[i]], 1);
        src_csr[pos] = src[i];
    }
}

// ---------------- bf16 MFMA GEMM (128x128, 4 waves) ----------------
// SWZ=1: 1D grid, XCD-aware group swizzle.
template<int HASBIAS, int OUTB, int SWZ>
__global__ __launch_bounds__(256)
void gemm_mfma_kernel(const unsigned short* __restrict__ A1, const unsigned short* __restrict__ B1, int k1,
                      const unsigned short* __restrict__ A2, const unsigned short* __restrict__ B2, int k2,
                      const float* __restrict__ bias, void* __restrict__ Cout, int M, int N, int nbn) {
    int bm, bn;
    if (SWZ) {
        int bid = blockIdx.x;
        int xcd = bid & 7, j = bid >> 3;
        int g   = (j / nbn) * 8 + xcd;
        bm = g << 7;
        bn = (j % nbn) << 7;
        if (bm >= M) return;   // padded group: whole block exits (pre-barrier)
    } else {
        bm = blockIdx.y << 7;
        bn = blockIdx.x << 7;
    }
    __shared__ unsigned short lds[2][2][128 * 32];
    const int tid  = threadIdx.x;
    const int lane = tid & 63;
    const int wave = tid >> 6;
    const int wr = (wave >> 1) << 6;
    const int wc = (wave & 1) << 6;
    const int ns1 = k1 >> 5, ns2 = k2 >> 5, ns = ns1 + ns2;

    const int lrow = lane >> 2;
    const int lke  = (lane & 3) << 3;

    auto stage = [&](int s, int buf) {
        const unsigned short *Ab, *Bb;
        int stride, koff;
        if (s < ns1) { Ab = A1; Bb = B1; stride = k1; koff = s << 5; }
        else         { Ab = A2; Bb = B2; stride = k2; koff = (s - ns1) << 5; }
#pragma unroll
        for (int r = 0; r < 2; r++) {
            int ch  = wave * 2 + r;
            int row = ch * 16 + lrow;
            int ga  = bm + row; if (ga >= M) ga = M - 1;
            GLD16(Ab + (size_t)ga * stride + koff + lke, &lds[buf][0][ch * 512]);
            GLD16(Bb + (size_t)(bn + row) * stride + koff + lke, &lds[buf][1][ch * 512]);
        }
    };

    f32x4 acc[4][4];
#pragma unroll
    for (int i = 0; i < 4; i++)
#pragma unroll
        for (int j = 0; j < 4; j++) acc[i][j] = (f32x4){0.f, 0.f, 0.f, 0.f};

    stage(0, 0);
    const int ko  = (lane >> 4) << 3;
    const int rla = lane & 15;
    for (int s = 0; s < ns; s++) {
        int buf = s & 1;
        __syncthreads();
        if (s + 1 < ns) stage(s + 1, buf ^ 1);
        bf16x8 af[4], bff[4];
#pragma unroll
        for (int f = 0; f < 4; f++) {
            af[f]  = *(const bf16x8*)&lds[buf][0][(wr + f * 16 + rla) * 32 + ko];
            bff[f] = *(const bf16x8*)&lds[buf][1][(wc + f * 16 + rla) * 32 + ko];
        }
#pragma unroll
        for (int i = 0; i < 4; i++)
#pragma unroll
            for (int j = 0; j < 4; j++)
                acc[i][j] = __builtin_amdgcn_mfma_f32_16x16x32_bf16(af[i], bff[j], acc[i][j], 0, 0, 0);
    }

#pragma unroll
    for (int i = 0; i < 4; i++) {
#pragma unroll
        for (int v = 0; v < 4; v++) {
            int m = bm + wr + i * 16 + ((lane >> 4) << 2) + v;
            if (m < M) {
#pragma unroll
                for (int j = 0; j < 4; j++) {
                    int n = bn + wc + j * 16 + rla;
                    float val = acc[i][j][v];
                    if (HASBIAS) val += bias[n];
                    if (OUTB) ((unsigned short*)Cout)[(size_t)m * N + n] = f2b(val);
                    else      ((float*)Cout)[(size_t)m * N + n] = val;
                }
            }
        }
    }
}

// ---------------- dual-direction LSTM step: 128x256 tile, 8 waves -----------
// Grid 800: bid -> xcd=bid&7, jj=bid>>3; g=(jj/10)*8+xcd (row panel, padded
// to 80); inner=jj%10 -> bn=(inner%5)*256, z=inner/5 (direction).
// USEP=1: Wih contribution precomputed in P (bf16, [step][10000][2560],
// fwd cols 0..1279, bwd 1280..2559); GEMM runs only K=320 (h @ Whh^T).
// Gate-interleaved cols: lane's j=0..3 are gates i,f,g,o of unit
// u = ((bn+wc)>>6)*16 + rla.
template<int FIRST, int USEP>
__global__ __launch_bounds__(512)
void gemm_lstm_dual_kernel(const unsigned short* __restrict__ A1f, const unsigned short* __restrict__ A1b,
                           const unsigned short* __restrict__ Bihf, const unsigned short* __restrict__ Bihb,
                           const unsigned short* __restrict__ A2f, const unsigned short* __restrict__ A2b,
                           const unsigned short* __restrict__ Bhhf, const unsigned short* __restrict__ Bhhb,
                           const float* __restrict__ biasPf, const float* __restrict__ biasPb,
                           float* __restrict__ cff, float* __restrict__ cbb,
                           unsigned short* __restrict__ hOutf, unsigned short* __restrict__ hOutb,
                           const float* __restrict__ jkw,
                           float* __restrict__ scoref, float* __restrict__ scoreb,
                           const unsigned short* __restrict__ PfP, const unsigned short* __restrict__ PbP) {
    constexpr int M = cN;
    constexpr int k1 = USEP ? 0 : cC;
    constexpr int k2 = FIRST ? 0 : cHL;
    const int bid = blockIdx.x;
    const int xcd = bid & 7, jj = bid >> 3;
    const int g     = (jj / 10) * 8 + xcd;
    const int inner = jj % 10;
    const int bm = g << 7;
    if (bm >= M) return;                 // padded group: uniform pre-barrier exit
    const int bn = (inner % 5) << 8;     // 0..1024 step 256
    const int z  = inner / 5;

    const unsigned short* A1 = z ? A1b : A1f;
    const unsigned short* B1 = z ? Bihb : Bihf;
    const unsigned short* A2 = z ? A2b : A2f;
    const unsigned short* B2 = z ? Bhhb : Bhhf;
    const float* biasP = z ? biasPb : biasPf;
    float* cbuf = z ? cbb : cff;
    unsigned short* hOut = z ? hOutb : hOutf;
    const float* jkwz = jkw + (z ? cHL : 0);
    float* score_t = z ? scoreb : scoref;
    const unsigned short* Pst = z ? PbP : PfP;
    const int pcb = (z ? c4HL : 0) + bn;

    __shared__ unsigned short ldsA[2][128 * 32];
    __shared__ unsigned short ldsB[2][256 * 32];
    const int tid  = threadIdx.x;
    const int lane = tid & 63;
    const int wave = tid >> 6;           // 0..7
    const int wr = (wave >> 2) << 6;     // 0 or 64
    const int wc = (wave & 3) << 6;      // 0,64,128,192
    const int ns1 = k1 >> 5, ns2 = k2 >> 5, ns = ns1 + ns2;

    const int lrow = lane >> 2;
    const int lke  = (lane & 3) << 3;

    auto stage = [&](int s, int buf) {
        const unsigned short *Ab, *Bb;
        int stride, koff;
        if (s < ns1) { Ab = A1; Bb = B1; stride = k1; koff = s << 5; }
        else         { Ab = A2; Bb = B2; stride = k2; koff = (s - ns1) << 5; }
        {
            int row = wave * 16 + lrow;
            int ga  = bm + row; if (ga >= M) ga = M - 1;
            GLD16(Ab + (size_t)ga * stride + koff + lke, &ldsA[buf][wave * 512]);
        }
#pragma unroll
        for (int r = 0; r < 2; r++) {
            int ch  = wave * 2 + r;
            int row = ch * 16 + lrow;
            GLD16(Bb + (size_t)(bn + row) * stride + koff + lke, &ldsB[buf][ch * 512]);
        }
    };

    f32x4 acc[4][4];
#pragma unroll
    for (int i = 0; i < 4; i++)
#pragma unroll
        for (int j = 0; j < 4; j++) acc[i][j] = (f32x4){0.f, 0.f, 0.f, 0.f};

    if (ns > 0) stage(0, 0);
    const int ko  = (lane >> 4) << 3;
    const int rla = lane & 15;
    for (int s = 0; s < ns; s++) {
        int buf = s & 1;
        __syncthreads();
        if (s + 1 < ns) stage(s + 1, buf ^ 1);
        bf16x8 af[4], bff[4];
#pragma unroll
        for (int f = 0; f < 4; f++) {
            af[f]  = *(const bf16x8*)&ldsA[buf][(wr + f * 16 + rla) * 32 + ko];
            bff[f] = *(const bf16x8*)&ldsB[buf][(wc + f * 16 + rla) * 32 + ko];
        }
#pragma unroll
        for (int i = 0; i < 4; i++)
#pragma unroll
            for (int j = 0; j < 4; j++)
                acc[i][j] = __builtin_amdgcn_mfma_f32_16x16x32_bf16(af[i], bff[j], acc[i][j], 0, 0, 0);
    }

    // gate-fused epilogue (fast sigmoid/tanh via v_exp_f32)
    float bias4[4];
#pragma unroll
    for (int j = 0; j < 4; j++) bias4[j] = biasP[bn + wc + j * 16 + rla];
    const int u = ((bn + wc) >> 6) * 16 + rla;
    const float jw = jkwz[u];

#pragma unroll
    for (int i = 0; i < 4; i++) {
#pragma unroll
        for (int v = 0; v < 4; v++) {
            int m = bm + wr + i * 16 + ((lane >> 4) << 2) + v;
            bool ok = (m < M);                      // uniform across rla group
            float p4[4] = {0.f, 0.f, 0.f, 0.f};
            if (USEP) {
                int mp = ok ? m : M - 1;            // clamp padded rows
#pragma unroll
                for (int j = 0; j < 4; j++)
                    p4[j] = b2f(Pst[(size_t)mp * cP + pcb + wc + j * 16 + rla]);
            }
            float gi = acc[i][0][v] + p4[0] + bias4[0];
            float gf = acc[i][1][v] + p4[1] + bias4[1];
            float gg = acc[i][2][v] + p4[2] + bias4[2];
            float go = acc[i][3][v] + p4[3] + bias4[3];
            float si = fsig(gi);
            float sf = fsig(gf);
            float so = fsig(go);
            float tg = ftanh(gg);
            size_t idx = (size_t)m * cHL + u;
            float cold = (FIRST || !ok) ? 0.f : cbuf[idx];
            float cc = sf * cold + si * tg;
            float hh = so * ftanh(cc);
            if (ok) { cbuf[idx] = cc; hOut[idx] = f2b(hh); }
            float part = ok ? hh * jw : 0.f;
#pragma unroll
            for (int o = 1; o < 16; o <<= 1) part += __shfl_xor(part, o);
            if (rla == 0 && ok) atomicAdd(&score_t[m], part);
        }
    }
}

// ---------------- fused GAT layer: one wave per node, 4-edge unrolled -------
__global__ __launch_bounds__(256)
void gat_fused_kernel(const unsigned short* __restrict__ xlr, const int* __restrict__ src_csr,
                      const int* __restrict__ offs, const float* __restrict__ att,
                      const float* __restrict__ conv_b, const float* __restrict__ lnw,
                      const float* __restrict__ lnb, float* __restrict__ seq_l,
                      unsigned short* __restrict__ seqb_l) {
    const int wv   = (blockIdx.x * blockDim.x + threadIdx.x) >> 6;  // node
    const int lane = threadIdx.x & 63;
    if (wv >= cN) return;
    const int h   = lane >> 4;
    const int cb  = (lane & 15) << 3;

    bf16x8 xrv = *(const bf16x8*)&xlr[(size_t)wv * 1024 + 512 + lane * 8];
    float xr[8], av[8];
#pragma unroll
    for (int k = 0; k < 8; k++) {
        xr[k] = b2f((unsigned short)xrv[k]);
        av[k] = att[h * 128 + cb + k];
    }

    float m = -INFINITY, l = 0.f;
    float acc[8];
#pragma unroll
    for (int k = 0; k < 8; k++) acc[k] = 0.f;

    const int beg = offs[wv], end = offs[wv + 1];
    int j = beg;
    // 4-edge pipelined online softmax: 4 gathers in flight, one rescale
    for (; j + 3 < end; j += 4) {
        int s0 = src_csr[j], s1 = src_csr[j + 1], s2 = src_csr[j + 2], s3 = src_csr[j + 3];
        bf16x8 xv0 = *(const bf16x8*)&xlr[(size_t)s0 * 1024 + lane * 8];
        bf16x8 xv1 = *(const bf16x8*)&xlr[(size_t)s1 * 1024 + lane * 8];
        bf16x8 xv2 = *(const bf16x8*)&xlr[(size_t)s2 * 1024 + lane * 8];
        bf16x8 xv3 = *(const bf16x8*)&xlr[(size_t)s3 * 1024 + lane * 8];
        float x0[8], x1[8], x2[8], x3[8];
        float sc0 = 0.f, sc1 = 0.f, sc2 = 0.f, sc3 = 0.f;
#pragma unroll
        for (int k = 0; k < 8; k++) {
            x0[k] = b2f((unsigned short)xv0[k]);
            x1[k] = b2f((unsigned short)xv1[k]);
            x2[k] = b2f((unsigned short)xv2[k]);
            x3[k] = b2f((unsigned short)xv3[k]);
            float v0 = x0[k] + xr[k]; v0 = v0 > 0.f ? v0 : 0.2f * v0;
            float v1 = x1[k] + xr[k]; v1 = v1 > 0.f ? v1 : 0.2f * v1;
            float v2 = x2[k] + xr[k]; v2 = v2 > 0.f ? v2 : 0.2f * v2;
            float v3 = x3[k] + xr[k]; v3 = v3 > 0.f ? v3 : 0.2f * v3;
            sc0 = fmaf(v0, av[k], sc0);
            sc1 = fmaf(v1, av[k], sc1);
            sc2 = fmaf(v2, av[k], sc2);
            sc3 = fmaf(v3, av[k], sc3);
        }
#pragma unroll
        for (int o = 1; o < 16; o <<= 1) {
            sc0 += __shfl_xor(sc0, o);
            sc1 += __shfl_xor(sc1, o);
            sc2 += __shfl_xor(sc2, o);
            sc3 += __shfl_xor(sc3, o);
        }
        float mn = fmaxf(fmaxf(fmaxf(sc0, sc1), fmaxf(sc2, sc3)), m);
        float r  = __expf(m - mn);
        float p0 = __expf(sc0 - mn);
        float p1 = __expf(sc1 - mn);
        float p2 = __expf(sc2 - mn);
        float p3 = __expf(sc3 - mn);
        l = l * r + p0 + p1 + p2 + p3;
#pragma unroll
        for (int k = 0; k < 8; k++)
            acc[k] = fmaf(acc[k], r,
                          fmaf(p0, x0[k], fmaf(p1, x1[k], fmaf(p2, x2[k], p3 * x3[k]))));
        m = mn;
    }
    // 1-3 edge tail
    for (; j < end; j++) {
        int s0 = src_csr[j];
        bf16x8 xv = *(const bf16x8*)&xlr[(size_t)s0 * 1024 + lane * 8];
        float x[8], sc = 0.f;
#pragma unroll
        for (int k = 0; k < 8; k++) {
            x[k] = b2f((unsigned short)xv[k]);
            float v = x[k] + xr[k];
            v = v > 0.f ? v : 0.2f * v;
            sc = fmaf(v, av[k], sc);
        }
#pragma unroll
        for (int o = 1; o < 16; o <<= 1) sc += __shfl_xor(sc, o);
        float mn = fmaxf(m, sc);
        float r  = __expf(m - mn);
        float p  = __expf(sc - mn);
        l = l * r + p;
#pragma unroll
        for (int k = 0; k < 8; k++) acc[k] = fmaf(acc[k], r, p * x[k]);
        m = mn;
    }
    float inv = 1.f / (l + 1e-16f);

#pragma unroll
    for (int k = 0; k < 8; k++) {
        float v = acc[k] * inv;
        v += __shfl_xor(v, 16);
        v += __shfl_xor(v, 32);
        acc[k] = 0.25f * v + conv_b[cb + k];
    }
    float ssum = 0.f;
#pragma unroll
    for (int k = 0; k < 8; k++) ssum += acc[k];
#pragma unroll
    for (int o = 1; o < 16; o <<= 1) ssum += __shfl_xor(ssum, o);
    float mu = ssum * (1.f / 128.f);
    float vs = 0.f;
#pragma unroll
    for (int k = 0; k < 8; k++) { float d = acc[k] - mu; vs = fmaf(d, d, vs); }
#pragma unroll
    for (int o = 1; o < 16; o <<= 1) vs += __shfl_xor(vs, o);
    float rstd = 1.f / sqrtf(vs * (1.f / 128.f) + 1e-5f);

    float outv[8];
#pragma unroll
    for (int k = 0; k < 8; k++)
        outv[k] = (acc[k] - mu) * rstd * lnw[cb + k] + lnb[cb + k];

    if (h == 0) {
        size_t b = (size_t)wv * 128 + cb;
        float4 o0 = make_float4(outv[0], outv[1], outv[2], outv[3]);
        float4 o1 = make_float4(outv[4], outv[5], outv[6], outv[7]);
        *(float4*)&seq_l[b]     = o0;
        *(float4*)&seq_l[b + 4] = o1;
        bf16x8 ob;
#pragma unroll
        for (int k = 0; k < 8; k++) ob[k] = (short)f2b(outv[k]);
        *(bf16x8*)&seqb_l[b] = ob;
    }
}

// ---------------- JK softmax + mean pooling ----------------
__global__ void jk_pool_kernel(const float* __restrict__ seq, const float* __restrict__ score,
                               const int* __restrict__ batch, float* __restrict__ pooled) {
    int wid = (blockIdx.x * blockDim.x + threadIdx.x) >> 6;
    int lane = threadIdx.x & 63;
    if (wid >= cN) return;
    float s[cL], mx = -INFINITY;
#pragma unroll
    for (int l = 0; l < cL; l++) { s[l] = score[(size_t)l * cN + wid]; mx = fmaxf(mx, s[l]); }
    float se = 0.f;
#pragma unroll
    for (int l = 0; l < cL; l++) { s[l] = __expf(s[l] - mx); se += s[l]; }
    float inv = 1.f / se;
    int g = batch[wid];
    float acc0 = 0.f, acc1 = 0.f;
#pragma unroll
    for (int l = 0; l < cL; l++) {
        const float* sp = seq + ((size_t)l * cN + wid) * 128;
        float w = s[l] * inv;
        acc0 += w * sp[lane];
        acc1 += w * sp[lane + 64];
    }
    atomicAdd(&pooled[(size_t)g * 128 + lane], acc0);
    atomicAdd(&pooled[(size_t)g * 128 + lane + 64], acc1);
}

__global__ void count_kernel(const int* __restrict__ batch, float* __restrict__ cnt) {
    int i = blockIdx.x * blockDim.x + threadIdx.x;
    if (i < cN) atomicAdd(&cnt[batch[i]], 1.f);
}

__global__ void div_pool_kernel(float* __restrict__ pooled, const float* __restrict__ cnt) {
    int i = blockIdx.x * blockDim.x + threadIdx.x;
    if (i < cG * 128) pooled[i] /= fmaxf(cnt[i >> 7], 1.f);
}

// ---------------- fused MLP head ----------------
__global__ __launch_bounds__(256)
void head_fused_kernel(const float* __restrict__ pooled,
                       const float* __restrict__ m1_w, const float* __restrict__ m1_b,
                       const float* __restrict__ m2_w, const float* __restrict__ m2_b,
                       const float* __restrict__ res_w, const float* __restrict__ res_b,
                       float* __restrict__ out) {
    __shared__ float pl[4][128];
    __shared__ float hd[4][128];
    const int tid = threadIdx.x;
    const int r0 = blockIdx.y << 2;
    const int c0 = blockIdx.x << 8;
#pragma unroll
    for (int e = tid; e < 512; e += 256) {
        int r = e >> 7, k = e & 127;
        pl[r][k] = pooled[(size_t)(r0 + r) * 128 + k];
    }
    __syncthreads();
#pragma unroll
    for (int e = tid; e < 512; e += 256) {
        int r = e >> 7, n = e & 127;
        float acc = m1_b[n];
#pragma unroll 8
        for (int k = 0; k < 128; k++) acc = fmaf(pl[r][k], m1_w[k * 128 + n], acc);
        hd[r][n] = fmaxf(acc, 0.f);
    }
    __syncthreads();
    int col = c0 + tid;
    if (col >= cOUT) return;
    float b = m2_b[col] + res_b[col];
    float acc[4] = {b, b, b, b};
    for (int k = 0; k < 128; k++) {
        float w2 = m2_w[(size_t)k * cOUT + col];
        float wr = res_w[(size_t)k * cOUT + col];
#pragma unroll
        for (int r = 0; r < 4; r++)
            acc[r] = fmaf(hd[r][k], w2, fmaf(pl[r][k], wr, acc[r]));
    }
#pragma unroll
    for (int r = 0; r < 4; r++)
        out[(size_t)(r0 + r) * cOUT + col] = acc[r];
}

// ---------------- launch helpers ----------------
static inline int ceil_div(long a, long b) { return (int)((a + b - 1) / b); }

// non-swizzled (embedding: single column block)
template<int OUTB>
static void launch_mfma(const unsigned short* A1, const unsigned short* B1, int k1,
                        const unsigned short* A2, const unsigned short* B2, int k2,
                        const float* bias, void* C, int M, int N, hipStream_t s) {
    dim3 g((N + 127) >> 7, (M + 127) >> 7);
    if (bias) gemm_mfma_kernel<1, OUTB, 0><<<g, 256, 0, s>>>(A1, B1, k1, A2, B2, k2, bias, C, M, N, 0);
    else      gemm_mfma_kernel<0, OUTB, 0><<<g, 256, 0, s>>>(A1, B1, k1, A2, B2, k2, bias, C, M, N, 0);
}
// XCD-swizzled (nbn column blocks share a row panel)
template<int HASBIAS, int OUTB>
static void launch_mfma_swz(const unsigned short* A1, const unsigned short* B1, int k1,
                            const float* bias, void* C, int M, int N, hipStream_t s) {
    int nbn = N >> 7;
    int groups = ((((M + 127) >> 7) + 7) / 8) * 8;   // pad to multiple of 8
    dim3 g(groups * nbn);
    gemm_mfma_kernel<HASBIAS, OUTB, 1><<<g, 256, 0, s>>>(A1, B1, k1, nullptr, nullptr, 0, bias, C, M, N, nbn);
}

static void fillI(int* p, long n, int v, hipStream_t s) {
    fill_i32_kernel<<<ceil_div(n, 256), 256, 0, s>>>(p, n, v);
}
static void convB(const float* a, unsigned short* b, long n, hipStream_t s) {
    conv_bf16_kernel<<<ceil_div(n, 256), 256, 0, s>>>(a, b, n);
}

extern "C" void kernel_launch(void* const* d_in, const int* in_sizes, int n_in,
                              void* d_out, int out_size, void* d_ws, size_t ws_size,
                              hipStream_t stream) {
    const float* x      = (const float*)d_in[0];
    const int*   ei     = (const int*)d_in[1];
    const int*   batch  = (const int*)d_in[2];
    const float* emb_W  = (const float*)d_in[3];
    const float* emb_b  = (const float*)d_in[4];
    const float* Wl     = (const float*)d_in[5];
    const float* bl     = (const float*)d_in[6];
    const float* Wr     = (const float*)d_in[7];
    const float* br     = (const float*)d_in[8];
    const float* att_a  = (const float*)d_in[9];
    const float* conv_b = (const float*)d_in[10];
    const float* ln_w   = (const float*)d_in[11];
    const float* ln_b   = (const float*)d_in[12];
    const float* Wih_f  = (const float*)d_in[13];
    const float* Whh_f  = (const float*)d_in[14];
    const float* bih_f  = (const float*)d_in[15];
    const float* bhh_f  = (const float*)d_in[16];
    const float* Wih_b  = (const float*)d_in[17];
    const float* Whh_b  = (const float*)d_in[18];
    const float* bih_b  = (const float*)d_in[19];
    const float* bhh_b  = (const float*)d_in[20];
    const float* jk_w   = (const float*)d_in[21];
    // d_in[22] = jk_b: constant across L -> softmax-invariant, unused
    const float* m1_w   = (const float*)d_in[23];
    const float* m1_b   = (const float*)d_in[24];
    const float* m2_w   = (const float*)d_in[25];
    const float* m2_b   = (const float*)d_in[26];
    const float* res_w  = (const float*)d_in[27];
    const float* res_b  = (const float*)d_in[28];
    float* out = (float*)d_out;

    const int* src = ei;
    const int* dst = ei + cE;

    // ---------------- workspace layout ----------------
    char* ws = (char*)d_ws;
    size_t off = 0;
    auto alloc = [&](size_t bytes) -> char* {
        size_t o = (off + 255) & ~(size_t)255;
        off = o + bytes;
        return ws + o;
    };
    unsigned short* x16     = (unsigned short*)alloc((size_t)cN * cFin * 2);
    unsigned short* embWT   = (unsigned short*)alloc((size_t)cC * cFin * 2);
    unsigned short* emb_b16 = (unsigned short*)alloc((size_t)cN * cC * 2);
    float*          seq     = (float*)alloc((size_t)cL * cN * cC * 4);
    unsigned short* seqb16  = (unsigned short*)alloc((size_t)cL * cN * cC * 2);
    unsigned short* WT      = (unsigned short*)alloc((size_t)cL * 1024 * 128 * 2);
    float*          bb      = (float*)alloc((size_t)cL * 1024 * 4);
    unsigned short* WihPfb  = (unsigned short*)alloc((size_t)cP * cC * 2);   // fwd rows 0..1279, bwd 1280..2559
    unsigned short* WhhPf   = (unsigned short*)alloc((size_t)c4HL * cHL * 2);
    unsigned short* WhhPb   = (unsigned short*)alloc((size_t)c4HL * cHL * 2);
    float*          biasPf  = (float*)alloc((size_t)c4HL * 4);
    float*          biasPb  = (float*)alloc((size_t)c4HL * 4);
    unsigned short* hf0     = (unsigned short*)alloc((size_t)cN * cHL * 2);
    unsigned short* hf1     = (unsigned short*)alloc((size_t)cN * cHL * 2);
    unsigned short* hbk0    = (unsigned short*)alloc((size_t)cN * cHL * 2);
    unsigned short* hbk1    = (unsigned short*)alloc((size_t)cN * cHL * 2);
    float*          cf      = (float*)alloc((size_t)cN * cHL * 4);
    float*          cbk     = (float*)alloc((size_t)cN * cHL * 4);
    float*          jks     = (float*)alloc((size_t)cL * cN * 4);
    float*          pooled  = (float*)alloc((size_t)cG * cC * 4);
    float*          cnt     = (float*)alloc((size_t)cG * 4);
    int*            offs    = (int*)alloc((size_t)(cN + 1) * 4);
    int*            cursor  = (int*)alloc((size_t)cN * 4);
    int*            src_csr = (int*)alloc((size_t)cE * 4);
    unsigned short* xlr     = (unsigned short*)alloc((size_t)cN * 1024 * 2);
    // P (Wih-hoist) allocated LAST; used only if the workspace is big enough.
    unsigned short* Pall    = (unsigned short*)alloc((size_t)cL * cN * cP * 2);  // 256 MB
    const bool useP = (off <= ws_size);

    unsigned short* WihPf = WihPfb;
    unsigned short* WihPb = WihPfb + (size_t)c4HL * cC;

    hipStream_t s = stream;

    // ---------------- CSR by dst (payload = src) ----------------
    fillI(cursor, cN, 0, s);
    hist_kernel<<<ceil_div(cE, 256), 256, 0, s>>>(dst, cursor);
    scan_kernel<<<1, 256, 0, s>>>(cursor, offs);
    copy_i32_kernel<<<ceil_div(cN, 256), 256, 0, s>>>(offs, cursor, cN);
    scatter_kernel<<<ceil_div(cE, 256), 256, 0, s>>>(src, dst, cursor, src_csr);

    // ---------------- weight prep (bf16) ----------------
    wproj_prep_kernel<<<ceil_div((long)cL * 1024 * 128, 256), 256, 0, s>>>(Wl, Wr, WT);
    bias_prep_kernel<<<ceil_div((long)cL * 1024, 256), 256, 0, s>>>(bl, br, bb);
    embw_prep_kernel<<<ceil_div((long)cC * cFin, 256), 256, 0, s>>>(emb_W, embWT);
    convB(x, x16, (long)cN * cFin, s);
    lstm_prep_kernel<<<ceil_div((long)c4HL * 449, 256), 256, 0, s>>>(
        Wih_f, Whh_f, bih_f, bhh_f, WihPf, WhhPf, biasPf);
    lstm_prep_kernel<<<ceil_div((long)c4HL * 449, 256), 256, 0, s>>>(
        Wih_b, Whh_b, bih_b, bhh_b, WihPb, WhhPb, biasPb);
    init_tail_kernel<<<ceil_div((long)cL * cN + cG * cC + cG, 256), 256, 0, s>>>(jks, pooled, cnt);

    // ---------------- embedding (bf16 MFMA, direct bf16 out) ----------------
    launch_mfma<1>(x16, embWT, cFin, nullptr, nullptr, 0, emb_b, emb_b16, cN, cC, s);

    // ---------------- GAT layers ----------------
    for (int l = 0; l < cL; l++) {
        const unsigned short* hin = (l == 0) ? emb_b16 : seqb16 + (size_t)(l - 1) * cN * cC;
        launch_mfma_swz<1, 1>(hin, WT + (size_t)l * 1024 * 128, cC,
                              bb + (size_t)l * 1024, xlr, cN, 1024, s);
        gat_fused_kernel<<<ceil_div((long)cN * 64, 256), 256, 0, s>>>(
            xlr, src_csr, offs, att_a + (size_t)l * cH * cC,
            conv_b + (size_t)l * cC, ln_w + (size_t)l * cC, ln_b + (size_t)l * cC,
            seq + (size_t)l * cN * cC, seqb16 + (size_t)l * cN * cC);
    }

    // ---------------- bidirectional LSTM ----------------
    if (useP) {
        // P = seq_all(50000x128) @ [Wih_f|Wih_b]^T (2560x128), bf16 out
        launch_mfma_swz<0, 1>(seqb16, WihPfb, cC, nullptr, Pall, cL * cN, cP, s);
    }
    unsigned short* hfb[2]  = {hf0, hf1};
    unsigned short* hbb[2]  = {hbk0, hbk1};
    dim3 lg(80 * 10);   // 80 row-groups (padded) x 5 bn x 2 dir, XCD-swizzled
    for (int k = 0; k < cL; k++) {
        int cur = k & 1, prev = cur ^ 1;
        int t = cL - 1 - k;
        const unsigned short* A1f = seqb16 + (size_t)k * cN * cC;
        const unsigned short* A1b = seqb16 + (size_t)t * cN * cC;
        const unsigned short* PfP = Pall + (size_t)k * cN * cP;
        const unsigned short* PbP = Pall + (size_t)t * cN * cP;
        if (useP) {
            if (k == 0)
                gemm_lstm_dual_kernel<1, 1><<<lg, 512, 0, s>>>(
                    nullptr, nullptr, nullptr, nullptr, nullptr, nullptr, nullptr, nullptr,
                    biasPf, biasPb, cf, cbk, hfb[cur], hbb[cur], jk_w,
                    jks + (size_t)k * cN, jks + (size_t)t * cN, PfP, PbP);
            else
                gemm_lstm_dual_kernel<0, 1><<<lg, 512, 0, s>>>(
                    nullptr, nullptr, nullptr, nullptr, hfb[prev], hbb[prev], WhhPf, WhhPb,
                    biasPf, biasPb, cf, cbk, hfb[cur], hbb[cur], jk_w,
                    jks + (size_t)k * cN, jks + (size_t)t * cN, PfP, PbP);
        } else {
            if (k == 0)
                gemm_lstm_dual_kernel<1, 0><<<lg, 512, 0, s>>>(
                    A1f, A1b, WihPf, WihPb, nullptr, nullptr, nullptr, nullptr,
                    biasPf, biasPb, cf, cbk, hfb[cur], hbb[cur], jk_w,
                    jks + (size_t)k * cN, jks + (size_t)t * cN, nullptr, nullptr);
            else
                gemm_lstm_dual_kernel<0, 0><<<lg, 512, 0, s>>>(
                    A1f, A1b, WihPf, WihPb, hfb[prev], hbb[prev], WhhPf, WhhPb,
                    biasPf, biasPb, cf, cbk, hfb[cur], hbb[cur], jk_w,
                    jks + (size_t)k * cN, jks + (size_t)t * cN, nullptr, nullptr);
        }
    }

    // ---------------- JK softmax, pooling, fused head ----------------
    jk_pool_kernel<<<ceil_div((long)cN * 64, 256), 256, 0, s>>>(seq, jks, batch, pooled);
    count_kernel<<<ceil_div(cN, 256), 256, 0, s>>>(batch, cnt);
    div_pool_kernel<<<ceil_div((long)cG * 128, 256), 256, 0, s>>>(pooled, cnt);
    head_fused_kernel<<<dim3(ceil_div(cOUT, 256), cG / 4), 256, 0, s>>>(
        pooled, m1_w, m1_b, m2_w, m2_b, res_w, res_b, out);
}